// Round 1
// baseline (1682.682 us; speedup 1.0000x reference)
//
#include <hip/hip_runtime.h>

#define B_ 64
#define A_ 1024
#define C_ 64
#define D_ 512
#define INV_SD 0.044194173824159216f

// ---------------- row stats (mean, rstd) over D=512 per row ----------------
__global__ __launch_bounds__(256) void k_rowstats(const float* __restrict__ x,
                                                  float* __restrict__ stats) {
  int row = blockIdx.x;
  const float* xr = x + (size_t)row * D_;
  int t = threadIdx.x;
  float2 v = *(const float2*)(xr + 2 * t);
  float s = v.x + v.y;
  float q = v.x * v.x + v.y * v.y;
#pragma unroll
  for (int o = 32; o; o >>= 1) { s += __shfl_xor(s, o); q += __shfl_xor(q, o); }
  __shared__ float ls[4], lq[4];
  int w = t >> 6;
  if ((t & 63) == 0) { ls[w] = s; lq[w] = q; }
  __syncthreads();
  if (t == 0) {
    float S = (ls[0] + ls[1]) + (ls[2] + ls[3]);
    float Q = (lq[0] + lq[1]) + (lq[2] + lq[3]);
    float mu = S * (1.0f / D_);
    float var = Q * (1.0f / D_) - mu * mu;
    stats[2 * row] = mu;
    stats[2 * row + 1] = rsqrtf(var + 1e-5f);
  }
}

// ---------------- LN a full row, write result ----------------
__global__ __launch_bounds__(256) void k_ln(const float* __restrict__ x,
                                            const float* __restrict__ lw,
                                            const float* __restrict__ lb,
                                            float* __restrict__ y) {
  int row = blockIdx.x;
  const float* xr = x + (size_t)row * D_;
  int t = threadIdx.x;
  float2 v = *(const float2*)(xr + 2 * t);
  float s = v.x + v.y, q = v.x * v.x + v.y * v.y;
#pragma unroll
  for (int o = 32; o; o >>= 1) { s += __shfl_xor(s, o); q += __shfl_xor(q, o); }
  __shared__ float ls[4], lq[4];
  int w = t >> 6;
  if ((t & 63) == 0) { ls[w] = s; lq[w] = q; }
  __syncthreads();
  float S = (ls[0] + ls[1]) + (ls[2] + ls[3]);
  float Q = (lq[0] + lq[1]) + (lq[2] + lq[3]);
  float mu = S * (1.0f / D_);
  float rs = rsqrtf(Q * (1.0f / D_) - mu * mu + 1e-5f);
  int d = 2 * t;
  float2 o2;
  o2.x = (v.x - mu) * rs * lw[d] + lb[d];
  o2.y = (v.y - mu) * rs * lw[d + 1] + lb[d + 1];
  *(float2*)(y + (size_t)row * D_ + d) = o2;
}

// ---------------- hl[b,c,d] = (1/16) * sum_j LN(att_vf[b, j*64+c, :])[d] ----------------
__global__ __launch_bounds__(256) void k_avg_hl(const float* __restrict__ att,
                                                const float* __restrict__ stats,
                                                const float* __restrict__ lw,
                                                const float* __restrict__ lb,
                                                float* __restrict__ hl) {
  int blk = blockIdx.x;  // B*C
  int b = blk >> 6, c = blk & 63;
  int t = threadIdx.x;
#pragma unroll
  for (int dd = 0; dd < 2; ++dd) {
    int d = t + dd * 256;
    float acc = 0.f;
#pragma unroll 4
    for (int jj = 0; jj < 16; ++jj) {
      size_t ridx = (size_t)b * A_ + jj * 64 + c;
      float mu = stats[2 * ridx], rs = stats[2 * ridx + 1];
      acc += (att[ridx * D_ + d] - mu) * rs;
    }
    acc *= (1.f / 16.f);
    hl[(size_t)blk * D_ + d] = acc * lw[d] + lb[d];
  }
}

// ---------------- GEMM: C[M,512] = (optional LN of A)[M,512] @ W[512,512] ----------------
template <bool LNA>
__global__ __launch_bounds__(256) void k_gemm(const float* __restrict__ Amat,
                                              const float* __restrict__ Wmat,
                                              const float* __restrict__ stats,
                                              const float* __restrict__ lw,
                                              const float* __restrict__ lb,
                                              float* __restrict__ Cmat) {
  __shared__ float As[64][33];
  __shared__ float Bs[32][65];
  int bn = blockIdx.x;  // 8 tiles of N
  int bm = blockIdx.y;
  int t = threadIdx.x;
  int tx = t & 15, ty = t >> 4;
  float acc[4][4] = {};
  int ar = t >> 2, ac = (t & 3) * 8;
  int br = t >> 3, bc = (t & 7) * 8;
  const float* Arow = Amat + (size_t)(bm * 64 + ar) * 512 + ac;
  float mu = 0.f, rs = 1.f;
  if constexpr (LNA) {
    mu = stats[(size_t)(bm * 64 + ar) * 2];
    rs = stats[(size_t)(bm * 64 + ar) * 2 + 1];
  }
  for (int k0 = 0; k0 < 512; k0 += 32) {
    float4 a0 = *(const float4*)(Arow + k0);
    float4 a1 = *(const float4*)(Arow + k0 + 4);
    float av[8] = {a0.x, a0.y, a0.z, a0.w, a1.x, a1.y, a1.z, a1.w};
    if constexpr (LNA) {
#pragma unroll
      for (int u = 0; u < 8; ++u)
        av[u] = (av[u] - mu) * rs * lw[k0 + ac + u] + lb[k0 + ac + u];
    }
    const float* Brow = Wmat + (size_t)(k0 + br) * 512 + bn * 64 + bc;
    float4 b0 = *(const float4*)(Brow);
    float4 b1 = *(const float4*)(Brow + 4);
    float bv[8] = {b0.x, b0.y, b0.z, b0.w, b1.x, b1.y, b1.z, b1.w};
#pragma unroll
    for (int u = 0; u < 8; ++u) As[ar][ac + u] = av[u];
#pragma unroll
    for (int u = 0; u < 8; ++u) Bs[br][bc + u] = bv[u];
    __syncthreads();
#pragma unroll 8
    for (int kk = 0; kk < 32; ++kk) {
      float af[4], bf[4];
#pragma unroll
      for (int ii = 0; ii < 4; ++ii) af[ii] = As[ty * 4 + ii][kk];
#pragma unroll
      for (int jj = 0; jj < 4; ++jj) bf[jj] = Bs[kk][tx * 4 + jj];
#pragma unroll
      for (int ii = 0; ii < 4; ++ii)
#pragma unroll
        for (int jj = 0; jj < 4; ++jj) acc[ii][jj] += af[ii] * bf[jj];
    }
    __syncthreads();
  }
#pragma unroll
  for (int ii = 0; ii < 4; ++ii) {
    float4 o;
    o.x = acc[ii][0]; o.y = acc[ii][1]; o.z = acc[ii][2]; o.w = acc[ii][3];
    *(float4*)(Cmat + (size_t)(bm * 64 + ty * 4 + ii) * 512 + bn * 64 + tx * 4) = o;
  }
}

// ---------------- h2h attention: per (b,i): s = hide[b,i]·hide[b,j], softmax, out = a @ hln ----------------
__global__ __launch_bounds__(256) void k_h2h_attn(const float* __restrict__ hide,
                                                  const float* __restrict__ hln,
                                                  float* __restrict__ outp) {
  int blk = blockIdx.x;  // B*C
  int b = blk >> 6, i = blk & 63;
  int t = threadIdx.x;
  __shared__ float hrow[D_];
  __shared__ float wts[C_];
  const float* Hb = hide + (size_t)b * C_ * D_;
  float2 hv = *(const float2*)(Hb + (size_t)i * D_ + 2 * t);
  hrow[2 * t] = hv.x;
  hrow[2 * t + 1] = hv.y;
  __syncthreads();
  int j = t >> 2, p = t & 3;
  const float* Hj = Hb + (size_t)j * D_;
  float partial = 0.f;
#pragma unroll 8
  for (int kk = 0; kk < 128; ++kk) {
    int k = p * 128 + ((kk + p * 8) & 127);  // stagger to avoid LDS bank conflict
    partial += hrow[k] * Hj[k];
  }
  partial += __shfl_xor(partial, 1);
  partial += __shfl_xor(partial, 2);
  if (p == 0) wts[j] = partial * INV_SD;
  __syncthreads();
  if (t < 64) {
    float v = wts[t];
    float m = v;
#pragma unroll
    for (int o = 32; o; o >>= 1) m = fmaxf(m, __shfl_xor(m, o));
    float e = __expf(v - m);
    float ssum = e;
#pragma unroll
    for (int o = 32; o; o >>= 1) ssum += __shfl_xor(ssum, o);
    wts[t] = e / ssum;
  }
  __syncthreads();
  const float* Lb = hln + (size_t)b * C_ * D_;
  float* orow = outp + (size_t)blk * D_;
#pragma unroll
  for (int dd = 0; dd < 2; ++dd) {
    int d = t + dd * 256;
    float acc = 0.f;
#pragma unroll 8
    for (int jj = 0; jj < 64; ++jj) acc += wts[jj] * Lb[(size_t)jj * D_ + d];
    orow[d] = acc;
  }
}

// ---------------- h2a: per (b,a): 2-way softmax over {hW[b,a%C], att[b,a]} then combine ----------------
__global__ __launch_bounds__(256) void k_h2a(const float* __restrict__ att,
                                             const float* __restrict__ hW,
                                             float* __restrict__ outp) {
  int blk = blockIdx.x;  // B*A
  int b = blk >> 10, a = blk & 1023;
  int c = a & 63;
  int t = threadIdx.x;
  const float* ar = att + (size_t)blk * D_;
  const float* wr = hW + (size_t)(b * 64 + c) * D_;
  float2 av = *(const float2*)(ar + 2 * t);
  float2 wv = *(const float2*)(wr + 2 * t);
  float d1 = av.x * wv.x + av.y * wv.y;
  float d2 = av.x * av.x + av.y * av.y;
#pragma unroll
  for (int o = 32; o; o >>= 1) { d1 += __shfl_xor(d1, o); d2 += __shfl_xor(d2, o); }
  __shared__ float r1[4], r2[4];
  int w = t >> 6;
  if ((t & 63) == 0) { r1[w] = d1; r2[w] = d2; }
  __syncthreads();
  float s1 = ((r1[0] + r1[1]) + (r1[2] + r1[3])) * INV_SD;
  float s2 = ((r2[0] + r2[1]) + (r2[2] + r2[3])) * INV_SD;
  float m = fmaxf(s1, s2);
  float e1 = __expf(s1 - m), e2 = __expf(s2 - m);
  float inv = 1.f / (e1 + e2);
  float alpha = e1 * inv, beta = e2 * inv;
  float2 o2;
  o2.x = alpha * wv.x + beta * av.x;
  o2.y = alpha * wv.y + beta * av.y;
  *(float2*)(outp + (size_t)blk * D_ + 2 * t) = o2;
}

// ---------------- layer2 a2h attention: per (b,c): 17-way softmax over {16 aW rows, hl1 self} ----------------
__global__ __launch_bounds__(256) void k_a2h_attn(const float* __restrict__ hl1,
                                                  const float* __restrict__ aW,
                                                  float* __restrict__ hl2) {
  int blk = blockIdx.x;  // CB*C (chunked over batches)
  int b = blk >> 6, c = blk & 63;
  int t = threadIdx.x;
  __shared__ float hrow[D_];
  __shared__ float wts[32];
  __shared__ float red[4];
  const float* hr = hl1 + (size_t)blk * D_;
  float2 v = *(const float2*)(hr + 2 * t);
  hrow[2 * t] = v.x;
  hrow[2 * t + 1] = v.y;
  float sd = v.x * v.x + v.y * v.y;
#pragma unroll
  for (int o = 32; o; o >>= 1) sd += __shfl_xor(sd, o);
  int w = t >> 6;
  if ((t & 63) == 0) red[w] = sd;
  __syncthreads();
  int j = t >> 4, p = t & 15;
  const float* arow = aW + ((size_t)b * A_ + j * 64 + c) * D_;
  float partial = 0.f;
#pragma unroll 8
  for (int kk = 0; kk < 32; ++kk) {
    int k = p * 32 + ((kk + p * 2) & 31);  // stagger to avoid LDS bank conflict
    partial += hrow[k] * arow[k];
  }
#pragma unroll
  for (int o = 8; o; o >>= 1) partial += __shfl_xor(partial, o);
  if (p == 0) wts[j] = partial * INV_SD;
  if (t == 0) wts[16] = ((red[0] + red[1]) + (red[2] + red[3])) * INV_SD;
  __syncthreads();
  if (t < 64) {
    float val = (t < 17) ? wts[t] : -3.0e38f;
    float m = val;
#pragma unroll
    for (int o = 32; o; o >>= 1) m = fmaxf(m, __shfl_xor(m, o));
    float e = (t < 17) ? __expf(val - m) : 0.f;
    float ssum = e;
#pragma unroll
    for (int o = 32; o; o >>= 1) ssum += __shfl_xor(ssum, o);
    if (t < 17) wts[t] = e / ssum;
  }
  __syncthreads();
  float* orow = hl2 + (size_t)blk * D_;
#pragma unroll
  for (int dd = 0; dd < 2; ++dd) {
    int d = t + dd * 256;
    float acc = wts[16] * hrow[d];
#pragma unroll 4
    for (int jj = 0; jj < 16; ++jj)
      acc += wts[jj] * aW[((size_t)b * A_ + jj * 64 + c) * D_ + d];
    orow[d] = acc;
  }
}

extern "C" void kernel_launch(void* const* d_in, const int* in_sizes, int n_in,
                              void* d_out, int out_size, void* d_ws, size_t ws_size,
                              hipStream_t stream) {
  const float* att_vf = (const float*)d_in[0];
  const float* W1_h2h = (const float*)d_in[4];
  const float* W1_h2a = (const float*)d_in[5];
  const float* ln11w = (const float*)d_in[6];
  const float* ln11b = (const float*)d_in[7];
  const float* ln12w = (const float*)d_in[8];
  const float* ln12b = (const float*)d_in[9];
  const float* ln13w = (const float*)d_in[10];
  const float* ln13b = (const float*)d_in[11];
  const float* W2_a2h = (const float*)d_in[12];
  const float* W2_h2h = (const float*)d_in[13];
  const float* W2_h2a = (const float*)d_in[14];
  const float* ln21w = (const float*)d_in[15];
  const float* ln21b = (const float*)d_in[16];
  const float* ln22w = (const float*)d_in[17];
  const float* ln22b = (const float*)d_in[18];
  const float* ln23w = (const float*)d_in[19];
  const float* ln23b = (const float*)d_in[20];
  float* out = (float*)d_out;

  float* ws = (float*)d_ws;
  const size_t SMALL = (size_t)B_ * C_ * D_;  // 2097152 floats
  float* stats = ws;                          // 2*B*A floats
  float* A0 = ws + 2 * B_ * A_;
  float* A1 = A0 + SMALL;
  float* A2 = A1 + SMALL;
  float* A3 = A2 + SMALL;
  float* aW = A3 + SMALL;
  size_t base_floats = (size_t)(aW - ws);
  size_t ws_floats = ws_size / 4;
  int CB = 1;
  if (ws_floats > base_floats) {
    size_t cap = (ws_floats - base_floats) / ((size_t)A_ * D_);
    CB = (int)(cap > 64 ? 64 : (cap < 1 ? 1 : cap));
  }
  int cb = 1;
  while (cb * 2 <= CB && cb * 2 <= 64) cb *= 2;  // power of two dividing 64
  CB = cb;
  int nchunks = B_ / CB;

  dim3 blk(256);
  // ---- layer 1 ----
  k_rowstats<<<B_ * A_, blk, 0, stream>>>(att_vf, stats);
  k_avg_hl<<<B_ * C_, blk, 0, stream>>>(att_vf, stats, ln11w, ln11b, A0);  // hl
  // h2h #1
  k_ln<<<B_ * C_, blk, 0, stream>>>(A0, ln12w, ln12b, A1);                  // hln
  k_gemm<false><<<dim3(8, (B_ * C_) / 64), blk, 0, stream>>>(A1, W1_h2h, nullptr, nullptr, nullptr, A2);
  k_h2h_attn<<<B_ * C_, blk, 0, stream>>>(A2, A1, A3);                      // hl1 = A3
  // h2a #1 -> att1 in d_out
  k_ln<<<B_ * C_, blk, 0, stream>>>(A3, ln13w, ln13b, A1);
  k_gemm<false><<<dim3(8, (B_ * C_) / 64), blk, 0, stream>>>(A1, W1_h2a, nullptr, nullptr, nullptr, A2);
  k_h2a<<<B_ * A_, blk, 0, stream>>>(att_vf, A2, out);
  // ---- layer 2: a2h attention ----
  k_rowstats<<<B_ * A_, blk, 0, stream>>>(out, stats);
  for (int ch = 0; ch < nchunks; ++ch) {
    size_t b0 = (size_t)ch * CB;
    k_gemm<true><<<dim3(8, (CB * A_) / 64), blk, 0, stream>>>(
        out + b0 * A_ * D_, W2_a2h, stats + b0 * A_ * 2, ln21w, ln21b, aW);
    k_a2h_attn<<<CB * C_, blk, 0, stream>>>(A3 + b0 * C_ * D_, aW, A0 + b0 * C_ * D_);  // hl2 = A0
  }
  // h2h #2
  k_ln<<<B_ * C_, blk, 0, stream>>>(A0, ln22w, ln22b, A1);
  k_gemm<false><<<dim3(8, (B_ * C_) / 64), blk, 0, stream>>>(A1, W2_h2h, nullptr, nullptr, nullptr, A2);
  k_h2h_attn<<<B_ * C_, blk, 0, stream>>>(A2, A1, A0);                      // hl2' = A0
  // h2a #2 -> att2 in d_out (in-place over att1)
  k_ln<<<B_ * C_, blk, 0, stream>>>(A0, ln23w, ln23b, A1);
  k_gemm<false><<<dim3(8, (B_ * C_) / 64), blk, 0, stream>>>(A1, W2_h2a, nullptr, nullptr, nullptr, A2);
  k_h2a<<<B_ * A_, blk, 0, stream>>>(out, A2, out);
}

// Round 2
// 1158.947 us; speedup vs baseline: 1.4519x; 1.4519x over previous
//
#include <hip/hip_runtime.h>

#define B_ 64
#define A_ 1024
#define C_ 64
#define D_ 512
#define INV_SD 0.044194173824159216f

typedef __bf16 bf16_t;
typedef __bf16 bf16x8 __attribute__((ext_vector_type(8)));
typedef __bf16 bf16x2 __attribute__((ext_vector_type(2)));
typedef float f32x4 __attribute__((ext_vector_type(4)));

static __device__ __forceinline__ bf16_t f2b(float x) { return (bf16_t)x; }

// ---------------- row stats (mean, rstd) over D=512 per row ----------------
__global__ __launch_bounds__(256) void k_rowstats(const float* __restrict__ x,
                                                  float* __restrict__ stats) {
  int row = blockIdx.x;
  const float* xr = x + (size_t)row * D_;
  int t = threadIdx.x;
  float2 v = *(const float2*)(xr + 2 * t);
  float s = v.x + v.y;
  float q = v.x * v.x + v.y * v.y;
#pragma unroll
  for (int o = 32; o; o >>= 1) { s += __shfl_xor(s, o); q += __shfl_xor(q, o); }
  __shared__ float ls[4], lq[4];
  int w = t >> 6;
  if ((t & 63) == 0) { ls[w] = s; lq[w] = q; }
  __syncthreads();
  if (t == 0) {
    float S = (ls[0] + ls[1]) + (ls[2] + ls[3]);
    float Q = (lq[0] + lq[1]) + (lq[2] + lq[3]);
    float mu = S * (1.0f / D_);
    float var = Q * (1.0f / D_) - mu * mu;
    stats[2 * row] = mu;
    stats[2 * row + 1] = rsqrtf(var + 1e-5f);
  }
}

// ---------------- LN a full row, write f32 + bf16 ----------------
__global__ __launch_bounds__(256) void k_ln(const float* __restrict__ x,
                                            const float* __restrict__ lw,
                                            const float* __restrict__ lb,
                                            float* __restrict__ y,
                                            bf16_t* __restrict__ yb) {
  int row = blockIdx.x;
  const float* xr = x + (size_t)row * D_;
  int t = threadIdx.x;
  float2 v = *(const float2*)(xr + 2 * t);
  float s = v.x + v.y, q = v.x * v.x + v.y * v.y;
#pragma unroll
  for (int o = 32; o; o >>= 1) { s += __shfl_xor(s, o); q += __shfl_xor(q, o); }
  __shared__ float ls[4], lq[4];
  int w = t >> 6;
  if ((t & 63) == 0) { ls[w] = s; lq[w] = q; }
  __syncthreads();
  float S = (ls[0] + ls[1]) + (ls[2] + ls[3]);
  float Q = (lq[0] + lq[1]) + (lq[2] + lq[3]);
  float mu = S * (1.0f / D_);
  float rs = rsqrtf(Q * (1.0f / D_) - mu * mu + 1e-5f);
  int d = 2 * t;
  float2 o2;
  o2.x = (v.x - mu) * rs * lw[d] + lb[d];
  o2.y = (v.y - mu) * rs * lw[d + 1] + lb[d + 1];
  *(float2*)(y + (size_t)row * D_ + d) = o2;
  bf16x2 ob;
  ob.x = f2b(o2.x);
  ob.y = f2b(o2.y);
  *(bf16x2*)(yb + (size_t)row * D_ + d) = ob;
}

// ---------------- LN a full row (stats in-kernel), write bf16 only ----------------
__global__ __launch_bounds__(256) void k_lnb(const float* __restrict__ x,
                                             const float* __restrict__ lw,
                                             const float* __restrict__ lb,
                                             bf16_t* __restrict__ yb) {
  int row = blockIdx.x;
  const float* xr = x + (size_t)row * D_;
  int t = threadIdx.x;
  float2 v = *(const float2*)(xr + 2 * t);
  float s = v.x + v.y, q = v.x * v.x + v.y * v.y;
#pragma unroll
  for (int o = 32; o; o >>= 1) { s += __shfl_xor(s, o); q += __shfl_xor(q, o); }
  __shared__ float ls[4], lq[4];
  int w = t >> 6;
  if ((t & 63) == 0) { ls[w] = s; lq[w] = q; }
  __syncthreads();
  float S = (ls[0] + ls[1]) + (ls[2] + ls[3]);
  float Q = (lq[0] + lq[1]) + (lq[2] + lq[3]);
  float mu = S * (1.0f / D_);
  float rs = rsqrtf(Q * (1.0f / D_) - mu * mu + 1e-5f);
  int d = 2 * t;
  bf16x2 ob;
  ob.x = f2b((v.x - mu) * rs * lw[d] + lb[d]);
  ob.y = f2b((v.y - mu) * rs * lw[d + 1] + lb[d + 1]);
  *(bf16x2*)(yb + (size_t)row * D_ + d) = ob;
}

// ---------------- transpose + convert W[k][n] f32 -> Wt[n][k] bf16 ----------------
__global__ __launch_bounds__(256) void k_wt(const float* __restrict__ W,
                                            bf16_t* __restrict__ Wt) {
  __shared__ float tile[64][65];
  int k0 = blockIdx.x * 64;
  int n0 = blockIdx.y * 64;
  int t = threadIdx.x;
  int r0 = t >> 6;
  int c = t & 63;
#pragma unroll 4
  for (int i = 0; i < 16; ++i) {
    int r = r0 * 16 + i;
    tile[r][c] = W[(size_t)(k0 + r) * 512 + n0 + c];
  }
  __syncthreads();
#pragma unroll 4
  for (int i = 0; i < 16; ++i) {
    int r = r0 * 16 + i;
    Wt[(size_t)(n0 + r) * 512 + k0 + c] = f2b(tile[c][r]);
  }
}

// ---------------- hl[b,c,d] = (1/16) * sum_j LN(att_vf[b, j*64+c, :])[d] ----------------
__global__ __launch_bounds__(256) void k_avg_hl(const float* __restrict__ att,
                                                const float* __restrict__ stats,
                                                const float* __restrict__ lw,
                                                const float* __restrict__ lb,
                                                float* __restrict__ hl) {
  int blk = blockIdx.x;  // B*C
  int b = blk >> 6, c = blk & 63;
  int t = threadIdx.x;
#pragma unroll
  for (int dd = 0; dd < 2; ++dd) {
    int d = t + dd * 256;
    float acc = 0.f;
#pragma unroll 4
    for (int jj = 0; jj < 16; ++jj) {
      size_t ridx = (size_t)b * A_ + jj * 64 + c;
      float mu = stats[2 * ridx], rs = stats[2 * ridx + 1];
      acc += (att[ridx * D_ + d] - mu) * rs;
    }
    acc *= (1.f / 16.f);
    hl[(size_t)blk * D_ + d] = acc * lw[d] + lb[d];
  }
}

// ---------------- MFMA GEMM: C[M,512] f32 = Abf[M,512] bf16 @ Wt^T ----------------
// Wt stored [n][k] bf16. Tile BM x 128, BK=64, 4 waves (2x2), wave tile (BM/2)x64.
template <int BM>
__global__ __launch_bounds__(256) void k_mfma_gemm(const bf16_t* __restrict__ Abf,
                                                   const bf16_t* __restrict__ Wt,
                                                   float* __restrict__ Cmat) {
  constexpr int TR = BM / 32;   // 16-row fragments per wave
  constexpr int NA = BM / 32;   // A 16B-chunks per thread per K-step
  __shared__ bf16_t As[BM * 64];   // [row][k] 128B rows, XOR-swizzled
  __shared__ bf16_t Bs[128 * 64];  // [col][k] 128B rows, XOR-swizzled

  int t = threadIdx.x;
  int lane = t & 63, wave = t >> 6;
  int wr = wave >> 1, wc = wave & 1;
  int lhi = lane >> 4, llo = lane & 15;
  int bn = blockIdx.x;  // 0..3
  int bm = blockIdx.y;

  const bf16_t* Ab = Abf + (size_t)bm * BM * 512;
  const bf16_t* Wb = Wt + (size_t)bn * 128 * 512;

  f32x4 acc[TR][4] = {};
  uint4 areg[NA], breg[4];
  int cc = t & 7;        // 16B chunk within row
  int rr = t >> 3;       // base row 0..31

  auto issue = [&](int k0) {
#pragma unroll
    for (int i = 0; i < NA; ++i)
      areg[i] = *(const uint4*)(Ab + (size_t)(rr + i * 32) * 512 + k0 + cc * 8);
#pragma unroll
    for (int i = 0; i < 4; ++i)
      breg[i] = *(const uint4*)(Wb + (size_t)(rr + i * 32) * 512 + k0 + cc * 8);
  };
  auto store_lds = [&] {
#pragma unroll
    for (int i = 0; i < NA; ++i) {
      int r = rr + i * 32;
      *(uint4*)((char*)As + r * 128 + ((cc * 16) ^ ((r & 7) << 4))) = areg[i];
    }
#pragma unroll
    for (int i = 0; i < 4; ++i) {
      int r = rr + i * 32;
      *(uint4*)((char*)Bs + r * 128 + ((cc * 16) ^ ((r & 7) << 4))) = breg[i];
    }
  };

  issue(0);
  store_lds();
  __syncthreads();

  for (int k0 = 0; k0 < 512; k0 += 64) {
    bool last = (k0 + 64 >= 512);
    if (!last) issue(k0 + 64);
    bf16x8 af[TR][2], bfr[4][2];
#pragma unroll
    for (int kk = 0; kk < 2; ++kk) {
      int bofs = kk * 64 + lhi * 16;
#pragma unroll
      for (int tr = 0; tr < TR; ++tr) {
        int row = wr * (BM / 2) + tr * 16 + llo;
        af[tr][kk] = *(const bf16x8*)((const char*)As + row * 128 + (bofs ^ ((row & 7) << 4)));
      }
#pragma unroll
      for (int tc = 0; tc < 4; ++tc) {
        int col = wc * 64 + tc * 16 + llo;
        bfr[tc][kk] = *(const bf16x8*)((const char*)Bs + col * 128 + (bofs ^ ((col & 7) << 4)));
      }
    }
#pragma unroll
    for (int kk = 0; kk < 2; ++kk)
#pragma unroll
      for (int tr = 0; tr < TR; ++tr)
#pragma unroll
        for (int tc = 0; tc < 4; ++tc)
          acc[tr][tc] = __builtin_amdgcn_mfma_f32_16x16x32_bf16(
              af[tr][kk], bfr[tc][kk], acc[tr][tc], 0, 0, 0);
    __syncthreads();
    if (!last) {
      store_lds();
      __syncthreads();
    }
  }

  float* Cb = Cmat + (size_t)bm * BM * 512 + bn * 128 + wc * 64;
#pragma unroll
  for (int tr = 0; tr < TR; ++tr) {
    int row = wr * (BM / 2) + tr * 16 + lhi * 4;
#pragma unroll
    for (int r = 0; r < 4; ++r)
#pragma unroll
      for (int tc = 0; tc < 4; ++tc)
        Cb[(size_t)(row + r) * 512 + tc * 16 + llo] = acc[tr][tc][r];
  }
}

// ---------------- h2h attention ----------------
__global__ __launch_bounds__(256) void k_h2h_attn(const float* __restrict__ hide,
                                                  const float* __restrict__ hln,
                                                  float* __restrict__ outp) {
  int blk = blockIdx.x;  // B*C
  int b = blk >> 6, i = blk & 63;
  int t = threadIdx.x;
  __shared__ float hrow[D_];
  __shared__ float wts[C_];
  const float* Hb = hide + (size_t)b * C_ * D_;
  float2 hv = *(const float2*)(Hb + (size_t)i * D_ + 2 * t);
  hrow[2 * t] = hv.x;
  hrow[2 * t + 1] = hv.y;
  __syncthreads();
  int j = t >> 2, p = t & 3;
  const float* Hj = Hb + (size_t)j * D_;
  float partial = 0.f;
#pragma unroll 8
  for (int kk = 0; kk < 128; ++kk) {
    int k = p * 128 + ((kk + p * 8) & 127);
    partial += hrow[k] * Hj[k];
  }
  partial += __shfl_xor(partial, 1);
  partial += __shfl_xor(partial, 2);
  if (p == 0) wts[j] = partial * INV_SD;
  __syncthreads();
  if (t < 64) {
    float v = wts[t];
    float m = v;
#pragma unroll
    for (int o = 32; o; o >>= 1) m = fmaxf(m, __shfl_xor(m, o));
    float e = __expf(v - m);
    float ssum = e;
#pragma unroll
    for (int o = 32; o; o >>= 1) ssum += __shfl_xor(ssum, o);
    wts[t] = e / ssum;
  }
  __syncthreads();
  const float* Lb = hln + (size_t)b * C_ * D_;
  float* orow = outp + (size_t)blk * D_;
#pragma unroll
  for (int dd = 0; dd < 2; ++dd) {
    int d = t + dd * 256;
    float acc = 0.f;
#pragma unroll 8
    for (int jj = 0; jj < 64; ++jj) acc += wts[jj] * Lb[(size_t)jj * D_ + d];
    orow[d] = acc;
  }
}

// ---------------- h2a: per (b,a): 2-way softmax over {hW[b,a%C], att[b,a]} ----------------
__global__ __launch_bounds__(256) void k_h2a(const float* __restrict__ att,
                                             const float* __restrict__ hW,
                                             float* __restrict__ outp) {
  int blk = blockIdx.x;  // B*A
  int b = blk >> 10, a = blk & 1023;
  int c = a & 63;
  int t = threadIdx.x;
  const float* ar = att + (size_t)blk * D_;
  const float* wr = hW + (size_t)(b * 64 + c) * D_;
  float2 av = *(const float2*)(ar + 2 * t);
  float2 wv = *(const float2*)(wr + 2 * t);
  float d1 = av.x * wv.x + av.y * wv.y;
  float d2 = av.x * av.x + av.y * av.y;
#pragma unroll
  for (int o = 32; o; o >>= 1) { d1 += __shfl_xor(d1, o); d2 += __shfl_xor(d2, o); }
  __shared__ float r1[4], r2[4];
  int w = t >> 6;
  if ((t & 63) == 0) { r1[w] = d1; r2[w] = d2; }
  __syncthreads();
  float s1 = ((r1[0] + r1[1]) + (r1[2] + r1[3])) * INV_SD;
  float s2 = ((r2[0] + r2[1]) + (r2[2] + r2[3])) * INV_SD;
  float m = fmaxf(s1, s2);
  float e1 = __expf(s1 - m), e2 = __expf(s2 - m);
  float inv = 1.f / (e1 + e2);
  float alpha = e1 * inv, beta = e2 * inv;
  float2 o2;
  o2.x = alpha * wv.x + beta * av.x;
  o2.y = alpha * wv.y + beta * av.y;
  *(float2*)(outp + (size_t)blk * D_ + 2 * t) = o2;
}

// ---------------- layer2 a2h attention: 17-way softmax ----------------
__global__ __launch_bounds__(256) void k_a2h_attn(const float* __restrict__ hl1,
                                                  const float* __restrict__ aW,
                                                  float* __restrict__ hl2) {
  int blk = blockIdx.x;  // CB*C
  int b = blk >> 6, c = blk & 63;
  int t = threadIdx.x;
  __shared__ float hrow[D_];
  __shared__ float wts[32];
  __shared__ float red[4];
  const float* hr = hl1 + (size_t)blk * D_;
  float2 v = *(const float2*)(hr + 2 * t);
  hrow[2 * t] = v.x;
  hrow[2 * t + 1] = v.y;
  float sd = v.x * v.x + v.y * v.y;
#pragma unroll
  for (int o = 32; o; o >>= 1) sd += __shfl_xor(sd, o);
  int w = t >> 6;
  if ((t & 63) == 0) red[w] = sd;
  __syncthreads();
  int j = t >> 4, p = t & 15;
  const float* arow = aW + ((size_t)b * A_ + j * 64 + c) * D_;
  float partial = 0.f;
#pragma unroll 8
  for (int kk = 0; kk < 32; ++kk) {
    int k = p * 32 + ((kk + p * 2) & 31);
    partial += hrow[k] * arow[k];
  }
#pragma unroll
  for (int o = 8; o; o >>= 1) partial += __shfl_xor(partial, o);
  if (p == 0) wts[j] = partial * INV_SD;
  if (t == 0) wts[16] = ((red[0] + red[1]) + (red[2] + red[3])) * INV_SD;
  __syncthreads();
  if (t < 64) {
    float val = (t < 17) ? wts[t] : -3.0e38f;
    float m = val;
#pragma unroll
    for (int o = 32; o; o >>= 1) m = fmaxf(m, __shfl_xor(m, o));
    float e = (t < 17) ? __expf(val - m) : 0.f;
    float ssum = e;
#pragma unroll
    for (int o = 32; o; o >>= 1) ssum += __shfl_xor(ssum, o);
    if (t < 17) wts[t] = e / ssum;
  }
  __syncthreads();
  float* orow = hl2 + (size_t)blk * D_;
#pragma unroll
  for (int dd = 0; dd < 2; ++dd) {
    int d = t + dd * 256;
    float acc = wts[16] * hrow[d];
#pragma unroll 4
    for (int jj = 0; jj < 16; ++jj)
      acc += wts[jj] * aW[((size_t)b * A_ + jj * 64 + c) * D_ + d];
    orow[d] = acc;
  }
}

extern "C" void kernel_launch(void* const* d_in, const int* in_sizes, int n_in,
                              void* d_out, int out_size, void* d_ws, size_t ws_size,
                              hipStream_t stream) {
  const float* att_vf = (const float*)d_in[0];
  const float* W1_h2h = (const float*)d_in[4];
  const float* W1_h2a = (const float*)d_in[5];
  const float* ln11w = (const float*)d_in[6];
  const float* ln11b = (const float*)d_in[7];
  const float* ln12w = (const float*)d_in[8];
  const float* ln12b = (const float*)d_in[9];
  const float* ln13w = (const float*)d_in[10];
  const float* ln13b = (const float*)d_in[11];
  const float* W2_a2h = (const float*)d_in[12];
  const float* W2_h2h = (const float*)d_in[13];
  const float* W2_h2a = (const float*)d_in[14];
  const float* ln21w = (const float*)d_in[15];
  const float* ln21b = (const float*)d_in[16];
  const float* ln22w = (const float*)d_in[17];
  const float* ln22b = (const float*)d_in[18];
  const float* ln23w = (const float*)d_in[19];
  const float* ln23b = (const float*)d_in[20];
  float* out = (float*)d_out;

  float* ws = (float*)d_ws;
  const size_t SMALL = (size_t)B_ * C_ * D_;  // 2097152 floats
  float* stats = ws;                          // 2*B*A floats
  float* A0 = ws + 2 * B_ * A_;
  float* A1 = A0 + SMALL;
  float* A2 = A1 + SMALL;
  float* A3 = A2 + SMALL;
  bf16_t* A1b = (bf16_t*)(A3 + SMALL);             // B*C*D bf16 = SMALL/2 floats
  bf16_t* Wt0 = (bf16_t*)((float*)A1b + SMALL / 2);  // 5 x 512*512 bf16
  const size_t WTF = (size_t)512 * 512 / 2;          // floats per Wt
  bf16_t* Wt_h2h1 = Wt0;
  bf16_t* Wt_h2a1 = (bf16_t*)((float*)Wt0 + WTF);
  bf16_t* Wt_a2h = (bf16_t*)((float*)Wt0 + 2 * WTF);
  bf16_t* Wt_h2h2 = (bf16_t*)((float*)Wt0 + 3 * WTF);
  bf16_t* Wt_h2a2 = (bf16_t*)((float*)Wt0 + 4 * WTF);
  float* chunk0 = (float*)Wt0 + 5 * WTF;

  size_t base_floats = (size_t)(chunk0 - ws);
  size_t ws_floats = ws_size / 4;
  // per-batch: aW f32 (A*D floats) + Abf bf16 (A*D/2 floats)
  const size_t PERB = (size_t)A_ * D_ + (size_t)A_ * D_ / 2;
  int CB = 1;
  if (ws_floats > base_floats) {
    size_t cap = (ws_floats - base_floats) / PERB;
    CB = (int)(cap > 64 ? 64 : (cap < 1 ? 1 : cap));
  }
  int cb = 1;
  while (cb * 2 <= CB && cb * 2 <= 64) cb *= 2;
  CB = cb;
  int nchunks = B_ / CB;
  float* aW = chunk0;                                    // CB*A*D f32
  bf16_t* Abf = (bf16_t*)(aW + (size_t)CB * A_ * D_);    // CB*A*D bf16

  dim3 blk(256);
  // weight prep
  k_wt<<<dim3(8, 8), blk, 0, stream>>>(W1_h2h, Wt_h2h1);
  k_wt<<<dim3(8, 8), blk, 0, stream>>>(W1_h2a, Wt_h2a1);
  k_wt<<<dim3(8, 8), blk, 0, stream>>>(W2_a2h, Wt_a2h);
  k_wt<<<dim3(8, 8), blk, 0, stream>>>(W2_h2h, Wt_h2h2);
  k_wt<<<dim3(8, 8), blk, 0, stream>>>(W2_h2a, Wt_h2a2);

  // ---- layer 1 ----
  k_rowstats<<<B_ * A_, blk, 0, stream>>>(att_vf, stats);
  k_avg_hl<<<B_ * C_, blk, 0, stream>>>(att_vf, stats, ln11w, ln11b, A0);  // hl
  // h2h #1
  k_ln<<<B_ * C_, blk, 0, stream>>>(A0, ln12w, ln12b, A1, A1b);
  k_mfma_gemm<64><<<dim3(4, 64), blk, 0, stream>>>(A1b, Wt_h2h1, A2);
  k_h2h_attn<<<B_ * C_, blk, 0, stream>>>(A2, A1, A3);  // hl1 = A3
  // h2a #1 -> att1 in d_out
  k_ln<<<B_ * C_, blk, 0, stream>>>(A3, ln13w, ln13b, A1, A1b);
  k_mfma_gemm<64><<<dim3(4, 64), blk, 0, stream>>>(A1b, Wt_h2a1, A2);
  k_h2a<<<B_ * A_, blk, 0, stream>>>(att_vf, A2, out);
  // ---- layer 2: a2h attention (chunked over batches) ----
  for (int ch = 0; ch < nchunks; ++ch) {
    size_t b0 = (size_t)ch * CB;
    k_lnb<<<CB * A_, blk, 0, stream>>>(out + b0 * A_ * D_, ln21w, ln21b, Abf);
    k_mfma_gemm<128><<<dim3(4, CB * 8), blk, 0, stream>>>(Abf, Wt_a2h, aW);
    k_a2h_attn<<<CB * C_, blk, 0, stream>>>(A3 + b0 * C_ * D_, aW, A0 + b0 * C_ * D_);
  }
  // h2h #2
  k_ln<<<B_ * C_, blk, 0, stream>>>(A0, ln22w, ln22b, A1, A1b);
  k_mfma_gemm<64><<<dim3(4, 64), blk, 0, stream>>>(A1b, Wt_h2h2, A2);
  k_h2h_attn<<<B_ * C_, blk, 0, stream>>>(A2, A1, A0);
  // h2a #2 -> att2 in d_out
  k_ln<<<B_ * C_, blk, 0, stream>>>(A0, ln23w, ln23b, A1, A1b);
  k_mfma_gemm<64><<<dim3(4, 64), blk, 0, stream>>>(A1b, Wt_h2a2, A2);
  k_h2a<<<B_ * A_, blk, 0, stream>>>(out, A2, out);
}

// Round 3
// 530.709 us; speedup vs baseline: 3.1706x; 2.1838x over previous
//
#include <hip/hip_runtime.h>

#define B_ 64
#define A_ 1024
#define C_ 64
#define D_ 512
#define INV_SD 0.044194173824159216f

typedef __bf16 bf16_t;
typedef __bf16 bf16x8 __attribute__((ext_vector_type(8)));
typedef __bf16 bf16x2 __attribute__((ext_vector_type(2)));
typedef float f32x4 __attribute__((ext_vector_type(4)));

static __device__ __forceinline__ bf16_t f2b(float x) { return (bf16_t)x; }
static __device__ __forceinline__ float b2f(bf16_t x) { return (float)x; }

// ---------------- row stats over D=512, wave-per-row ----------------
__global__ __launch_bounds__(256) void k_rowstats(const float* __restrict__ x,
                                                  float* __restrict__ stats) {
  int t = threadIdx.x;
  int row = blockIdx.x * 4 + (t >> 6);
  int lane = t & 63;
  const float* xr = x + (size_t)row * D_ + lane * 8;
  float4 v1 = *(const float4*)xr;
  float4 v2 = *(const float4*)(xr + 4);
  float s = (v1.x + v1.y + v1.z + v1.w) + (v2.x + v2.y + v2.z + v2.w);
  float q = v1.x * v1.x + v1.y * v1.y + v1.z * v1.z + v1.w * v1.w +
            v2.x * v2.x + v2.y * v2.y + v2.z * v2.z + v2.w * v2.w;
#pragma unroll
  for (int o = 32; o; o >>= 1) { s += __shfl_xor(s, o); q += __shfl_xor(q, o); }
  if (lane == 0) {
    float mu = s * (1.0f / D_);
    stats[2 * row] = mu;
    stats[2 * row + 1] = rsqrtf(q * (1.0f / D_) - mu * mu + 1e-5f);
  }
}

// ---------------- LN row -> bf16, wave-per-row ----------------
__global__ __launch_bounds__(256) void k_lnb(const float* __restrict__ x,
                                             const float* __restrict__ lw,
                                             const float* __restrict__ lb,
                                             bf16_t* __restrict__ yb) {
  int t = threadIdx.x;
  int row = blockIdx.x * 4 + (t >> 6);
  int lane = t & 63;
  int d0 = lane * 8;
  const float* xr = x + (size_t)row * D_ + d0;
  float4 v1 = *(const float4*)xr;
  float4 v2 = *(const float4*)(xr + 4);
  float s = (v1.x + v1.y + v1.z + v1.w) + (v2.x + v2.y + v2.z + v2.w);
  float q = v1.x * v1.x + v1.y * v1.y + v1.z * v1.z + v1.w * v1.w +
            v2.x * v2.x + v2.y * v2.y + v2.z * v2.z + v2.w * v2.w;
#pragma unroll
  for (int o = 32; o; o >>= 1) { s += __shfl_xor(s, o); q += __shfl_xor(q, o); }
  float mu = s * (1.0f / D_);
  float rs = rsqrtf(q * (1.0f / D_) - mu * mu + 1e-5f);
  float4 w1 = *(const float4*)(lw + d0);
  float4 w2 = *(const float4*)(lw + d0 + 4);
  float4 b1 = *(const float4*)(lb + d0);
  float4 b2 = *(const float4*)(lb + d0 + 4);
  bf16x8 ob;
  ob[0] = f2b((v1.x - mu) * rs * w1.x + b1.x);
  ob[1] = f2b((v1.y - mu) * rs * w1.y + b1.y);
  ob[2] = f2b((v1.z - mu) * rs * w1.z + b1.z);
  ob[3] = f2b((v1.w - mu) * rs * w1.w + b1.w);
  ob[4] = f2b((v2.x - mu) * rs * w2.x + b2.x);
  ob[5] = f2b((v2.y - mu) * rs * w2.y + b2.y);
  ob[6] = f2b((v2.z - mu) * rs * w2.z + b2.z);
  ob[7] = f2b((v2.w - mu) * rs * w2.w + b2.w);
  *(bf16x8*)(yb + (size_t)row * D_ + d0) = ob;
}

// ---------------- transpose hln bf16 [64][512] -> hlnT [512][64] per batch ----------------
__global__ __launch_bounds__(256) void k_tr(const bf16_t* __restrict__ src,
                                            bf16_t* __restrict__ dst) {
  __shared__ unsigned short sm[64][72];
  int n0 = blockIdx.x;  // 0..7 (d-block of 64)
  int b = blockIdx.y;
  int t = threadIdx.x;
  const bf16_t* sb = src + (size_t)b * C_ * D_;
  bf16_t* db = dst + (size_t)b * D_ * C_;
#pragma unroll
  for (int rep = 0; rep < 2; ++rep) {
    int f = t + rep * 256;       // 0..511
    int c = f >> 3, c8 = f & 7;  // row c, 16B chunk
    ushort4 v = *(const ushort4*)(sb + (size_t)c * D_ + n0 * 64 + c8 * 8);
    unsigned short* p = &sm[c][c8 * 8];
    p[0] = v.x & 0xffff; p[1] = v.x >> 16;
    // ushort4 holds 8 ushorts? no — use uint4 instead below
    (void)p;
  }
  // redo with uint4 for clarity
  __syncthreads();
#pragma unroll
  for (int rep = 0; rep < 2; ++rep) {
    int f = t + rep * 256;
    int c = f >> 3, c8 = f & 7;
    uint4 v = *(const uint4*)(sb + (size_t)c * D_ + n0 * 64 + c8 * 8);
    unsigned int* p = (unsigned int*)&sm[c][c8 * 8];
    p[0] = v.x; p[1] = v.y; p[2] = v.z; p[3] = v.w;
  }
  __syncthreads();
#pragma unroll
  for (int rep = 0; rep < 2; ++rep) {
    int f = t + rep * 256;
    int nr = f >> 3, c8 = f & 7;
    unsigned short tmp[8];
#pragma unroll
    for (int u = 0; u < 8; ++u) tmp[u] = sm[c8 * 8 + u][nr];
    *(uint4*)(db + (size_t)(n0 * 64 + nr) * 64 + c8 * 8) = *(const uint4*)tmp;
  }
}

// ---------------- hl[b,c,d] = (1/16) * sum_j LN(att_vf[b, j*64+c, :])[d] ----------------
__global__ __launch_bounds__(256) void k_avg_hl(const float* __restrict__ att,
                                                const float* __restrict__ stats,
                                                const float* __restrict__ lw,
                                                const float* __restrict__ lb,
                                                float* __restrict__ hl) {
  int blk = blockIdx.x;  // B*C
  int b = blk >> 6, c = blk & 63;
  int t = threadIdx.x;
  int d = 2 * t;
  float ax = 0.f, ay = 0.f;
#pragma unroll 4
  for (int jj = 0; jj < 16; ++jj) {
    size_t ridx = (size_t)b * A_ + jj * 64 + c;
    float mu = stats[2 * ridx], rs = stats[2 * ridx + 1];
    float2 v = *(const float2*)(att + ridx * D_ + d);
    ax += (v.x - mu) * rs;
    ay += (v.y - mu) * rs;
  }
  float2 o2;
  o2.x = ax * (1.f / 16.f) * lw[d] + lb[d];
  o2.y = ay * (1.f / 16.f) * lw[d + 1] + lb[d + 1];
  *(float2*)(hl + (size_t)blk * D_ + d) = o2;
}

// ---------------- transpose + convert W[k][n] f32 -> Wt[n][k] bf16 ----------------
__global__ __launch_bounds__(256) void k_wt(const float* __restrict__ W,
                                            bf16_t* __restrict__ Wt) {
  __shared__ float tile[64][65];
  int k0 = blockIdx.x * 64;
  int n0 = blockIdx.y * 64;
  int t = threadIdx.x;
  int r0 = t >> 6;
  int c = t & 63;
#pragma unroll 4
  for (int i = 0; i < 16; ++i) {
    int r = r0 * 16 + i;
    tile[r][c] = W[(size_t)(k0 + r) * 512 + n0 + c];
  }
  __syncthreads();
#pragma unroll 4
  for (int i = 0; i < 16; ++i) {
    int r = r0 * 16 + i;
    Wt[(size_t)(n0 + r) * 512 + k0 + c] = f2b(tile[c][r]);
  }
}

// ---------------- MFMA GEMM: Cb[M,512] bf16 = Abf[M,512] bf16 @ Wt^T ----------------
template <int BM>
__global__ __launch_bounds__(256) void k_mfma_gemm(const bf16_t* __restrict__ Abf,
                                                   const bf16_t* __restrict__ Wt,
                                                   bf16_t* __restrict__ Cmat) {
  constexpr int TR = BM / 32;
  constexpr int NA = BM / 32;
  __shared__ bf16_t As[BM * 64];
  __shared__ bf16_t Bs[128 * 64];

  int t = threadIdx.x;
  int lane = t & 63, wave = t >> 6;
  int wr = wave >> 1, wc = wave & 1;
  int lhi = lane >> 4, llo = lane & 15;
  int bn = blockIdx.x;
  int bm = blockIdx.y;

  const bf16_t* Ab = Abf + (size_t)bm * BM * 512;
  const bf16_t* Wb = Wt + (size_t)bn * 128 * 512;

  f32x4 acc[TR][4] = {};
  uint4 areg[NA], breg[4];
  int cc = t & 7;
  int rr = t >> 3;

  auto issue = [&](int k0) {
#pragma unroll
    for (int i = 0; i < NA; ++i)
      areg[i] = *(const uint4*)(Ab + (size_t)(rr + i * 32) * 512 + k0 + cc * 8);
#pragma unroll
    for (int i = 0; i < 4; ++i)
      breg[i] = *(const uint4*)(Wb + (size_t)(rr + i * 32) * 512 + k0 + cc * 8);
  };
  auto store_lds = [&] {
#pragma unroll
    for (int i = 0; i < NA; ++i) {
      int r = rr + i * 32;
      *(uint4*)((char*)As + r * 128 + ((cc * 16) ^ ((r & 7) << 4))) = areg[i];
    }
#pragma unroll
    for (int i = 0; i < 4; ++i) {
      int r = rr + i * 32;
      *(uint4*)((char*)Bs + r * 128 + ((cc * 16) ^ ((r & 7) << 4))) = breg[i];
    }
  };

  issue(0);
  store_lds();
  __syncthreads();

  for (int k0 = 0; k0 < 512; k0 += 64) {
    bool last = (k0 + 64 >= 512);
    if (!last) issue(k0 + 64);
    bf16x8 af[TR][2], bfr[4][2];
#pragma unroll
    for (int kk = 0; kk < 2; ++kk) {
      int bofs = kk * 64 + lhi * 16;
#pragma unroll
      for (int tr = 0; tr < TR; ++tr) {
        int row = wr * (BM / 2) + tr * 16 + llo;
        af[tr][kk] = *(const bf16x8*)((const char*)As + row * 128 + (bofs ^ ((row & 7) << 4)));
      }
#pragma unroll
      for (int tc = 0; tc < 4; ++tc) {
        int col = wc * 64 + tc * 16 + llo;
        bfr[tc][kk] = *(const bf16x8*)((const char*)Bs + col * 128 + (bofs ^ ((col & 7) << 4)));
      }
    }
#pragma unroll
    for (int kk = 0; kk < 2; ++kk)
#pragma unroll
      for (int tr = 0; tr < TR; ++tr)
#pragma unroll
        for (int tc = 0; tc < 4; ++tc)
          acc[tr][tc] = __builtin_amdgcn_mfma_f32_16x16x32_bf16(
              af[tr][kk], bfr[tc][kk], acc[tr][tc], 0, 0, 0);
    __syncthreads();
    if (!last) {
      store_lds();
      __syncthreads();
    }
  }

  bf16_t* Cb = Cmat + (size_t)bm * BM * 512 + bn * 128 + wc * 64;
#pragma unroll
  for (int tr = 0; tr < TR; ++tr) {
    int row = wr * (BM / 2) + tr * 16 + lhi * 4;
#pragma unroll
    for (int r = 0; r < 4; ++r)
#pragma unroll
      for (int tc = 0; tc < 4; ++tc)
        Cb[(size_t)(row + r) * 512 + tc * 16 + llo] = f2b(acc[tr][tc][r]);
  }
}

// ---------------- fused h2h: gram(MFMA) + softmax + PV(MFMA) ----------------
// hide bf16 [B][64][512]; hlnT bf16 [B][512][64]; out f32 [B][64][512]
__global__ __launch_bounds__(256) void k_h2h(const bf16_t* __restrict__ hide,
                                             const bf16_t* __restrict__ hlnT,
                                             float* __restrict__ outp) {
  __shared__ bf16_t hS[8 * 64 * 64];  // [kc][row][64k] swizzled, 64 KB
  __shared__ float sS[16][68];
  __shared__ bf16_t wS[16 * 64];      // [i][j] 128B rows swizzled

  int q = blockIdx.x;  // row quarter 0..3
  int b = blockIdx.y;
  int t = threadIdx.x;
  int lane = t & 63, wave = t >> 6;
  int lhi = lane >> 4, llo = lane & 15;

  const bf16_t* Hb = hide + (size_t)b * C_ * D_;
  // stage hide_b: 4096 uint4
#pragma unroll
  for (int rep = 0; rep < 16; ++rep) {
    int f = t + rep * 256;
    int row = f >> 6, c16 = f & 63;
    int kc = c16 >> 3, ci = c16 & 7;
    uint4 v = *(const uint4*)(Hb + (size_t)row * 512 + c16 * 8);
    *(uint4*)((char*)hS + kc * 8192 + row * 128 + ((ci * 16) ^ ((row & 7) << 4))) = v;
  }
  __syncthreads();

  // gram: wave computes S[16 rows (q)][16 cols (wave)]
  {
    f32x4 acc = {};
#pragma unroll
    for (int ks = 0; ks < 16; ++ks) {
      int kc = ks >> 1;
      int bofs = (ks & 1) * 64 + lhi * 16;
      int ra = q * 16 + llo;
      int rb = wave * 16 + llo;
      bf16x8 af = *(const bf16x8*)((const char*)hS + kc * 8192 + ra * 128 + (bofs ^ ((ra & 7) << 4)));
      bf16x8 bf = *(const bf16x8*)((const char*)hS + kc * 8192 + rb * 128 + (bofs ^ ((rb & 7) << 4)));
      acc = __builtin_amdgcn_mfma_f32_16x16x32_bf16(af, bf, acc, 0, 0, 0);
    }
#pragma unroll
    for (int r = 0; r < 4; ++r) sS[lhi * 4 + r][wave * 16 + llo] = acc[r] * INV_SD;
  }
  __syncthreads();

  // softmax over 64 cols per row; 8 threads/row
  if (t < 128) {
    int row = t >> 3, sg = t & 7;
    float v[8];
#pragma unroll
    for (int u = 0; u < 8; ++u) v[u] = sS[row][sg * 8 + u];
    float m = v[0];
#pragma unroll
    for (int u = 1; u < 8; ++u) m = fmaxf(m, v[u]);
#pragma unroll
    for (int o = 4; o; o >>= 1) m = fmaxf(m, __shfl_xor(m, o));
    float sum = 0.f;
#pragma unroll
    for (int u = 0; u < 8; ++u) { v[u] = __expf(v[u] - m); sum += v[u]; }
#pragma unroll
    for (int o = 4; o; o >>= 1) sum += __shfl_xor(sum, o);
    float inv = 1.f / sum;
    bf16x8 wv;
#pragma unroll
    for (int u = 0; u < 8; ++u) wv[u] = f2b(v[u] * inv);
    *(bf16x8*)((char*)wS + row * 128 + ((sg * 16) ^ ((row & 7) << 4))) = wv;
  }
  __syncthreads();

  // PV: out[16 rows][512] ; wave covers d-range wave*128
  {
    bf16x8 af[2];
#pragma unroll
    for (int ks = 0; ks < 2; ++ks)
      af[ks] = *(const bf16x8*)((const char*)wS + llo * 128 + (((ks * 64 + lhi * 16)) ^ ((llo & 7) << 4)));
    const bf16_t* Tb = hlnT + (size_t)b * D_ * C_;
    f32x4 acc[8] = {};
#pragma unroll
    for (int nt = 0; nt < 8; ++nt) {
      int drow = wave * 128 + nt * 16 + llo;
#pragma unroll
      for (int ks = 0; ks < 2; ++ks) {
        bf16x8 bf = *(const bf16x8*)(Tb + (size_t)drow * 64 + ks * 32 + lhi * 8);
        acc[nt] = __builtin_amdgcn_mfma_f32_16x16x32_bf16(af[ks], bf, acc[nt], 0, 0, 0);
      }
    }
    float* Ob = outp + (size_t)b * C_ * D_;
#pragma unroll
    for (int nt = 0; nt < 8; ++nt) {
      int dcol = wave * 128 + nt * 16 + llo;
#pragma unroll
      for (int r = 0; r < 4; ++r)
        Ob[(size_t)(q * 16 + lhi * 4 + r) * 512 + dcol] = acc[nt][r];
    }
  }
}

// ---------------- h2a: wave-per-row, 2-way softmax {hW[b,a%C], att[b,a]} ----------------
__global__ __launch_bounds__(256) void k_h2a(const float* __restrict__ att,
                                             const bf16_t* __restrict__ hW,
                                             float* __restrict__ outp) {
  int t = threadIdx.x;
  int row = blockIdx.x * 4 + (t >> 6);  // b*A + a
  int lane = t & 63;
  int b = row >> 10, a = row & 1023;
  int c = a & 63;
  int d0 = lane * 8;
  const float* ar = att + (size_t)row * D_ + d0;
  const bf16_t* wr = hW + (size_t)(b * 64 + c) * D_ + d0;
  float4 a1 = *(const float4*)ar;
  float4 a2 = *(const float4*)(ar + 4);
  bf16x8 wb = *(const bf16x8*)wr;
  float w[8];
#pragma unroll
  for (int u = 0; u < 8; ++u) w[u] = b2f(wb[u]);
  float av[8] = {a1.x, a1.y, a1.z, a1.w, a2.x, a2.y, a2.z, a2.w};
  float d1 = 0.f, d2 = 0.f;
#pragma unroll
  for (int u = 0; u < 8; ++u) { d1 += av[u] * w[u]; d2 += av[u] * av[u]; }
#pragma unroll
  for (int o = 32; o; o >>= 1) { d1 += __shfl_xor(d1, o); d2 += __shfl_xor(d2, o); }
  float s1 = d1 * INV_SD, s2 = d2 * INV_SD;
  float m = fmaxf(s1, s2);
  float e1 = __expf(s1 - m), e2 = __expf(s2 - m);
  float inv = 1.f / (e1 + e2);
  float alpha = e1 * inv, beta = e2 * inv;
  float4 o1, o2;
  o1.x = alpha * w[0] + beta * av[0]; o1.y = alpha * w[1] + beta * av[1];
  o1.z = alpha * w[2] + beta * av[2]; o1.w = alpha * w[3] + beta * av[3];
  o2.x = alpha * w[4] + beta * av[4]; o2.y = alpha * w[5] + beta * av[5];
  o2.z = alpha * w[6] + beta * av[6]; o2.w = alpha * w[7] + beta * av[7];
  float* orow = outp + (size_t)row * D_ + d0;
  *(float4*)orow = o1;
  *(float4*)(orow + 4) = o2;
}

// ---------------- layer2 a2h attention: 17-way softmax, aW bf16 ----------------
__global__ __launch_bounds__(256) void k_a2h_attn(const float* __restrict__ hl1,
                                                  const bf16_t* __restrict__ aW,
                                                  float* __restrict__ hl2) {
  int blk = blockIdx.x;  // CB*C
  int b = blk >> 6, c = blk & 63;
  int t = threadIdx.x;
  __shared__ float hrow[D_];
  __shared__ float wts[32];
  __shared__ float red[4];
  const float* hr = hl1 + (size_t)blk * D_;
  float2 v = *(const float2*)(hr + 2 * t);
  hrow[2 * t] = v.x;
  hrow[2 * t + 1] = v.y;
  float sd = v.x * v.x + v.y * v.y;
#pragma unroll
  for (int o = 32; o; o >>= 1) sd += __shfl_xor(sd, o);
  int w = t >> 6;
  if ((t & 63) == 0) red[w] = sd;
  __syncthreads();
  int j = t >> 4, p = t & 15;
  const bf16_t* arow = aW + ((size_t)b * A_ + j * 64 + c) * D_;
  float partial = 0.f;
#pragma unroll
  for (int kk = 0; kk < 16; ++kk) {
    int k = p * 32 + 2 * ((kk + p) & 15);  // stagger, 4B aligned
    bf16x2 a2 = *(const bf16x2*)(arow + k);
    partial += hrow[k] * b2f(a2.x) + hrow[k + 1] * b2f(a2.y);
  }
#pragma unroll
  for (int o = 8; o; o >>= 1) partial += __shfl_xor(partial, o);
  if (p == 0) wts[j] = partial * INV_SD;
  if (t == 0) wts[16] = ((red[0] + red[1]) + (red[2] + red[3])) * INV_SD;
  __syncthreads();
  if (t < 64) {
    float val = (t < 17) ? wts[t] : -3.0e38f;
    float m = val;
#pragma unroll
    for (int o = 32; o; o >>= 1) m = fmaxf(m, __shfl_xor(m, o));
    float e = (t < 17) ? __expf(val - m) : 0.f;
    float ssum = e;
#pragma unroll
    for (int o = 32; o; o >>= 1) ssum += __shfl_xor(ssum, o);
    if (t < 17) wts[t] = e / ssum;
  }
  __syncthreads();
  float* orow = hl2 + (size_t)blk * D_;
  int d = 2 * t;
  float accx = wts[16] * hrow[d];
  float accy = wts[16] * hrow[d + 1];
#pragma unroll 4
  for (int jj = 0; jj < 16; ++jj) {
    bf16x2 a2 = *(const bf16x2*)(aW + ((size_t)b * A_ + jj * 64 + c) * D_ + d);
    accx += wts[jj] * b2f(a2.x);
    accy += wts[jj] * b2f(a2.y);
  }
  float2 o2 = {accx, accy};
  *(float2*)(orow + d) = o2;
}

extern "C" void kernel_launch(void* const* d_in, const int* in_sizes, int n_in,
                              void* d_out, int out_size, void* d_ws, size_t ws_size,
                              hipStream_t stream) {
  const float* att_vf = (const float*)d_in[0];
  const float* W1_h2h = (const float*)d_in[4];
  const float* W1_h2a = (const float*)d_in[5];
  const float* ln11w = (const float*)d_in[6];
  const float* ln11b = (const float*)d_in[7];
  const float* ln12w = (const float*)d_in[8];
  const float* ln12b = (const float*)d_in[9];
  const float* ln13w = (const float*)d_in[10];
  const float* ln13b = (const float*)d_in[11];
  const float* W2_a2h = (const float*)d_in[12];
  const float* W2_h2h = (const float*)d_in[13];
  const float* W2_h2a = (const float*)d_in[14];
  const float* ln21w = (const float*)d_in[15];
  const float* ln21b = (const float*)d_in[16];
  const float* ln22w = (const float*)d_in[17];
  const float* ln22b = (const float*)d_in[18];
  const float* ln23w = (const float*)d_in[19];
  const float* ln23b = (const float*)d_in[20];
  float* out = (float*)d_out;

  float* ws = (float*)d_ws;
  const size_t SMALL = (size_t)B_ * C_ * D_;  // 2097152
  float* stats = ws;                           // 2*B*A
  float* A0 = ws + 2 * B_ * A_;                // hl / hl2 (f32)
  float* A3 = A0 + SMALL;                      // hl1 / hl2' (f32)
  bf16_t* A1b = (bf16_t*)(A3 + SMALL);         // hln bf16
  bf16_t* A1t = (bf16_t*)((float*)A1b + SMALL / 2);  // hlnT bf16
  bf16_t* A2b = (bf16_t*)((float*)A1t + SMALL / 2);  // hide / hW bf16
  bf16_t* Wt0 = (bf16_t*)((float*)A2b + SMALL / 2);
  const size_t WTF = (size_t)512 * 512 / 2;
  bf16_t* Wt_h2h1 = Wt0;
  bf16_t* Wt_h2a1 = (bf16_t*)((float*)Wt0 + WTF);
  bf16_t* Wt_a2h = (bf16_t*)((float*)Wt0 + 2 * WTF);
  bf16_t* Wt_h2h2 = (bf16_t*)((float*)Wt0 + 3 * WTF);
  bf16_t* Wt_h2a2 = (bf16_t*)((float*)Wt0 + 4 * WTF);
  float* chunk0 = (float*)Wt0 + 5 * WTF;

  size_t base_floats = (size_t)(chunk0 - ws);
  size_t ws_floats = ws_size / 4;
  // per-batch: Abf bf16 (A*D/2 fl) + aWb bf16 (A*D/2 fl)
  const size_t PERB = (size_t)A_ * D_;
  int CB = 1;
  if (ws_floats > base_floats) {
    size_t cap = (ws_floats - base_floats) / PERB;
    CB = (int)(cap > 64 ? 64 : (cap < 1 ? 1 : cap));
  }
  int cb = 1;
  while (cb * 2 <= CB && cb * 2 <= 64) cb *= 2;
  CB = cb;
  int nchunks = B_ / CB;
  bf16_t* Abf = (bf16_t*)chunk0;
  bf16_t* aWb = (bf16_t*)(chunk0 + (size_t)CB * A_ * D_ / 2);

  dim3 blk(256);
  // weight prep
  k_wt<<<dim3(8, 8), blk, 0, stream>>>(W1_h2h, Wt_h2h1);
  k_wt<<<dim3(8, 8), blk, 0, stream>>>(W1_h2a, Wt_h2a1);
  k_wt<<<dim3(8, 8), blk, 0, stream>>>(W2_a2h, Wt_a2h);
  k_wt<<<dim3(8, 8), blk, 0, stream>>>(W2_h2h, Wt_h2h2);
  k_wt<<<dim3(8, 8), blk, 0, stream>>>(W2_h2a, Wt_h2a2);

  // ---- layer 1 ----
  k_rowstats<<<(B_ * A_) / 4, blk, 0, stream>>>(att_vf, stats);
  k_avg_hl<<<B_ * C_, blk, 0, stream>>>(att_vf, stats, ln11w, ln11b, A0);  // hl
  // h2h #1 -> hl1 = A3
  k_lnb<<<(B_ * C_) / 4, blk, 0, stream>>>(A0, ln12w, ln12b, A1b);
  k_tr<<<dim3(8, B_), blk, 0, stream>>>(A1b, A1t);
  k_mfma_gemm<64><<<dim3(4, 64), blk, 0, stream>>>(A1b, Wt_h2h1, A2b);  // hide
  k_h2h<<<dim3(4, B_), blk, 0, stream>>>(A2b, A1t, A3);
  // h2a #1 -> att1 in d_out
  k_lnb<<<(B_ * C_) / 4, blk, 0, stream>>>(A3, ln13w, ln13b, A1b);
  k_mfma_gemm<64><<<dim3(4, 64), blk, 0, stream>>>(A1b, Wt_h2a1, A2b);  // hW
  k_h2a<<<(B_ * A_) / 4, blk, 0, stream>>>(att_vf, A2b, out);
  // ---- layer 2: a2h attention (chunked) ----
  for (int ch = 0; ch < nchunks; ++ch) {
    size_t b0 = (size_t)ch * CB;
    k_lnb<<<(CB * A_) / 4, blk, 0, stream>>>(out + b0 * A_ * D_, ln21w, ln21b, Abf);
    k_mfma_gemm<128><<<dim3(4, CB * 8), blk, 0, stream>>>(Abf, Wt_a2h, aWb);
    k_a2h_attn<<<CB * C_, blk, 0, stream>>>(A3 + b0 * C_ * D_, aWb, A0 + b0 * C_ * D_);
  }
  // h2h #2: hl2=A0 -> hl2'=A3
  k_lnb<<<(B_ * C_) / 4, blk, 0, stream>>>(A0, ln22w, ln22b, A1b);
  k_tr<<<dim3(8, B_), blk, 0, stream>>>(A1b, A1t);
  k_mfma_gemm<64><<<dim3(4, 64), blk, 0, stream>>>(A1b, Wt_h2h2, A2b);
  k_h2h<<<dim3(4, B_), blk, 0, stream>>>(A2b, A1t, A3);
  // h2a #2 -> att2 in d_out (in-place)
  k_lnb<<<(B_ * C_) / 4, blk, 0, stream>>>(A3, ln23w, ln23b, A1b);
  k_mfma_gemm<64><<<dim3(4, 64), blk, 0, stream>>>(A1b, Wt_h2a2, A2b);
  k_h2a<<<(B_ * A_) / 4, blk, 0, stream>>>(out, A2b, out);
}

// Round 4
// 529.103 us; speedup vs baseline: 3.1803x; 1.0030x over previous
//
#include <hip/hip_runtime.h>

#define B_ 64
#define A_ 1024
#define C_ 64
#define D_ 512
#define INV_SD 0.044194173824159216f

typedef __bf16 bf16_t;
typedef __bf16 bf16x8 __attribute__((ext_vector_type(8)));
typedef __bf16 bf16x2 __attribute__((ext_vector_type(2)));
typedef float f32x4 __attribute__((ext_vector_type(4)));

static __device__ __forceinline__ bf16_t f2b(float x) { return (bf16_t)x; }
static __device__ __forceinline__ float b2f(bf16_t x) { return (float)x; }

// ---- fused: per (b,c): stats+LN11 of 16 att rows, avg, LN12 -> hln bf16 ----
__global__ __launch_bounds__(256) void k_hl0(const float* __restrict__ att,
                                             const float* __restrict__ lw1,
                                             const float* __restrict__ lb1,
                                             const float* __restrict__ lw2,
                                             const float* __restrict__ lb2,
                                             bf16_t* __restrict__ hlnb) {
  int blk = blockIdx.x;  // B*C
  int b = blk >> 6, c = blk & 63;
  int t = threadIdx.x;
  int w = t >> 6, lane = t & 63;
  __shared__ float part[4][512];
  __shared__ float reds[8];
  float ps[8] = {0.f, 0.f, 0.f, 0.f, 0.f, 0.f, 0.f, 0.f};
#pragma unroll
  for (int i = 0; i < 4; ++i) {
    int jj = w * 4 + i;
    const float* xr = att + ((size_t)b * A_ + jj * 64 + c) * D_ + lane * 8;
    float4 v1 = *(const float4*)xr;
    float4 v2 = *(const float4*)(xr + 4);
    float v[8] = {v1.x, v1.y, v1.z, v1.w, v2.x, v2.y, v2.z, v2.w};
    float s = 0.f, q = 0.f;
#pragma unroll
    for (int u = 0; u < 8; ++u) { s += v[u]; q += v[u] * v[u]; }
#pragma unroll
    for (int o = 32; o; o >>= 1) { s += __shfl_xor(s, o); q += __shfl_xor(q, o); }
    float mu = s * (1.0f / D_);
    float rs = rsqrtf(q * (1.0f / D_) - mu * mu + 1e-5f);
#pragma unroll
    for (int u = 0; u < 8; ++u) ps[u] += (v[u] - mu) * rs;
  }
#pragma unroll
  for (int u = 0; u < 8; ++u) part[w][lane * 8 + u] = ps[u];
  __syncthreads();
  int d = 2 * t;
  float hx = ((part[0][d] + part[1][d]) + (part[2][d] + part[3][d])) * (1.f / 16.f) * lw1[d] + lb1[d];
  float hy = ((part[0][d + 1] + part[1][d + 1]) + (part[2][d + 1] + part[3][d + 1])) * (1.f / 16.f) * lw1[d + 1] + lb1[d + 1];
  float s = hx + hy, q = hx * hx + hy * hy;
#pragma unroll
  for (int o = 32; o; o >>= 1) { s += __shfl_xor(s, o); q += __shfl_xor(q, o); }
  if (lane == 0) { reds[w] = s; reds[4 + w] = q; }
  __syncthreads();
  float S = (reds[0] + reds[1]) + (reds[2] + reds[3]);
  float Q = (reds[4] + reds[5]) + (reds[6] + reds[7]);
  float mu = S * (1.0f / D_);
  float rs = rsqrtf(Q * (1.0f / D_) - mu * mu + 1e-5f);
  bf16x2 ob;
  ob.x = f2b((hx - mu) * rs * lw2[d] + lb2[d]);
  ob.y = f2b((hy - mu) * rs * lw2[d + 1] + lb2[d + 1]);
  *(bf16x2*)(hlnb + (size_t)blk * D_ + d) = ob;
}

// ---------------- LN row f32 -> bf16, wave-per-row ----------------
__global__ __launch_bounds__(256) void k_lnb(const float* __restrict__ x,
                                             const float* __restrict__ lw,
                                             const float* __restrict__ lb,
                                             bf16_t* __restrict__ yb) {
  int t = threadIdx.x;
  int row = blockIdx.x * 4 + (t >> 6);
  int lane = t & 63;
  int d0 = lane * 8;
  const float* xr = x + (size_t)row * D_ + d0;
  float4 v1 = *(const float4*)xr;
  float4 v2 = *(const float4*)(xr + 4);
  float s = (v1.x + v1.y + v1.z + v1.w) + (v2.x + v2.y + v2.z + v2.w);
  float q = v1.x * v1.x + v1.y * v1.y + v1.z * v1.z + v1.w * v1.w +
            v2.x * v2.x + v2.y * v2.y + v2.z * v2.z + v2.w * v2.w;
#pragma unroll
  for (int o = 32; o; o >>= 1) { s += __shfl_xor(s, o); q += __shfl_xor(q, o); }
  float mu = s * (1.0f / D_);
  float rs = rsqrtf(q * (1.0f / D_) - mu * mu + 1e-5f);
  float4 w1 = *(const float4*)(lw + d0);
  float4 w2 = *(const float4*)(lw + d0 + 4);
  float4 b1 = *(const float4*)(lb + d0);
  float4 b2 = *(const float4*)(lb + d0 + 4);
  bf16x8 ob;
  ob[0] = f2b((v1.x - mu) * rs * w1.x + b1.x);
  ob[1] = f2b((v1.y - mu) * rs * w1.y + b1.y);
  ob[2] = f2b((v1.z - mu) * rs * w1.z + b1.z);
  ob[3] = f2b((v1.w - mu) * rs * w1.w + b1.w);
  ob[4] = f2b((v2.x - mu) * rs * w2.x + b2.x);
  ob[5] = f2b((v2.y - mu) * rs * w2.y + b2.y);
  ob[6] = f2b((v2.z - mu) * rs * w2.z + b2.z);
  ob[7] = f2b((v2.w - mu) * rs * w2.w + b2.w);
  *(bf16x8*)(yb + (size_t)row * D_ + d0) = ob;
}

// ---------------- transpose hln bf16 [64][512] -> hlnT [512][64] per batch ----------------
__global__ __launch_bounds__(256) void k_tr(const bf16_t* __restrict__ src,
                                            bf16_t* __restrict__ dst) {
  __shared__ unsigned short sm[64][72];
  int n0 = blockIdx.x;  // 0..7
  int b = blockIdx.y;
  int t = threadIdx.x;
  const bf16_t* sb = src + (size_t)b * C_ * D_;
  bf16_t* db = dst + (size_t)b * D_ * C_;
#pragma unroll
  for (int rep = 0; rep < 2; ++rep) {
    int f = t + rep * 256;
    int r = f >> 3, c8 = f & 7;
    uint4 v = *(const uint4*)(sb + (size_t)r * D_ + n0 * 64 + c8 * 8);
    unsigned int* p = (unsigned int*)&sm[r][c8 * 8];
    p[0] = v.x; p[1] = v.y; p[2] = v.z; p[3] = v.w;
  }
  __syncthreads();
#pragma unroll
  for (int rep = 0; rep < 2; ++rep) {
    int f = t + rep * 256;
    int nr = f >> 3, c8 = f & 7;
    unsigned short tmp[8];
#pragma unroll
    for (int u = 0; u < 8; ++u) tmp[u] = sm[c8 * 8 + u][nr];
    *(uint4*)(db + (size_t)(n0 * 64 + nr) * 64 + c8 * 8) = *(const uint4*)tmp;
  }
}

// ---------------- transpose+convert 5 weights W[k][n] f32 -> Wt[n][k] bf16 ----------------
__global__ __launch_bounds__(256) void k_wt5(const float* __restrict__ W0, const float* __restrict__ W1,
                                             const float* __restrict__ W2, const float* __restrict__ W3,
                                             const float* __restrict__ W4, bf16_t* __restrict__ WtBase) {
  __shared__ float tile[64][65];
  const float* Ws[5] = {W0, W1, W2, W3, W4};
  const float* W = Ws[blockIdx.z];
  bf16_t* Wt = WtBase + (size_t)blockIdx.z * 512 * 512;
  int k0 = blockIdx.x * 64;
  int n0 = blockIdx.y * 64;
  int t = threadIdx.x;
  int r0 = t >> 6;
  int c = t & 63;
#pragma unroll 4
  for (int i = 0; i < 16; ++i) {
    int r = r0 * 16 + i;
    tile[r][c] = W[(size_t)(k0 + r) * 512 + n0 + c];
  }
  __syncthreads();
#pragma unroll 4
  for (int i = 0; i < 16; ++i) {
    int r = r0 * 16 + i;
    Wt[(size_t)(n0 + r) * 512 + k0 + c] = f2b(tile[c][r]);
  }
}

// ---- MFMA GEMM: Cb[M,512] bf16 = Abf[M,512] bf16 @ Wt^T ; NBN n-tiles looped in-block ----
template <int BM, int NBN>
__global__ __launch_bounds__(256) void k_mfma_gemm(const bf16_t* __restrict__ Abf,
                                                   const bf16_t* __restrict__ Wt,
                                                   bf16_t* __restrict__ Cmat) {
  constexpr int TR = BM / 32;
  __shared__ bf16_t As[BM * 64];
  __shared__ bf16_t Bs[128 * 64];
  __shared__ bf16_t Cs[BM][132];

  int t = threadIdx.x;
  int lane = t & 63, wave = t >> 6;
  int wr = wave >> 1, wc = wave & 1;
  int lhi = lane >> 4, llo = lane & 15;
  int bm = blockIdx.y;

  const bf16_t* Ab = Abf + (size_t)bm * BM * 512;
  int cc = t & 7;
  int rr = t >> 3;
  uint4 areg[TR], breg[4];

  for (int bng = 0; bng < NBN; ++bng) {
    int bn = blockIdx.x * NBN + bng;
    const bf16_t* Wb = Wt + (size_t)bn * 128 * 512;
    f32x4 acc[TR][4] = {};

    auto issue = [&](int k0) {
#pragma unroll
      for (int i = 0; i < TR; ++i)
        areg[i] = *(const uint4*)(Ab + (size_t)(rr + i * 32) * 512 + k0 + cc * 8);
#pragma unroll
      for (int i = 0; i < 4; ++i)
        breg[i] = *(const uint4*)(Wb + (size_t)(rr + i * 32) * 512 + k0 + cc * 8);
    };
    auto store_lds = [&] {
#pragma unroll
      for (int i = 0; i < TR; ++i) {
        int r = rr + i * 32;
        *(uint4*)((char*)As + r * 128 + ((cc * 16) ^ ((r & 7) << 4))) = areg[i];
      }
#pragma unroll
      for (int i = 0; i < 4; ++i) {
        int r = rr + i * 32;
        *(uint4*)((char*)Bs + r * 128 + ((cc * 16) ^ ((r & 7) << 4))) = breg[i];
      }
    };

    issue(0);
    store_lds();
    __syncthreads();

    for (int k0 = 0; k0 < 512; k0 += 64) {
      bool last = (k0 + 64 >= 512);
      if (!last) issue(k0 + 64);
      bf16x8 af[TR][2], bfr[4][2];
#pragma unroll
      for (int kk = 0; kk < 2; ++kk) {
        int bofs = kk * 64 + lhi * 16;
#pragma unroll
        for (int tr = 0; tr < TR; ++tr) {
          int row = wr * (BM / 2) + tr * 16 + llo;
          af[tr][kk] = *(const bf16x8*)((const char*)As + row * 128 + (bofs ^ ((row & 7) << 4)));
        }
#pragma unroll
        for (int tc = 0; tc < 4; ++tc) {
          int col = wc * 64 + tc * 16 + llo;
          bfr[tc][kk] = *(const bf16x8*)((const char*)Bs + col * 128 + (bofs ^ ((col & 7) << 4)));
        }
      }
#pragma unroll
      for (int kk = 0; kk < 2; ++kk)
#pragma unroll
        for (int tr = 0; tr < TR; ++tr)
#pragma unroll
          for (int tc = 0; tc < 4; ++tc)
            acc[tr][tc] = __builtin_amdgcn_mfma_f32_16x16x32_bf16(
                af[tr][kk], bfr[tc][kk], acc[tr][tc], 0, 0, 0);
      __syncthreads();
      if (!last) {
        store_lds();
        __syncthreads();
      }
    }

    // epilogue: stage to LDS, then coalesced 256B-per-row stores
#pragma unroll
    for (int tr = 0; tr < TR; ++tr) {
      int row = wr * (BM / 2) + tr * 16 + lhi * 4;
#pragma unroll
      for (int r = 0; r < 4; ++r)
#pragma unroll
        for (int tc = 0; tc < 4; ++tc)
          Cs[row + r][wc * 64 + tc * 16 + llo] = f2b(acc[tr][tc][r]);
    }
    __syncthreads();
#pragma unroll
    for (int i = 0; i < BM / 16; ++i) {
      int row = i * 16 + wave * 4 + lhi;
      uint4 v = *(const uint4*)(&Cs[row][llo * 8]);
      *(uint4*)(Cmat + (size_t)(bm * BM + row) * 512 + bn * 128 + llo * 8) = v;
    }
    __syncthreads();
  }
}

// ---------------- fused h2h: gram(MFMA) + softmax + PV(MFMA) -> f32 ----------------
__global__ __launch_bounds__(256) void k_h2h(const bf16_t* __restrict__ hide,
                                             const bf16_t* __restrict__ hlnT,
                                             float* __restrict__ outp) {
  __shared__ bf16_t hS[8 * 64 * 64];
  __shared__ float sS[16][68];
  __shared__ bf16_t wS[16 * 64];

  int q = blockIdx.x;
  int b = blockIdx.y;
  int t = threadIdx.x;
  int lane = t & 63, wave = t >> 6;
  int lhi = lane >> 4, llo = lane & 15;

  const bf16_t* Hb = hide + (size_t)b * C_ * D_;
#pragma unroll
  for (int rep = 0; rep < 16; ++rep) {
    int f = t + rep * 256;
    int row = f >> 6, c16 = f & 63;
    int kc = c16 >> 3, ci = c16 & 7;
    uint4 v = *(const uint4*)(Hb + (size_t)row * 512 + c16 * 8);
    *(uint4*)((char*)hS + kc * 8192 + row * 128 + ((ci * 16) ^ ((row & 7) << 4))) = v;
  }
  __syncthreads();

  {
    f32x4 acc = {};
#pragma unroll
    for (int ks = 0; ks < 16; ++ks) {
      int kc = ks >> 1;
      int bofs = (ks & 1) * 64 + lhi * 16;
      int ra = q * 16 + llo;
      int rb = wave * 16 + llo;
      bf16x8 af = *(const bf16x8*)((const char*)hS + kc * 8192 + ra * 128 + (bofs ^ ((ra & 7) << 4)));
      bf16x8 bf = *(const bf16x8*)((const char*)hS + kc * 8192 + rb * 128 + (bofs ^ ((rb & 7) << 4)));
      acc = __builtin_amdgcn_mfma_f32_16x16x32_bf16(af, bf, acc, 0, 0, 0);
    }
#pragma unroll
    for (int r = 0; r < 4; ++r) sS[lhi * 4 + r][wave * 16 + llo] = acc[r] * INV_SD;
  }
  __syncthreads();

  if (t < 128) {
    int row = t >> 3, sg = t & 7;
    float v[8];
#pragma unroll
    for (int u = 0; u < 8; ++u) v[u] = sS[row][sg * 8 + u];
    float m = v[0];
#pragma unroll
    for (int u = 1; u < 8; ++u) m = fmaxf(m, v[u]);
#pragma unroll
    for (int o = 4; o; o >>= 1) m = fmaxf(m, __shfl_xor(m, o));
    float sum = 0.f;
#pragma unroll
    for (int u = 0; u < 8; ++u) { v[u] = __expf(v[u] - m); sum += v[u]; }
#pragma unroll
    for (int o = 4; o; o >>= 1) sum += __shfl_xor(sum, o);
    float inv = 1.f / sum;
    bf16x8 wv;
#pragma unroll
    for (int u = 0; u < 8; ++u) wv[u] = f2b(v[u] * inv);
    *(bf16x8*)((char*)wS + row * 128 + ((sg * 16) ^ ((row & 7) << 4))) = wv;
  }
  __syncthreads();

  {
    bf16x8 af[2];
#pragma unroll
    for (int ks = 0; ks < 2; ++ks)
      af[ks] = *(const bf16x8*)((const char*)wS + llo * 128 + (((ks * 64 + lhi * 16)) ^ ((llo & 7) << 4)));
    const bf16_t* Tb = hlnT + (size_t)b * D_ * C_;
    f32x4 acc[8] = {};
#pragma unroll
    for (int nt = 0; nt < 8; ++nt) {
      int drow = wave * 128 + nt * 16 + llo;
#pragma unroll
      for (int ks = 0; ks < 2; ++ks) {
        bf16x8 bf = *(const bf16x8*)(Tb + (size_t)drow * 64 + ks * 32 + lhi * 8);
        acc[nt] = __builtin_amdgcn_mfma_f32_16x16x32_bf16(af[ks], bf, acc[nt], 0, 0, 0);
      }
    }
    float* Ob = outp + (size_t)b * C_ * D_;
#pragma unroll
    for (int nt = 0; nt < 8; ++nt) {
      int dcol = wave * 128 + nt * 16 + llo;
#pragma unroll
      for (int r = 0; r < 4; ++r)
        Ob[(size_t)(q * 16 + lhi * 4 + r) * 512 + dcol] = acc[nt][r];
    }
  }
}

// ---- h2a #1 + fused LN21: att f32 in; out att1 bf16 + LN(att1) bf16 ----
__global__ __launch_bounds__(256) void k_h2a_ln(const float* __restrict__ att,
                                                const bf16_t* __restrict__ hW,
                                                const float* __restrict__ lw,
                                                const float* __restrict__ lb,
                                                bf16_t* __restrict__ att1b,
                                                bf16_t* __restrict__ lnb) {
  int t = threadIdx.x;
  int row = blockIdx.x * 4 + (t >> 6);
  int lane = t & 63;
  int b = row >> 10, a = row & 1023;
  int c = a & 63;
  int d0 = lane * 8;
  const float* ar = att + (size_t)row * D_ + d0;
  const bf16_t* wr = hW + (size_t)(b * 64 + c) * D_ + d0;
  float4 a1 = *(const float4*)ar;
  float4 a2 = *(const float4*)(ar + 4);
  bf16x8 wb = *(const bf16x8*)wr;
  float w[8], av[8] = {a1.x, a1.y, a1.z, a1.w, a2.x, a2.y, a2.z, a2.w};
#pragma unroll
  for (int u = 0; u < 8; ++u) w[u] = b2f(wb[u]);
  float d1 = 0.f, d2 = 0.f;
#pragma unroll
  for (int u = 0; u < 8; ++u) { d1 += av[u] * w[u]; d2 += av[u] * av[u]; }
#pragma unroll
  for (int o = 32; o; o >>= 1) { d1 += __shfl_xor(d1, o); d2 += __shfl_xor(d2, o); }
  float s1 = d1 * INV_SD, s2 = d2 * INV_SD;
  float m = fmaxf(s1, s2);
  float e1 = __expf(s1 - m), e2 = __expf(s2 - m);
  float inv = 1.f / (e1 + e2);
  float alpha = e1 * inv, beta = e2 * inv;
  float o8[8];
  float s = 0.f, q = 0.f;
#pragma unroll
  for (int u = 0; u < 8; ++u) {
    o8[u] = alpha * w[u] + beta * av[u];
    s += o8[u];
    q += o8[u] * o8[u];
  }
  bf16x8 ob;
#pragma unroll
  for (int u = 0; u < 8; ++u) ob[u] = f2b(o8[u]);
  *(bf16x8*)(att1b + (size_t)row * D_ + d0) = ob;
#pragma unroll
  for (int o = 32; o; o >>= 1) { s += __shfl_xor(s, o); q += __shfl_xor(q, o); }
  float mu = s * (1.0f / D_);
  float rs = rsqrtf(q * (1.0f / D_) - mu * mu + 1e-5f);
  float4 w1 = *(const float4*)(lw + d0);
  float4 w2 = *(const float4*)(lw + d0 + 4);
  float4 b1 = *(const float4*)(lb + d0);
  float4 b2 = *(const float4*)(lb + d0 + 4);
  float lwv[8] = {w1.x, w1.y, w1.z, w1.w, w2.x, w2.y, w2.z, w2.w};
  float lbv[8] = {b1.x, b1.y, b1.z, b1.w, b2.x, b2.y, b2.z, b2.w};
  bf16x8 nb;
#pragma unroll
  for (int u = 0; u < 8; ++u) nb[u] = f2b((o8[u] - mu) * rs * lwv[u] + lbv[u]);
  *(bf16x8*)(lnb + (size_t)row * D_ + d0) = nb;
}

// ---- h2a #2 (final): att1 bf16 in, out f32 ----
__global__ __launch_bounds__(256) void k_h2a_out(const bf16_t* __restrict__ att,
                                                 const bf16_t* __restrict__ hW,
                                                 float* __restrict__ outp) {
  int t = threadIdx.x;
  int row = blockIdx.x * 4 + (t >> 6);
  int lane = t & 63;
  int b = row >> 10, a = row & 1023;
  int c = a & 63;
  int d0 = lane * 8;
  bf16x8 ab = *(const bf16x8*)(att + (size_t)row * D_ + d0);
  bf16x8 wb = *(const bf16x8*)(hW + (size_t)(b * 64 + c) * D_ + d0);
  float av[8], w[8];
#pragma unroll
  for (int u = 0; u < 8; ++u) { av[u] = b2f(ab[u]); w[u] = b2f(wb[u]); }
  float d1 = 0.f, d2 = 0.f;
#pragma unroll
  for (int u = 0; u < 8; ++u) { d1 += av[u] * w[u]; d2 += av[u] * av[u]; }
#pragma unroll
  for (int o = 32; o; o >>= 1) { d1 += __shfl_xor(d1, o); d2 += __shfl_xor(d2, o); }
  float s1 = d1 * INV_SD, s2 = d2 * INV_SD;
  float m = fmaxf(s1, s2);
  float e1 = __expf(s1 - m), e2 = __expf(s2 - m);
  float inv = 1.f / (e1 + e2);
  float alpha = e1 * inv, beta = e2 * inv;
  float4 o1, o2;
  o1.x = alpha * w[0] + beta * av[0]; o1.y = alpha * w[1] + beta * av[1];
  o1.z = alpha * w[2] + beta * av[2]; o1.w = alpha * w[3] + beta * av[3];
  o2.x = alpha * w[4] + beta * av[4]; o2.y = alpha * w[5] + beta * av[5];
  o2.z = alpha * w[6] + beta * av[6]; o2.w = alpha * w[7] + beta * av[7];
  float* orow = outp + (size_t)row * D_ + d0;
  *(float4*)orow = o1;
  *(float4*)(orow + 4) = o2;
}

// ---- layer2 a2h attention + fused LN22 -> hln bf16 ----
__global__ __launch_bounds__(256) void k_a2h_ln(const float* __restrict__ hl1,
                                                const bf16_t* __restrict__ aW,
                                                const float* __restrict__ lw,
                                                const float* __restrict__ lb,
                                                bf16_t* __restrict__ hlnb) {
  int blk = blockIdx.x;  // CB*C
  int b = blk >> 6, c = blk & 63;
  int t = threadIdx.x;
  __shared__ float hrow[D_];
  __shared__ float wts[32];
  __shared__ float red[4];
  __shared__ float red2[8];
  const float* hr = hl1 + (size_t)blk * D_;
  float2 v = *(const float2*)(hr + 2 * t);
  hrow[2 * t] = v.x;
  hrow[2 * t + 1] = v.y;
  float sd = v.x * v.x + v.y * v.y;
#pragma unroll
  for (int o = 32; o; o >>= 1) sd += __shfl_xor(sd, o);
  int w = t >> 6;
  if ((t & 63) == 0) red[w] = sd;
  __syncthreads();
  int j = t >> 4, p = t & 15;
  const bf16_t* arow = aW + ((size_t)b * A_ + j * 64 + c) * D_;
  float partial = 0.f;
#pragma unroll
  for (int kk = 0; kk < 16; ++kk) {
    int k = p * 32 + 2 * ((kk + p) & 15);
    bf16x2 a2 = *(const bf16x2*)(arow + k);
    partial += hrow[k] * b2f(a2.x) + hrow[k + 1] * b2f(a2.y);
  }
#pragma unroll
  for (int o = 8; o; o >>= 1) partial += __shfl_xor(partial, o);
  if (p == 0) wts[j] = partial * INV_SD;
  if (t == 0) wts[16] = ((red[0] + red[1]) + (red[2] + red[3])) * INV_SD;
  __syncthreads();
  if (t < 64) {
    float val = (t < 17) ? wts[t] : -3.0e38f;
    float m = val;
#pragma unroll
    for (int o = 32; o; o >>= 1) m = fmaxf(m, __shfl_xor(m, o));
    float e = (t < 17) ? __expf(val - m) : 0.f;
    float ssum = e;
#pragma unroll
    for (int o = 32; o; o >>= 1) ssum += __shfl_xor(ssum, o);
    if (t < 17) wts[t] = e / ssum;
  }
  __syncthreads();
  int d = 2 * t;
  float accx = wts[16] * hrow[d];
  float accy = wts[16] * hrow[d + 1];
#pragma unroll 4
  for (int jj = 0; jj < 16; ++jj) {
    bf16x2 a2 = *(const bf16x2*)(aW + ((size_t)b * A_ + jj * 64 + c) * D_ + d);
    accx += wts[jj] * b2f(a2.x);
    accy += wts[jj] * b2f(a2.y);
  }
  // fused LN22
  float s = accx + accy, q = accx * accx + accy * accy;
#pragma unroll
  for (int o = 32; o; o >>= 1) { s += __shfl_xor(s, o); q += __shfl_xor(q, o); }
  int lane = t & 63;
  if (lane == 0) { red2[w] = s; red2[4 + w] = q; }
  __syncthreads();
  float S = (red2[0] + red2[1]) + (red2[2] + red2[3]);
  float Q = (red2[4] + red2[5]) + (red2[6] + red2[7]);
  float mu = S * (1.0f / D_);
  float rs = rsqrtf(Q * (1.0f / D_) - mu * mu + 1e-5f);
  bf16x2 ob;
  ob.x = f2b((accx - mu) * rs * lw[d] + lb[d]);
  ob.y = f2b((accy - mu) * rs * lw[d + 1] + lb[d + 1]);
  *(bf16x2*)(hlnb + (size_t)blk * D_ + d) = ob;
}

extern "C" void kernel_launch(void* const* d_in, const int* in_sizes, int n_in,
                              void* d_out, int out_size, void* d_ws, size_t ws_size,
                              hipStream_t stream) {
  const float* att_vf = (const float*)d_in[0];
  const float* W1_h2h = (const float*)d_in[4];
  const float* W1_h2a = (const float*)d_in[5];
  const float* ln11w = (const float*)d_in[6];
  const float* ln11b = (const float*)d_in[7];
  const float* ln12w = (const float*)d_in[8];
  const float* ln12b = (const float*)d_in[9];
  const float* ln13w = (const float*)d_in[10];
  const float* ln13b = (const float*)d_in[11];
  const float* W2_a2h = (const float*)d_in[12];
  const float* W2_h2h = (const float*)d_in[13];
  const float* W2_h2a = (const float*)d_in[14];
  const float* ln21w = (const float*)d_in[15];
  const float* ln21b = (const float*)d_in[16];
  const float* ln22w = (const float*)d_in[17];
  const float* ln22b = (const float*)d_in[18];
  const float* ln23w = (const float*)d_in[19];
  const float* ln23b = (const float*)d_in[20];
  float* out = (float*)d_out;

  float* ws = (float*)d_ws;
  const size_t SMALL = (size_t)B_ * C_ * D_;  // 2097152 elems
  float* A3 = ws;                               // hl1 / hl2' f32 (SMALL)
  bf16_t* A1b = (bf16_t*)(A3 + SMALL);          // hln bf16 (SMALL/2 floats)
  bf16_t* A1t = (bf16_t*)((float*)A1b + SMALL / 2);
  bf16_t* A2b = (bf16_t*)((float*)A1t + SMALL / 2);
  bf16_t* Wt0 = (bf16_t*)((float*)A2b + SMALL / 2);
  const size_t WTF = (size_t)512 * 512 / 2;  // floats per Wt
  bf16_t* Wt_h2h1 = Wt0;
  bf16_t* Wt_h2a1 = (bf16_t*)((float*)Wt0 + WTF);
  bf16_t* Wt_a2h = (bf16_t*)((float*)Wt0 + 2 * WTF);
  bf16_t* Wt_h2h2 = (bf16_t*)((float*)Wt0 + 3 * WTF);
  bf16_t* Wt_h2a2 = (bf16_t*)((float*)Wt0 + 4 * WTF);
  bf16_t* att1b = (bf16_t*)((float*)Wt0 + 5 * WTF);          // B*A*D bf16
  bf16_t* Abf = (bf16_t*)((float*)att1b + (size_t)B_ * A_ * D_ / 2);  // B*A*D bf16
  float* chunk0 = (float*)Abf + (size_t)B_ * A_ * D_ / 2;

  size_t base_floats = (size_t)(chunk0 - ws);
  size_t ws_floats = ws_size / 4;
  const size_t PERB = (size_t)A_ * D_ / 2;  // aWb bf16 floats per batch
  int CB = 1;
  if (ws_floats > base_floats) {
    size_t cap = (ws_floats - base_floats) / PERB;
    CB = (int)(cap > 64 ? 64 : (cap < 1 ? 1 : cap));
  }
  int cb = 1;
  while (cb * 2 <= CB && cb * 2 <= 64) cb *= 2;
  CB = cb;
  int nchunks = B_ / CB;
  bf16_t* aWb = (bf16_t*)chunk0;

  dim3 blk(256);
  // weight prep (one kernel, 5 weights)
  k_wt5<<<dim3(8, 8, 5), blk, 0, stream>>>(W1_h2h, W1_h2a, W2_a2h, W2_h2h, W2_h2a, Wt0);

  // ---- layer 1 ----
  k_hl0<<<B_ * C_, blk, 0, stream>>>(att_vf, ln11w, ln11b, ln12w, ln12b, A1b);  // hln1
  k_tr<<<dim3(8, B_), blk, 0, stream>>>(A1b, A1t);
  k_mfma_gemm<64, 1><<<dim3(4, 64), blk, 0, stream>>>(A1b, Wt_h2h1, A2b);  // hide
  k_h2h<<<dim3(4, B_), blk, 0, stream>>>(A2b, A1t, A3);                    // hl1 f32
  k_lnb<<<(B_ * C_) / 4, blk, 0, stream>>>(A3, ln13w, ln13b, A1b);         // ln13
  k_mfma_gemm<64, 1><<<dim3(4, 64), blk, 0, stream>>>(A1b, Wt_h2a1, A2b);  // hW1
  k_h2a_ln<<<(B_ * A_) / 4, blk, 0, stream>>>(att_vf, A2b, ln21w, ln21b, att1b, Abf);
  // ---- layer 2: a2h attention (chunked over batches) ----
  for (int ch = 0; ch < nchunks; ++ch) {
    size_t b0 = (size_t)ch * CB;
    k_mfma_gemm<128, 4><<<dim3(1, CB * 8), blk, 0, stream>>>(Abf + b0 * A_ * D_, Wt_a2h, aWb);
    k_a2h_ln<<<CB * C_, blk, 0, stream>>>(A3 + b0 * C_ * D_, aWb, ln22w, ln22b,
                                          A1b + b0 * C_ * D_);  // hln22 bf16
  }
  // h2h #2
  k_tr<<<dim3(8, B_), blk, 0, stream>>>(A1b, A1t);
  k_mfma_gemm<64, 1><<<dim3(4, 64), blk, 0, stream>>>(A1b, Wt_h2h2, A2b);  // hide2
  k_h2h<<<dim3(4, B_), blk, 0, stream>>>(A2b, A1t, A3);                    // hl2' f32
  k_lnb<<<(B_ * C_) / 4, blk, 0, stream>>>(A3, ln23w, ln23b, A1b);         // ln23
  k_mfma_gemm<64, 1><<<dim3(4, 64), blk, 0, stream>>>(A1b, Wt_h2a2, A2b);  // hW2
  k_h2a_out<<<(B_ * A_) / 4, blk, 0, stream>>>(att1b, A2b, out);
}

// Round 5
// 298.443 us; speedup vs baseline: 5.6382x; 1.7729x over previous
//
#include <hip/hip_runtime.h>

#define B_ 64
#define A_ 1024
#define C_ 64
#define D_ 512
#define INV_SD 0.044194173824159216f

typedef __bf16 bf16_t;
typedef __bf16 bf16x8 __attribute__((ext_vector_type(8)));
typedef __bf16 bf16x2 __attribute__((ext_vector_type(2)));
typedef float f32x4 __attribute__((ext_vector_type(4)));

static __device__ __forceinline__ bf16_t f2b(float x) { return (bf16_t)x; }
static __device__ __forceinline__ float b2f(bf16_t x) { return (float)x; }

// async global->LDS, 16B per lane; LDS dest = wave-uniform base + lane*16 (linear)
static __device__ __forceinline__ void gl_lds16(const void* g, void* l) {
  __builtin_amdgcn_global_load_lds(
      (const __attribute__((address_space(1))) unsigned int*)g,
      (__attribute__((address_space(3))) unsigned int*)l, 16, 0, 0);
}

// ---- fused: per (b,c): stats+LN11 of 16 att rows, avg, LN12 -> hln bf16 ----
__global__ __launch_bounds__(256) void k_hl0(const float* __restrict__ att,
                                             const float* __restrict__ lw1,
                                             const float* __restrict__ lb1,
                                             const float* __restrict__ lw2,
                                             const float* __restrict__ lb2,
                                             bf16_t* __restrict__ hlnb) {
  int blk = blockIdx.x;  // B*C
  int b = blk >> 6, c = blk & 63;
  int t = threadIdx.x;
  int w = t >> 6, lane = t & 63;
  __shared__ float part[4][512];
  __shared__ float reds[8];
  float ps[8] = {0.f, 0.f, 0.f, 0.f, 0.f, 0.f, 0.f, 0.f};
#pragma unroll
  for (int i = 0; i < 4; ++i) {
    int jj = w * 4 + i;
    const float* xr = att + ((size_t)b * A_ + jj * 64 + c) * D_ + lane * 8;
    float4 v1 = *(const float4*)xr;
    float4 v2 = *(const float4*)(xr + 4);
    float v[8] = {v1.x, v1.y, v1.z, v1.w, v2.x, v2.y, v2.z, v2.w};
    float s = 0.f, q = 0.f;
#pragma unroll
    for (int u = 0; u < 8; ++u) { s += v[u]; q += v[u] * v[u]; }
#pragma unroll
    for (int o = 32; o; o >>= 1) { s += __shfl_xor(s, o); q += __shfl_xor(q, o); }
    float mu = s * (1.0f / D_);
    float rs = rsqrtf(q * (1.0f / D_) - mu * mu + 1e-5f);
#pragma unroll
    for (int u = 0; u < 8; ++u) ps[u] += (v[u] - mu) * rs;
  }
#pragma unroll
  for (int u = 0; u < 8; ++u) part[w][lane * 8 + u] = ps[u];
  __syncthreads();
  int d = 2 * t;
  float hx = ((part[0][d] + part[1][d]) + (part[2][d] + part[3][d])) * (1.f / 16.f) * lw1[d] + lb1[d];
  float hy = ((part[0][d + 1] + part[1][d + 1]) + (part[2][d + 1] + part[3][d + 1])) * (1.f / 16.f) * lw1[d + 1] + lb1[d + 1];
  float s = hx + hy, q = hx * hx + hy * hy;
#pragma unroll
  for (int o = 32; o; o >>= 1) { s += __shfl_xor(s, o); q += __shfl_xor(q, o); }
  if (lane == 0) { reds[w] = s; reds[4 + w] = q; }
  __syncthreads();
  float S = (reds[0] + reds[1]) + (reds[2] + reds[3]);
  float Q = (reds[4] + reds[5]) + (reds[6] + reds[7]);
  float mu = S * (1.0f / D_);
  float rs = rsqrtf(Q * (1.0f / D_) - mu * mu + 1e-5f);
  bf16x2 ob;
  ob.x = f2b((hx - mu) * rs * lw2[d] + lb2[d]);
  ob.y = f2b((hy - mu) * rs * lw2[d + 1] + lb2[d + 1]);
  *(bf16x2*)(hlnb + (size_t)blk * D_ + d) = ob;
}

// ---------------- LN row f32 -> bf16, wave-per-row ----------------
__global__ __launch_bounds__(256) void k_lnb(const float* __restrict__ x,
                                             const float* __restrict__ lw,
                                             const float* __restrict__ lb,
                                             bf16_t* __restrict__ yb) {
  int t = threadIdx.x;
  int row = blockIdx.x * 4 + (t >> 6);
  int lane = t & 63;
  int d0 = lane * 8;
  const float* xr = x + (size_t)row * D_ + d0;
  float4 v1 = *(const float4*)xr;
  float4 v2 = *(const float4*)(xr + 4);
  float s = (v1.x + v1.y + v1.z + v1.w) + (v2.x + v2.y + v2.z + v2.w);
  float q = v1.x * v1.x + v1.y * v1.y + v1.z * v1.z + v1.w * v1.w +
            v2.x * v2.x + v2.y * v2.y + v2.z * v2.z + v2.w * v2.w;
#pragma unroll
  for (int o = 32; o; o >>= 1) { s += __shfl_xor(s, o); q += __shfl_xor(q, o); }
  float mu = s * (1.0f / D_);
  float rs = rsqrtf(q * (1.0f / D_) - mu * mu + 1e-5f);
  float4 w1 = *(const float4*)(lw + d0);
  float4 w2 = *(const float4*)(lw + d0 + 4);
  float4 b1 = *(const float4*)(lb + d0);
  float4 b2 = *(const float4*)(lb + d0 + 4);
  bf16x8 ob;
  ob[0] = f2b((v1.x - mu) * rs * w1.x + b1.x);
  ob[1] = f2b((v1.y - mu) * rs * w1.y + b1.y);
  ob[2] = f2b((v1.z - mu) * rs * w1.z + b1.z);
  ob[3] = f2b((v1.w - mu) * rs * w1.w + b1.w);
  ob[4] = f2b((v2.x - mu) * rs * w2.x + b2.x);
  ob[5] = f2b((v2.y - mu) * rs * w2.y + b2.y);
  ob[6] = f2b((v2.z - mu) * rs * w2.z + b2.z);
  ob[7] = f2b((v2.w - mu) * rs * w2.w + b2.w);
  *(bf16x8*)(yb + (size_t)row * D_ + d0) = ob;
}

// ---------------- transpose hln bf16 [64][512] -> hlnT [512][64] per batch ----------------
__global__ __launch_bounds__(256) void k_tr(const bf16_t* __restrict__ src,
                                            bf16_t* __restrict__ dst) {
  __shared__ unsigned short sm[64][72];
  int n0 = blockIdx.x;  // 0..7
  int b = blockIdx.y;
  int t = threadIdx.x;
  const bf16_t* sb = src + (size_t)b * C_ * D_;
  bf16_t* db = dst + (size_t)b * D_ * C_;
#pragma unroll
  for (int rep = 0; rep < 2; ++rep) {
    int f = t + rep * 256;
    int r = f >> 3, c8 = f & 7;
    uint4 v = *(const uint4*)(sb + (size_t)r * D_ + n0 * 64 + c8 * 8);
    unsigned int* p = (unsigned int*)&sm[r][c8 * 8];
    p[0] = v.x; p[1] = v.y; p[2] = v.z; p[3] = v.w;
  }
  __syncthreads();
#pragma unroll
  for (int rep = 0; rep < 2; ++rep) {
    int f = t + rep * 256;
    int nr = f >> 3, c8 = f & 7;
    unsigned short tmp[8];
#pragma unroll
    for (int u = 0; u < 8; ++u) tmp[u] = sm[c8 * 8 + u][nr];
    *(uint4*)(db + (size_t)(n0 * 64 + nr) * 64 + c8 * 8) = *(const uint4*)tmp;
  }
}

// ---------------- transpose+convert 5 weights W[k][n] f32 -> Wt[n][k] bf16 ----------------
__global__ __launch_bounds__(256) void k_wt5(const float* __restrict__ W0, const float* __restrict__ W1,
                                             const float* __restrict__ W2, const float* __restrict__ W3,
                                             const float* __restrict__ W4, bf16_t* __restrict__ WtBase) {
  __shared__ float tile[64][65];
  const float* Ws[5] = {W0, W1, W2, W3, W4};
  const float* W = Ws[blockIdx.z];
  bf16_t* Wt = WtBase + (size_t)blockIdx.z * 512 * 512;
  int k0 = blockIdx.x * 64;
  int n0 = blockIdx.y * 64;
  int t = threadIdx.x;
  int r0 = t >> 6;
  int c = t & 63;
#pragma unroll 4
  for (int i = 0; i < 16; ++i) {
    int r = r0 * 16 + i;
    tile[r][c] = W[(size_t)(k0 + r) * 512 + n0 + c];
  }
  __syncthreads();
#pragma unroll 4
  for (int i = 0; i < 16; ++i) {
    int r = r0 * 16 + i;
    Wt[(size_t)(n0 + r) * 512 + k0 + c] = f2b(tile[c][r]);
  }
}

// ---- MFMA GEMM: Cb[M,512] bf16 = Abf[M,512] bf16 @ Wt^T ----
// 1-D grid of (M/BM)*4 tiles, XCD-chunked swizzle; global_load_lds staging with
// pre-swizzled global source (linear LDS dest + XOR read); epilogue Cs aliases As/Bs.
template <int BM>
__global__ __launch_bounds__(256, 4) void k_mfma_gemm(const bf16_t* __restrict__ Abf,
                                                      const bf16_t* __restrict__ Wt,
                                                      bf16_t* __restrict__ Cmat) {
  constexpr int TR = BM / 32;
  constexpr int ABYTES = BM * 128;          // A tile bytes (BM x 64 bf16)
  constexpr int CBYTES = BM * 136 * 2;      // epilogue staging
  constexpr int SMEM = (ABYTES + 16384 > CBYTES) ? (ABYTES + 16384) : CBYTES;
  __shared__ char smem[SMEM];
  bf16_t* As = (bf16_t*)smem;
  bf16_t* Bs = (bf16_t*)(smem + ABYTES);

  int t = threadIdx.x;
  int lane = t & 63, wave = t >> 6;
  int wr = wave >> 1, wc = wave & 1;
  int lhi = lane >> 4, llo = lane & 15;

  // XCD-chunked swizzle: consecutive tiles (4 bn of one bm) stay on one XCD
  int nwg = gridDim.x;
  int bid = blockIdx.x;
  int tile = (bid & 7) * (nwg >> 3) + (bid >> 3);
  int bm = tile >> 2, bn = tile & 3;

  const bf16_t* Ab = Abf + (size_t)bm * BM * 512;
  const bf16_t* Wb = Wt + (size_t)bn * 128 * 512;

  int l3 = lane >> 3;                 // row-within-8 == (r & 7)
  int srcOff = ((lane & 7) ^ l3) * 8; // pre-swizzled source chunk (elems)

  auto stage = [&](int k0) {
#pragma unroll
    for (int i = 0; i < BM / 32; ++i) {
      int r0 = wave * (BM / 4) + i * 8;
      gl_lds16(Ab + (size_t)(r0 + l3) * 512 + k0 + srcOff, As + r0 * 64);
    }
#pragma unroll
    for (int i = 0; i < 4; ++i) {
      int r0 = wave * 32 + i * 8;
      gl_lds16(Wb + (size_t)(r0 + l3) * 512 + k0 + srcOff, Bs + r0 * 64);
    }
  };

  f32x4 acc[TR][4] = {};
  stage(0);
  __syncthreads();

  for (int k0 = 0; k0 < 512; k0 += 64) {
#pragma unroll
    for (int kk = 0; kk < 2; ++kk) {
      bf16x8 af[TR], bfr[4];
      int bofs = kk * 64 + lhi * 16;
#pragma unroll
      for (int tr = 0; tr < TR; ++tr) {
        int row = wr * (BM / 2) + tr * 16 + llo;
        af[tr] = *(const bf16x8*)((const char*)As + row * 128 + (bofs ^ ((row & 7) << 4)));
      }
#pragma unroll
      for (int tc = 0; tc < 4; ++tc) {
        int col = wc * 64 + tc * 16 + llo;
        bfr[tc] = *(const bf16x8*)((const char*)Bs + col * 128 + (bofs ^ ((col & 7) << 4)));
      }
#pragma unroll
      for (int tr = 0; tr < TR; ++tr)
#pragma unroll
        for (int tc = 0; tc < 4; ++tc)
          acc[tr][tc] = __builtin_amdgcn_mfma_f32_16x16x32_bf16(af[tr], bfr[tc], acc[tr][tc], 0, 0, 0);
    }
    if (k0 + 64 < 512) {
      __syncthreads();
      stage(k0 + 64);
      __syncthreads();
    }
  }

  // epilogue: stage C tile in LDS (aliases As/Bs), then coalesced 256B stores
  __syncthreads();
  bf16_t(*Cs)[136] = (bf16_t(*)[136])smem;
#pragma unroll
  for (int tr = 0; tr < TR; ++tr) {
    int row = wr * (BM / 2) + tr * 16 + lhi * 4;
#pragma unroll
    for (int r = 0; r < 4; ++r)
#pragma unroll
      for (int tc = 0; tc < 4; ++tc)
        Cs[row + r][wc * 64 + tc * 16 + llo] = f2b(acc[tr][tc][r]);
  }
  __syncthreads();
#pragma unroll
  for (int i = 0; i < BM / 16; ++i) {
    int row = i * 16 + wave * 4 + lhi;
    uint4 v = *(const uint4*)(&Cs[row][llo * 8]);
    *(uint4*)(Cmat + (size_t)(bm * BM + row) * 512 + bn * 128 + llo * 8) = v;
  }
}

// ---------------- fused h2h: gram(MFMA) + softmax + PV(MFMA) -> f32 ----------------
__global__ __launch_bounds__(256) void k_h2h(const bf16_t* __restrict__ hide,
                                             const bf16_t* __restrict__ hlnT,
                                             float* __restrict__ outp) {
  __shared__ bf16_t hS[8 * 64 * 64];
  __shared__ float sS[16][68];
  __shared__ bf16_t wS[16 * 64];

  int q = blockIdx.x;
  int b = blockIdx.y;
  int t = threadIdx.x;
  int lane = t & 63, wave = t >> 6;
  int lhi = lane >> 4, llo = lane & 15;

  const bf16_t* Hb = hide + (size_t)b * C_ * D_;
#pragma unroll
  for (int rep = 0; rep < 16; ++rep) {
    int f = t + rep * 256;
    int row = f >> 6, c16 = f & 63;
    int kc = c16 >> 3, ci = c16 & 7;
    uint4 v = *(const uint4*)(Hb + (size_t)row * 512 + c16 * 8);
    *(uint4*)((char*)hS + kc * 8192 + row * 128 + ((ci * 16) ^ ((row & 7) << 4))) = v;
  }
  __syncthreads();

  {
    f32x4 acc = {};
#pragma unroll
    for (int ks = 0; ks < 16; ++ks) {
      int kc = ks >> 1;
      int bofs = (ks & 1) * 64 + lhi * 16;
      int ra = q * 16 + llo;
      int rb = wave * 16 + llo;
      bf16x8 af = *(const bf16x8*)((const char*)hS + kc * 8192 + ra * 128 + (bofs ^ ((ra & 7) << 4)));
      bf16x8 bf = *(const bf16x8*)((const char*)hS + kc * 8192 + rb * 128 + (bofs ^ ((rb & 7) << 4)));
      acc = __builtin_amdgcn_mfma_f32_16x16x32_bf16(af, bf, acc, 0, 0, 0);
    }
#pragma unroll
    for (int r = 0; r < 4; ++r) sS[lhi * 4 + r][wave * 16 + llo] = acc[r] * INV_SD;
  }
  __syncthreads();

  if (t < 128) {
    int row = t >> 3, sg = t & 7;
    float v[8];
#pragma unroll
    for (int u = 0; u < 8; ++u) v[u] = sS[row][sg * 8 + u];
    float m = v[0];
#pragma unroll
    for (int u = 1; u < 8; ++u) m = fmaxf(m, v[u]);
#pragma unroll
    for (int o = 4; o; o >>= 1) m = fmaxf(m, __shfl_xor(m, o));
    float sum = 0.f;
#pragma unroll
    for (int u = 0; u < 8; ++u) { v[u] = __expf(v[u] - m); sum += v[u]; }
#pragma unroll
    for (int o = 4; o; o >>= 1) sum += __shfl_xor(sum, o);
    float inv = 1.f / sum;
    bf16x8 wv;
#pragma unroll
    for (int u = 0; u < 8; ++u) wv[u] = f2b(v[u] * inv);
    *(bf16x8*)((char*)wS + row * 128 + ((sg * 16) ^ ((row & 7) << 4))) = wv;
  }
  __syncthreads();

  {
    bf16x8 af[2];
#pragma unroll
    for (int ks = 0; ks < 2; ++ks)
      af[ks] = *(const bf16x8*)((const char*)wS + llo * 128 + (((ks * 64 + lhi * 16)) ^ ((llo & 7) << 4)));
    const bf16_t* Tb = hlnT + (size_t)b * D_ * C_;
    f32x4 acc[8] = {};
#pragma unroll
    for (int nt = 0; nt < 8; ++nt) {
      int drow = wave * 128 + nt * 16 + llo;
#pragma unroll
      for (int ks = 0; ks < 2; ++ks) {
        bf16x8 bf = *(const bf16x8*)(Tb + (size_t)drow * 64 + ks * 32 + lhi * 8);
        acc[nt] = __builtin_amdgcn_mfma_f32_16x16x32_bf16(af[ks], bf, acc[nt], 0, 0, 0);
      }
    }
    float* Ob = outp + (size_t)b * C_ * D_;
#pragma unroll
    for (int nt = 0; nt < 8; ++nt) {
      int dcol = wave * 128 + nt * 16 + llo;
#pragma unroll
      for (int r = 0; r < 4; ++r)
        Ob[(size_t)(q * 16 + lhi * 4 + r) * 512 + dcol] = acc[nt][r];
    }
  }
}

// ---- h2a #1 + fused LN21: att f32 in; out att1 bf16 + LN(att1) bf16 ----
__global__ __launch_bounds__(256) void k_h2a_ln(const float* __restrict__ att,
                                                const bf16_t* __restrict__ hW,
                                                const float* __restrict__ lw,
                                                const float* __restrict__ lb,
                                                bf16_t* __restrict__ att1b,
                                                bf16_t* __restrict__ lnb) {
  int t = threadIdx.x;
  int row = blockIdx.x * 4 + (t >> 6);
  int lane = t & 63;
  int b = row >> 10, a = row & 1023;
  int c = a & 63;
  int d0 = lane * 8;
  const float* ar = att + (size_t)row * D_ + d0;
  const bf16_t* wr = hW + (size_t)(b * 64 + c) * D_ + d0;
  float4 a1 = *(const float4*)ar;
  float4 a2 = *(const float4*)(ar + 4);
  bf16x8 wb = *(const bf16x8*)wr;
  float w[8], av[8] = {a1.x, a1.y, a1.z, a1.w, a2.x, a2.y, a2.z, a2.w};
#pragma unroll
  for (int u = 0; u < 8; ++u) w[u] = b2f(wb[u]);
  float d1 = 0.f, d2 = 0.f;
#pragma unroll
  for (int u = 0; u < 8; ++u) { d1 += av[u] * w[u]; d2 += av[u] * av[u]; }
#pragma unroll
  for (int o = 32; o; o >>= 1) { d1 += __shfl_xor(d1, o); d2 += __shfl_xor(d2, o); }
  float s1 = d1 * INV_SD, s2 = d2 * INV_SD;
  float m = fmaxf(s1, s2);
  float e1 = __expf(s1 - m), e2 = __expf(s2 - m);
  float inv = 1.f / (e1 + e2);
  float alpha = e1 * inv, beta = e2 * inv;
  float o8[8];
  float s = 0.f, q = 0.f;
#pragma unroll
  for (int u = 0; u < 8; ++u) {
    o8[u] = alpha * w[u] + beta * av[u];
    s += o8[u];
    q += o8[u] * o8[u];
  }
  bf16x8 ob;
#pragma unroll
  for (int u = 0; u < 8; ++u) ob[u] = f2b(o8[u]);
  *(bf16x8*)(att1b + (size_t)row * D_ + d0) = ob;
#pragma unroll
  for (int o = 32; o; o >>= 1) { s += __shfl_xor(s, o); q += __shfl_xor(q, o); }
  float mu = s * (1.0f / D_);
  float rs = rsqrtf(q * (1.0f / D_) - mu * mu + 1e-5f);
  float4 w1 = *(const float4*)(lw + d0);
  float4 w2 = *(const float4*)(lw + d0 + 4);
  float4 b1 = *(const float4*)(lb + d0);
  float4 b2 = *(const float4*)(lb + d0 + 4);
  float lwv[8] = {w1.x, w1.y, w1.z, w1.w, w2.x, w2.y, w2.z, w2.w};
  float lbv[8] = {b1.x, b1.y, b1.z, b1.w, b2.x, b2.y, b2.z, b2.w};
  bf16x8 nb;
#pragma unroll
  for (int u = 0; u < 8; ++u) nb[u] = f2b((o8[u] - mu) * rs * lwv[u] + lbv[u]);
  *(bf16x8*)(lnb + (size_t)row * D_ + d0) = nb;
}

// ---- h2a #2 (final): att1 bf16 in, out f32 ----
__global__ __launch_bounds__(256) void k_h2a_out(const bf16_t* __restrict__ att,
                                                 const bf16_t* __restrict__ hW,
                                                 float* __restrict__ outp) {
  int t = threadIdx.x;
  int row = blockIdx.x * 4 + (t >> 6);
  int lane = t & 63;
  int b = row >> 10, a = row & 1023;
  int c = a & 63;
  int d0 = lane * 8;
  bf16x8 ab = *(const bf16x8*)(att + (size_t)row * D_ + d0);
  bf16x8 wb = *(const bf16x8*)(hW + (size_t)(b * 64 + c) * D_ + d0);
  float av[8], w[8];
#pragma unroll
  for (int u = 0; u < 8; ++u) { av[u] = b2f(ab[u]); w[u] = b2f(wb[u]); }
  float d1 = 0.f, d2 = 0.f;
#pragma unroll
  for (int u = 0; u < 8; ++u) { d1 += av[u] * w[u]; d2 += av[u] * av[u]; }
#pragma unroll
  for (int o = 32; o; o >>= 1) { d1 += __shfl_xor(d1, o); d2 += __shfl_xor(d2, o); }
  float s1 = d1 * INV_SD, s2 = d2 * INV_SD;
  float m = fmaxf(s1, s2);
  float e1 = __expf(s1 - m), e2 = __expf(s2 - m);
  float inv = 1.f / (e1 + e2);
  float alpha = e1 * inv, beta = e2 * inv;
  float4 o1, o2;
  o1.x = alpha * w[0] + beta * av[0]; o1.y = alpha * w[1] + beta * av[1];
  o1.z = alpha * w[2] + beta * av[2]; o1.w = alpha * w[3] + beta * av[3];
  o2.x = alpha * w[4] + beta * av[4]; o2.y = alpha * w[5] + beta * av[5];
  o2.z = alpha * w[6] + beta * av[6]; o2.w = alpha * w[7] + beta * av[7];
  float* orow = outp + (size_t)row * D_ + d0;
  *(float4*)orow = o1;
  *(float4*)(orow + 4) = o2;
}

// ---- layer2 a2h attention + fused LN22 -> hln bf16 ----
__global__ __launch_bounds__(256) void k_a2h_ln(const float* __restrict__ hl1,
                                                const bf16_t* __restrict__ aW,
                                                const float* __restrict__ lw,
                                                const float* __restrict__ lb,
                                                bf16_t* __restrict__ hlnb) {
  int blk = blockIdx.x;  // CB*C
  int b = blk >> 6, c = blk & 63;
  int t = threadIdx.x;
  __shared__ float hrow[D_];
  __shared__ float wts[32];
  __shared__ float red[4];
  __shared__ float red2[8];
  const float* hr = hl1 + (size_t)blk * D_;
  float2 v = *(const float2*)(hr + 2 * t);
  hrow[2 * t] = v.x;
  hrow[2 * t + 1] = v.y;
  float sd = v.x * v.x + v.y * v.y;
#pragma unroll
  for (int o = 32; o; o >>= 1) sd += __shfl_xor(sd, o);
  int w = t >> 6;
  if ((t & 63) == 0) red[w] = sd;
  __syncthreads();
  int j = t >> 4, p = t & 15;
  const bf16_t* arow = aW + ((size_t)b * A_ + j * 64 + c) * D_;
  float partial = 0.f;
#pragma unroll
  for (int kk = 0; kk < 16; ++kk) {
    int k = p * 32 + 2 * ((kk + p) & 15);
    bf16x2 a2 = *(const bf16x2*)(arow + k);
    partial += hrow[k] * b2f(a2.x) + hrow[k + 1] * b2f(a2.y);
  }
#pragma unroll
  for (int o = 8; o; o >>= 1) partial += __shfl_xor(partial, o);
  if (p == 0) wts[j] = partial * INV_SD;
  if (t == 0) wts[16] = ((red[0] + red[1]) + (red[2] + red[3])) * INV_SD;
  __syncthreads();
  if (t < 64) {
    float val = (t < 17) ? wts[t] : -3.0e38f;
    float m = val;
#pragma unroll
    for (int o = 32; o; o >>= 1) m = fmaxf(m, __shfl_xor(m, o));
    float e = (t < 17) ? __expf(val - m) : 0.f;
    float ssum = e;
#pragma unroll
    for (int o = 32; o; o >>= 1) ssum += __shfl_xor(ssum, o);
    if (t < 17) wts[t] = e / ssum;
  }
  __syncthreads();
  int d = 2 * t;
  float accx = wts[16] * hrow[d];
  float accy = wts[16] * hrow[d + 1];
#pragma unroll 4
  for (int jj = 0; jj < 16; ++jj) {
    bf16x2 a2 = *(const bf16x2*)(aW + ((size_t)b * A_ + jj * 64 + c) * D_ + d);
    accx += wts[jj] * b2f(a2.x);
    accy += wts[jj] * b2f(a2.y);
  }
  // fused LN22
  float s = accx + accy, q = accx * accx + accy * accy;
#pragma unroll
  for (int o = 32; o; o >>= 1) { s += __shfl_xor(s, o); q += __shfl_xor(q, o); }
  int lane = t & 63;
  if (lane == 0) { red2[w] = s; red2[4 + w] = q; }
  __syncthreads();
  float S = (red2[0] + red2[1]) + (red2[2] + red2[3]);
  float Q = (red2[4] + red2[5]) + (red2[6] + red2[7]);
  float mu = S * (1.0f / D_);
  float rs = rsqrtf(Q * (1.0f / D_) - mu * mu + 1e-5f);
  bf16x2 ob;
  ob.x = f2b((accx - mu) * rs * lw[d] + lb[d]);
  ob.y = f2b((accy - mu) * rs * lw[d + 1] + lb[d + 1]);
  *(bf16x2*)(hlnb + (size_t)blk * D_ + d) = ob;
}

extern "C" void kernel_launch(void* const* d_in, const int* in_sizes, int n_in,
                              void* d_out, int out_size, void* d_ws, size_t ws_size,
                              hipStream_t stream) {
  const float* att_vf = (const float*)d_in[0];
  const float* W1_h2h = (const float*)d_in[4];
  const float* W1_h2a = (const float*)d_in[5];
  const float* ln11w = (const float*)d_in[6];
  const float* ln11b = (const float*)d_in[7];
  const float* ln12w = (const float*)d_in[8];
  const float* ln12b = (const float*)d_in[9];
  const float* ln13w = (const float*)d_in[10];
  const float* ln13b = (const float*)d_in[11];
  const float* W2_a2h = (const float*)d_in[12];
  const float* W2_h2h = (const float*)d_in[13];
  const float* W2_h2a = (const float*)d_in[14];
  const float* ln21w = (const float*)d_in[15];
  const float* ln21b = (const float*)d_in[16];
  const float* ln22w = (const float*)d_in[17];
  const float* ln22b = (const float*)d_in[18];
  const float* ln23w = (const float*)d_in[19];
  const float* ln23b = (const float*)d_in[20];
  float* out = (float*)d_out;

  float* ws = (float*)d_ws;
  const size_t SMALL = (size_t)B_ * C_ * D_;  // 2097152 elems
  float* A3 = ws;                               // hl1 / hl2' f32 (SMALL)
  bf16_t* A1b = (bf16_t*)(A3 + SMALL);          // hln bf16 (SMALL/2 floats)
  bf16_t* A1t = (bf16_t*)((float*)A1b + SMALL / 2);
  bf16_t* A2b = (bf16_t*)((float*)A1t + SMALL / 2);
  bf16_t* Wt0 = (bf16_t*)((float*)A2b + SMALL / 2);
  const size_t WTF = (size_t)512 * 512 / 2;  // floats per Wt
  bf16_t* Wt_h2h1 = Wt0;
  bf16_t* Wt_h2a1 = (bf16_t*)((float*)Wt0 + WTF);
  bf16_t* Wt_a2h = (bf16_t*)((float*)Wt0 + 2 * WTF);
  bf16_t* Wt_h2h2 = (bf16_t*)((float*)Wt0 + 3 * WTF);
  bf16_t* Wt_h2a2 = (bf16_t*)((float*)Wt0 + 4 * WTF);
  bf16_t* att1b = (bf16_t*)((float*)Wt0 + 5 * WTF);          // B*A*D bf16
  bf16_t* Abf = (bf16_t*)((float*)att1b + (size_t)B_ * A_ * D_ / 2);  // B*A*D bf16
  float* chunk0 = (float*)Abf + (size_t)B_ * A_ * D_ / 2;

  size_t base_floats = (size_t)(chunk0 - ws);
  size_t ws_floats = ws_size / 4;
  const size_t PERB = (size_t)A_ * D_ / 2;  // aWb bf16 floats per batch
  int CB = 1;
  if (ws_floats > base_floats) {
    size_t cap = (ws_floats - base_floats) / PERB;
    CB = (int)(cap > 64 ? 64 : (cap < 1 ? 1 : cap));
  }
  int cb = 1;
  while (cb * 2 <= CB && cb * 2 <= 64) cb *= 2;
  CB = cb;
  int nchunks = B_ / CB;
  bf16_t* aWb = (bf16_t*)chunk0;

  dim3 blk(256);
  // weight prep (one kernel, 5 weights)
  k_wt5<<<dim3(8, 8, 5), blk, 0, stream>>>(W1_h2h, W1_h2a, W2_a2h, W2_h2h, W2_h2a, Wt0);

  // ---- layer 1 ----
  k_hl0<<<B_ * C_, blk, 0, stream>>>(att_vf, ln11w, ln11b, ln12w, ln12b, A1b);  // hln1
  k_tr<<<dim3(8, B_), blk, 0, stream>>>(A1b, A1t);
  k_mfma_gemm<64><<<256, blk, 0, stream>>>(A1b, Wt_h2h1, A2b);  // hide
  k_h2h<<<dim3(4, B_), blk, 0, stream>>>(A2b, A1t, A3);         // hl1 f32
  k_lnb<<<(B_ * C_) / 4, blk, 0, stream>>>(A3, ln13w, ln13b, A1b);  // ln13
  k_mfma_gemm<64><<<256, blk, 0, stream>>>(A1b, Wt_h2a1, A2b);  // hW1
  k_h2a_ln<<<(B_ * A_) / 4, blk, 0, stream>>>(att_vf, A2b, ln21w, ln21b, att1b, Abf);
  // ---- layer 2: a2h attention (chunked over batches) ----
  for (int ch = 0; ch < nchunks; ++ch) {
    size_t b0 = (size_t)ch * CB;
    k_mfma_gemm<128><<<CB * 32, blk, 0, stream>>>(Abf + b0 * A_ * D_, Wt_a2h, aWb);
    k_a2h_ln<<<CB * C_, blk, 0, stream>>>(A3 + b0 * C_ * D_, aWb, ln22w, ln22b,
                                          A1b + b0 * C_ * D_);  // hln22 bf16
  }
  // h2h #2
  k_tr<<<dim3(8, B_), blk, 0, stream>>>(A1b, A1t);
  k_mfma_gemm<64><<<256, blk, 0, stream>>>(A1b, Wt_h2h2, A2b);  // hide2
  k_h2h<<<dim3(4, B_), blk, 0, stream>>>(A2b, A1t, A3);         // hl2' f32
  k_lnb<<<(B_ * C_) / 4, blk, 0, stream>>>(A3, ln23w, ln23b, A1b);  // ln23
  k_mfma_gemm<64><<<256, blk, 0, stream>>>(A1b, Wt_h2a2, A2b);  // hW2
  k_h2a_out<<<(B_ * A_) / 4, blk, 0, stream>>>(att1b, A2b, out);
}

// Round 6
// 208.548 us; speedup vs baseline: 8.0686x; 1.4311x over previous
//
#include <hip/hip_runtime.h>

#define B_ 64
#define A_ 1024
#define C_ 64
#define D_ 512
#define INV_SD 0.044194173824159216f

typedef __bf16 bf16_t;
typedef __bf16 bf16x8 __attribute__((ext_vector_type(8)));
typedef __bf16 bf16x2 __attribute__((ext_vector_type(2)));
typedef float f32x4 __attribute__((ext_vector_type(4)));

static __device__ __forceinline__ bf16_t f2b(float x) { return (bf16_t)x; }
static __device__ __forceinline__ float b2f(bf16_t x) { return (float)x; }

// async global->LDS, 16B per lane; LDS dest = wave-uniform base + lane*16 (linear)
static __device__ __forceinline__ void gl_lds16(const void* g, void* l) {
  __builtin_amdgcn_global_load_lds(
      (const __attribute__((address_space(1))) unsigned int*)g,
      (__attribute__((address_space(3))) unsigned int*)l, 16, 0, 0);
}

// ---- fused: per (b,c): stats+LN11 of 16 att rows, avg, LN12 -> hln bf16 ----
__global__ __launch_bounds__(256) void k_hl0(const float* __restrict__ att,
                                             const float* __restrict__ lw1,
                                             const float* __restrict__ lb1,
                                             const float* __restrict__ lw2,
                                             const float* __restrict__ lb2,
                                             bf16_t* __restrict__ hlnb) {
  int blk = blockIdx.x;  // B*C
  int b = blk >> 6, c = blk & 63;
  int t = threadIdx.x;
  int w = t >> 6, lane = t & 63;
  __shared__ float part[4][512];
  __shared__ float reds[8];
  float ps[8] = {0.f, 0.f, 0.f, 0.f, 0.f, 0.f, 0.f, 0.f};
#pragma unroll
  for (int i = 0; i < 4; ++i) {
    int jj = w * 4 + i;
    const float* xr = att + ((size_t)b * A_ + jj * 64 + c) * D_ + lane * 8;
    float4 v1 = *(const float4*)xr;
    float4 v2 = *(const float4*)(xr + 4);
    float v[8] = {v1.x, v1.y, v1.z, v1.w, v2.x, v2.y, v2.z, v2.w};
    float s = 0.f, q = 0.f;
#pragma unroll
    for (int u = 0; u < 8; ++u) { s += v[u]; q += v[u] * v[u]; }
#pragma unroll
    for (int o = 32; o; o >>= 1) { s += __shfl_xor(s, o); q += __shfl_xor(q, o); }
    float mu = s * (1.0f / D_);
    float rs = rsqrtf(q * (1.0f / D_) - mu * mu + 1e-5f);
#pragma unroll
    for (int u = 0; u < 8; ++u) ps[u] += (v[u] - mu) * rs;
  }
#pragma unroll
  for (int u = 0; u < 8; ++u) part[w][lane * 8 + u] = ps[u];
  __syncthreads();
  int d = 2 * t;
  float hx = ((part[0][d] + part[1][d]) + (part[2][d] + part[3][d])) * (1.f / 16.f) * lw1[d] + lb1[d];
  float hy = ((part[0][d + 1] + part[1][d + 1]) + (part[2][d + 1] + part[3][d + 1])) * (1.f / 16.f) * lw1[d + 1] + lb1[d + 1];
  float s = hx + hy, q = hx * hx + hy * hy;
#pragma unroll
  for (int o = 32; o; o >>= 1) { s += __shfl_xor(s, o); q += __shfl_xor(q, o); }
  if (lane == 0) { reds[w] = s; reds[4 + w] = q; }
  __syncthreads();
  float S = (reds[0] + reds[1]) + (reds[2] + reds[3]);
  float Q = (reds[4] + reds[5]) + (reds[6] + reds[7]);
  float mu = S * (1.0f / D_);
  float rs = rsqrtf(Q * (1.0f / D_) - mu * mu + 1e-5f);
  bf16x2 ob;
  ob.x = f2b((hx - mu) * rs * lw2[d] + lb2[d]);
  ob.y = f2b((hy - mu) * rs * lw2[d + 1] + lb2[d + 1]);
  *(bf16x2*)(hlnb + (size_t)blk * D_ + d) = ob;
}

// ---------------- LN row bf16 -> bf16, wave-per-row ----------------
__global__ __launch_bounds__(256) void k_lnb_bf(const bf16_t* __restrict__ x,
                                                const float* __restrict__ lw,
                                                const float* __restrict__ lb,
                                                bf16_t* __restrict__ yb) {
  int t = threadIdx.x;
  int row = blockIdx.x * 4 + (t >> 6);
  int lane = t & 63;
  int d0 = lane * 8;
  bf16x8 xb = *(const bf16x8*)(x + (size_t)row * D_ + d0);
  float v[8];
#pragma unroll
  for (int u = 0; u < 8; ++u) v[u] = b2f(xb[u]);
  float s = 0.f, q = 0.f;
#pragma unroll
  for (int u = 0; u < 8; ++u) { s += v[u]; q += v[u] * v[u]; }
#pragma unroll
  for (int o = 32; o; o >>= 1) { s += __shfl_xor(s, o); q += __shfl_xor(q, o); }
  float mu = s * (1.0f / D_);
  float rs = rsqrtf(q * (1.0f / D_) - mu * mu + 1e-5f);
  float4 w1 = *(const float4*)(lw + d0);
  float4 w2 = *(const float4*)(lw + d0 + 4);
  float4 b1 = *(const float4*)(lb + d0);
  float4 b2 = *(const float4*)(lb + d0 + 4);
  float lwv[8] = {w1.x, w1.y, w1.z, w1.w, w2.x, w2.y, w2.z, w2.w};
  float lbv[8] = {b1.x, b1.y, b1.z, b1.w, b2.x, b2.y, b2.z, b2.w};
  bf16x8 ob;
#pragma unroll
  for (int u = 0; u < 8; ++u) ob[u] = f2b((v[u] - mu) * rs * lwv[u] + lbv[u]);
  *(bf16x8*)(yb + (size_t)row * D_ + d0) = ob;
}

// ---------------- transpose hln bf16 [64][512] -> hlnT [512][64] per batch ----------------
__global__ __launch_bounds__(256) void k_tr(const bf16_t* __restrict__ src,
                                            bf16_t* __restrict__ dst) {
  __shared__ unsigned short sm[64][72];
  int n0 = blockIdx.x;  // 0..7
  int b = blockIdx.y;
  int t = threadIdx.x;
  const bf16_t* sb = src + (size_t)b * C_ * D_;
  bf16_t* db = dst + (size_t)b * D_ * C_;
#pragma unroll
  for (int rep = 0; rep < 2; ++rep) {
    int f = t + rep * 256;
    int r = f >> 3, c8 = f & 7;
    uint4 v = *(const uint4*)(sb + (size_t)r * D_ + n0 * 64 + c8 * 8);
    unsigned int* p = (unsigned int*)&sm[r][c8 * 8];
    p[0] = v.x; p[1] = v.y; p[2] = v.z; p[3] = v.w;
  }
  __syncthreads();
#pragma unroll
  for (int rep = 0; rep < 2; ++rep) {
    int f = t + rep * 256;
    int nr = f >> 3, c8 = f & 7;
    unsigned short tmp[8];
#pragma unroll
    for (int u = 0; u < 8; ++u) tmp[u] = sm[c8 * 8 + u][nr];
    *(uint4*)(db + (size_t)(n0 * 64 + nr) * 64 + c8 * 8) = *(const uint4*)tmp;
  }
}

// ---- weight prep: slots 0-4 transposed Wt[n][k] bf16; slot 5 = raw bf16 of W2_a2h ----
__global__ __launch_bounds__(256) void k_wt6(const float* __restrict__ W0, const float* __restrict__ W1,
                                             const float* __restrict__ W2, const float* __restrict__ W3,
                                             const float* __restrict__ W4, bf16_t* __restrict__ WtBase) {
  __shared__ float tile[64][65];
  const float* Ws[5] = {W0, W1, W2, W3, W4};
  int z = blockIdx.z;
  int k0 = blockIdx.x * 64;
  int n0 = blockIdx.y * 64;
  int t = threadIdx.x;
  int r0 = t >> 6;
  int c = t & 63;
  if (z == 5) {  // raw convert of W2_a2h
    const float* W = Ws[2];
    bf16_t* Wt = WtBase + (size_t)5 * 512 * 512;
#pragma unroll 4
    for (int i = 0; i < 16; ++i) {
      int r = r0 * 16 + i;
      Wt[(size_t)(k0 + r) * 512 + n0 + c] = f2b(W[(size_t)(k0 + r) * 512 + n0 + c]);
    }
    return;
  }
  const float* W = Ws[z];
  bf16_t* Wt = WtBase + (size_t)z * 512 * 512;
#pragma unroll 4
  for (int i = 0; i < 16; ++i) {
    int r = r0 * 16 + i;
    tile[r][c] = W[(size_t)(k0 + r) * 512 + n0 + c];
  }
  __syncthreads();
#pragma unroll 4
  for (int i = 0; i < 16; ++i) {
    int r = r0 * 16 + i;
    Wt[(size_t)(n0 + r) * 512 + k0 + c] = f2b(tile[c][r]);
  }
}

// ---- MFMA GEMM: Cb[M,512] bf16 = Abf[M,512] bf16 @ Wt^T (+ optional bias Rb) ----
template <int BM, bool BIAS>
__global__ __launch_bounds__(256, 4) void k_mfma_gemm(const bf16_t* __restrict__ Abf,
                                                      const bf16_t* __restrict__ Wt,
                                                      const bf16_t* __restrict__ Rb,
                                                      bf16_t* __restrict__ Cmat) {
  constexpr int TR = BM / 32;
  constexpr int ABYTES = BM * 128;
  constexpr int CBYTES = BM * 136 * 2;
  constexpr int SMEM = (ABYTES + 16384 > CBYTES) ? (ABYTES + 16384) : CBYTES;
  __shared__ char smem[SMEM];
  bf16_t* As = (bf16_t*)smem;
  bf16_t* Bs = (bf16_t*)(smem + ABYTES);

  int t = threadIdx.x;
  int lane = t & 63, wave = t >> 6;
  int wr = wave >> 1, wc = wave & 1;
  int lhi = lane >> 4, llo = lane & 15;

  int nwg = gridDim.x;
  int bid = blockIdx.x;
  int tile = (bid & 7) * (nwg >> 3) + (bid >> 3);
  int bm = tile >> 2, bn = tile & 3;

  const bf16_t* Ab = Abf + (size_t)bm * BM * 512;
  const bf16_t* Wb = Wt + (size_t)bn * 128 * 512;

  int l3 = lane >> 3;
  int srcOff = ((lane & 7) ^ l3) * 8;

  auto stage = [&](int k0) {
#pragma unroll
    for (int i = 0; i < BM / 32; ++i) {
      int r0 = wave * (BM / 4) + i * 8;
      gl_lds16(Ab + (size_t)(r0 + l3) * 512 + k0 + srcOff, As + r0 * 64);
    }
#pragma unroll
    for (int i = 0; i < 4; ++i) {
      int r0 = wave * 32 + i * 8;
      gl_lds16(Wb + (size_t)(r0 + l3) * 512 + k0 + srcOff, Bs + r0 * 64);
    }
  };

  f32x4 acc[TR][4] = {};
  stage(0);
  __syncthreads();

  for (int k0 = 0; k0 < 512; k0 += 64) {
#pragma unroll
    for (int kk = 0; kk < 2; ++kk) {
      bf16x8 af[TR], bfr[4];
      int bofs = kk * 64 + lhi * 16;
#pragma unroll
      for (int tr = 0; tr < TR; ++tr) {
        int row = wr * (BM / 2) + tr * 16 + llo;
        af[tr] = *(const bf16x8*)((const char*)As + row * 128 + (bofs ^ ((row & 7) << 4)));
      }
#pragma unroll
      for (int tc = 0; tc < 4; ++tc) {
        int col = wc * 64 + tc * 16 + llo;
        bfr[tc] = *(const bf16x8*)((const char*)Bs + col * 128 + (bofs ^ ((col & 7) << 4)));
      }
#pragma unroll
      for (int tr = 0; tr < TR; ++tr)
#pragma unroll
        for (int tc = 0; tc < 4; ++tc)
          acc[tr][tc] = __builtin_amdgcn_mfma_f32_16x16x32_bf16(af[tr], bfr[tc], acc[tr][tc], 0, 0, 0);
    }
    if (k0 + 64 < 512) {
      __syncthreads();
      stage(k0 + 64);
      __syncthreads();
    }
  }

  __syncthreads();
  bf16_t(*Cs)[136] = (bf16_t(*)[136])smem;
#pragma unroll
  for (int tr = 0; tr < TR; ++tr) {
    int row = wr * (BM / 2) + tr * 16 + lhi * 4;
#pragma unroll
    for (int r = 0; r < 4; ++r)
#pragma unroll
      for (int tc = 0; tc < 4; ++tc) {
        float v = acc[tr][tc][r];
        if constexpr (BIAS)
          v += b2f(Rb[(size_t)(bm * BM + row + r) * 512 + bn * 128 + wc * 64 + tc * 16 + llo]);
        Cs[row + r][wc * 64 + tc * 16 + llo] = f2b(v);
      }
  }
  __syncthreads();
#pragma unroll
  for (int i = 0; i < BM / 16; ++i) {
    int row = i * 16 + wave * 4 + lhi;
    uint4 v = *(const uint4*)(&Cs[row][llo * 8]);
    *(uint4*)(Cmat + (size_t)(bm * BM + row) * 512 + bn * 128 + llo * 8) = v;
  }
}

// ---- fused h2h: gram(MFMA) + softmax + PV(MFMA) + epilogue LN ----
// MODE 0: write hl1f (f32), hl1b (bf16), lnout=LN(hl1) bf16.  MODE 1: lnout only.
template <int MODE>
__global__ __launch_bounds__(256) void k_h2h(const bf16_t* __restrict__ hide,
                                             const bf16_t* __restrict__ hlnT,
                                             const float* __restrict__ lnw,
                                             const float* __restrict__ lnbv,
                                             float* __restrict__ hl1f,
                                             bf16_t* __restrict__ hl1b,
                                             bf16_t* __restrict__ lnout) {
  __shared__ bf16_t hS[8 * 64 * 64];  // 64KB; reused as f32 sf[16][516] in epilogue
  __shared__ float sS[16][68];
  __shared__ bf16_t wS[16 * 64];
  __shared__ float mur[16], rsr[16];

  int q = blockIdx.x;
  int b = blockIdx.y;
  int t = threadIdx.x;
  int lane = t & 63, wave = t >> 6;
  int lhi = lane >> 4, llo = lane & 15;

  const bf16_t* Hb = hide + (size_t)b * C_ * D_;
#pragma unroll
  for (int rep = 0; rep < 16; ++rep) {
    int f = t + rep * 256;
    int row = f >> 6, c16 = f & 63;
    int kc = c16 >> 3, ci = c16 & 7;
    uint4 v = *(const uint4*)(Hb + (size_t)row * 512 + c16 * 8);
    *(uint4*)((char*)hS + kc * 8192 + row * 128 + ((ci * 16) ^ ((row & 7) << 4))) = v;
  }
  __syncthreads();

  {
    f32x4 acc = {};
#pragma unroll
    for (int ks = 0; ks < 16; ++ks) {
      int kc = ks >> 1;
      int bofs = (ks & 1) * 64 + lhi * 16;
      int ra = q * 16 + llo;
      int rb = wave * 16 + llo;
      bf16x8 af = *(const bf16x8*)((const char*)hS + kc * 8192 + ra * 128 + (bofs ^ ((ra & 7) << 4)));
      bf16x8 bf = *(const bf16x8*)((const char*)hS + kc * 8192 + rb * 128 + (bofs ^ ((rb & 7) << 4)));
      acc = __builtin_amdgcn_mfma_f32_16x16x32_bf16(af, bf, acc, 0, 0, 0);
    }
#pragma unroll
    for (int r = 0; r < 4; ++r) sS[lhi * 4 + r][wave * 16 + llo] = acc[r] * INV_SD;
  }
  __syncthreads();

  if (t < 128) {
    int row = t >> 3, sg = t & 7;
    float v[8];
#pragma unroll
    for (int u = 0; u < 8; ++u) v[u] = sS[row][sg * 8 + u];
    float m = v[0];
#pragma unroll
    for (int u = 1; u < 8; ++u) m = fmaxf(m, v[u]);
#pragma unroll
    for (int o = 4; o; o >>= 1) m = fmaxf(m, __shfl_xor(m, o));
    float sum = 0.f;
#pragma unroll
    for (int u = 0; u < 8; ++u) { v[u] = __expf(v[u] - m); sum += v[u]; }
#pragma unroll
    for (int o = 4; o; o >>= 1) sum += __shfl_xor(sum, o);
    float inv = 1.f / sum;
    bf16x8 wv;
#pragma unroll
    for (int u = 0; u < 8; ++u) wv[u] = f2b(v[u] * inv);
    *(bf16x8*)((char*)wS + row * 128 + ((sg * 16) ^ ((row & 7) << 4))) = wv;
  }
  __syncthreads();

  float* sf = (float*)hS;  // [16][516] f32 staging (33KB <= 64KB)
  {
    bf16x8 af[2];
#pragma unroll
    for (int ks = 0; ks < 2; ++ks)
      af[ks] = *(const bf16x8*)((const char*)wS + llo * 128 + (((ks * 64 + lhi * 16)) ^ ((llo & 7) << 4)));
    const bf16_t* Tb = hlnT + (size_t)b * D_ * C_;
#pragma unroll
    for (int nt = 0; nt < 8; ++nt) {
      int dcol = wave * 128 + nt * 16 + llo;
      f32x4 acc = {};
#pragma unroll
      for (int ks = 0; ks < 2; ++ks) {
        bf16x8 bf = *(const bf16x8*)(Tb + (size_t)dcol * 64 + ks * 32 + lhi * 8);
        acc = __builtin_amdgcn_mfma_f32_16x16x32_bf16(af[ks], bf, acc, 0, 0, 0);
      }
#pragma unroll
      for (int r = 0; r < 4; ++r) sf[(lhi * 4 + r) * 516 + dcol] = acc[r];
    }
  }
  __syncthreads();

  // per-row LN stats over 512 cols
  {
    int lr = t >> 4, p = t & 15;
    float s = 0.f, q2 = 0.f;
#pragma unroll 8
    for (int i = 0; i < 32; ++i) {
      float v = sf[lr * 516 + p + 16 * i];
      s += v;
      q2 += v * v;
    }
#pragma unroll
    for (int o = 8; o; o >>= 1) { s += __shfl_xor(s, o); q2 += __shfl_xor(q2, o); }
    if (p == 0) {
      float mu = s * (1.0f / D_);
      mur[lr] = mu;
      rsr[lr] = rsqrtf(q2 * (1.0f / D_) - mu * mu + 1e-5f);
    }
  }
  __syncthreads();

  int d = 2 * t;
  float lwx = lnw[d], lwy = lnw[d + 1], lbx = lnbv[d], lby = lnbv[d + 1];
#pragma unroll 4
  for (int r = 0; r < 16; ++r) {
    float2 xy = *(const float2*)(&sf[r * 516 + d]);
    size_t go = ((size_t)b * C_ + q * 16 + r) * 512 + d;
    float mu = mur[r], rs = rsr[r];
    if constexpr (MODE == 0) {
      *(float2*)(hl1f + go) = xy;
      bf16x2 hb;
      hb.x = f2b(xy.x);
      hb.y = f2b(xy.y);
      *(bf16x2*)(hl1b + go) = hb;
    }
    bf16x2 lb2;
    lb2.x = f2b((xy.x - mu) * rs * lwx + lbx);
    lb2.y = f2b((xy.y - mu) * rs * lwy + lby);
    *(bf16x2*)(lnout + go) = lb2;
  }
}

// ---- h2a #1: att f32 in; out att1 bf16 + per-row LN21 stats ----
__global__ __launch_bounds__(256) void k_h2a_ln(const float* __restrict__ att,
                                                const bf16_t* __restrict__ hW,
                                                bf16_t* __restrict__ att1b,
                                                float* __restrict__ stats) {
  int t = threadIdx.x;
  int row = blockIdx.x * 4 + (t >> 6);
  int lane = t & 63;
  int b = row >> 10, a = row & 1023;
  int c = a & 63;
  int d0 = lane * 8;
  const float* ar = att + (size_t)row * D_ + d0;
  const bf16_t* wr = hW + (size_t)(b * 64 + c) * D_ + d0;
  float4 a1 = *(const float4*)ar;
  float4 a2 = *(const float4*)(ar + 4);
  bf16x8 wb = *(const bf16x8*)wr;
  float w[8], av[8] = {a1.x, a1.y, a1.z, a1.w, a2.x, a2.y, a2.z, a2.w};
#pragma unroll
  for (int u = 0; u < 8; ++u) w[u] = b2f(wb[u]);
  float d1 = 0.f, d2 = 0.f;
#pragma unroll
  for (int u = 0; u < 8; ++u) { d1 += av[u] * w[u]; d2 += av[u] * av[u]; }
#pragma unroll
  for (int o = 32; o; o >>= 1) { d1 += __shfl_xor(d1, o); d2 += __shfl_xor(d2, o); }
  float s1 = d1 * INV_SD, s2 = d2 * INV_SD;
  float m = fmaxf(s1, s2);
  float e1 = __expf(s1 - m), e2 = __expf(s2 - m);
  float inv = 1.f / (e1 + e2);
  float alpha = e1 * inv, beta = e2 * inv;
  float o8[8];
  float s = 0.f, q = 0.f;
#pragma unroll
  for (int u = 0; u < 8; ++u) {
    o8[u] = alpha * w[u] + beta * av[u];
    s += o8[u];
    q += o8[u] * o8[u];
  }
  bf16x8 ob;
#pragma unroll
  for (int u = 0; u < 8; ++u) ob[u] = f2b(o8[u]);
  *(bf16x8*)(att1b + (size_t)row * D_ + d0) = ob;
#pragma unroll
  for (int o = 32; o; o >>= 1) { s += __shfl_xor(s, o); q += __shfl_xor(q, o); }
  if (lane == 0) {
    float mu = s * (1.0f / D_);
    stats[2 * row] = mu;
    stats[2 * row + 1] = rsqrtf(q * (1.0f / D_) - mu * mu + 1e-5f);
  }
}

// ---- h2a #2 (final): att1 bf16 in, out f32 ----
__global__ __launch_bounds__(256) void k_h2a_out(const bf16_t* __restrict__ att,
                                                 const bf16_t* __restrict__ hW,
                                                 float* __restrict__ outp) {
  int t = threadIdx.x;
  int row = blockIdx.x * 4 + (t >> 6);
  int lane = t & 63;
  int b = row >> 10, a = row & 1023;
  int c = a & 63;
  int d0 = lane * 8;
  bf16x8 ab = *(const bf16x8*)(att + (size_t)row * D_ + d0);
  bf16x8 wb = *(const bf16x8*)(hW + (size_t)(b * 64 + c) * D_ + d0);
  float av[8], w[8];
#pragma unroll
  for (int u = 0; u < 8; ++u) { av[u] = b2f(ab[u]); w[u] = b2f(wb[u]); }
  float d1 = 0.f, d2 = 0.f;
#pragma unroll
  for (int u = 0; u < 8; ++u) { d1 += av[u] * w[u]; d2 += av[u] * av[u]; }
#pragma unroll
  for (int o = 32; o; o >>= 1) { d1 += __shfl_xor(d1, o); d2 += __shfl_xor(d2, o); }
  float s1 = d1 * INV_SD, s2 = d2 * INV_SD;
  float m = fmaxf(s1, s2);
  float e1 = __expf(s1 - m), e2 = __expf(s2 - m);
  float inv = 1.f / (e1 + e2);
  float alpha = e1 * inv, beta = e2 * inv;
  float4 o1, o2;
  o1.x = alpha * w[0] + beta * av[0]; o1.y = alpha * w[1] + beta * av[1];
  o1.z = alpha * w[2] + beta * av[2]; o1.w = alpha * w[3] + beta * av[3];
  o2.x = alpha * w[4] + beta * av[4]; o2.y = alpha * w[5] + beta * av[5];
  o2.z = alpha * w[6] + beta * av[6]; o2.w = alpha * w[7] + beta * av[7];
  float* orow = outp + (size_t)row * D_ + d0;
  *(float4*)orow = o1;
  *(float4*)(orow + 4) = o2;
}

// ---- layer2 a2h via linearity: per (b,c): scores attln_j·G, softmax(17),
//      u = sum_j p_j*attln_j (bf16), R = p_self*hl1 (bf16) ----
__global__ __launch_bounds__(256) void k_a2h_u(const float* __restrict__ hl1f,
                                               const bf16_t* __restrict__ G,
                                               const bf16_t* __restrict__ att1b,
                                               const float* __restrict__ stats,
                                               const float* __restrict__ lw,
                                               const float* __restrict__ lb,
                                               bf16_t* __restrict__ u_out,
                                               bf16_t* __restrict__ R_out) {
  int blk = blockIdx.x;  // B*C
  int b = blk >> 6, c = blk & 63;
  int t = threadIdx.x;
  int wave = t >> 6, lane = t & 63;
  __shared__ float hrow[512], grow[512], lwS[512], lbS[512];
  __shared__ bf16_t lnS[16][512];
  __shared__ float wts[32];
  __shared__ float red[4];
  {
    int d = 2 * t;
    float2 h2 = *(const float2*)(hl1f + (size_t)blk * 512 + d);
    hrow[d] = h2.x;
    hrow[d + 1] = h2.y;
    bf16x2 g2 = *(const bf16x2*)(G + (size_t)blk * 512 + d);
    grow[d] = b2f(g2.x);
    grow[d + 1] = b2f(g2.y);
    float2 w2 = *(const float2*)(lw + d);
    lwS[d] = w2.x;
    lwS[d + 1] = w2.y;
    float2 bb = *(const float2*)(lb + d);
    lbS[d] = bb.x;
    lbS[d + 1] = bb.y;
    float sd = h2.x * h2.x + h2.y * h2.y;
#pragma unroll
    for (int o = 32; o; o >>= 1) sd += __shfl_xor(sd, o);
    if (lane == 0) red[wave] = sd;
  }
  __syncthreads();
  // 16 dots: wave handles j = wave*4 + i
#pragma unroll
  for (int i = 0; i < 4; ++i) {
    int j = wave * 4 + i;
    size_t row = (size_t)b * A_ + j * 64 + c;
    float mu = stats[2 * row], rs = stats[2 * row + 1];
    bf16x8 x = *(const bf16x8*)(att1b + row * 512 + lane * 8);
    float dot = 0.f;
    bf16x8 lnv;
#pragma unroll
    for (int u = 0; u < 8; ++u) {
      int k = lane * 8 + u;
      float v = (b2f(x[u]) - mu) * rs * lwS[k] + lbS[k];
      lnv[u] = f2b(v);
      dot += v * grow[k];
    }
    *(bf16x8*)(&lnS[j][lane * 8]) = lnv;
#pragma unroll
    for (int o = 32; o; o >>= 1) dot += __shfl_xor(dot, o);
    if (lane == 0) wts[j] = dot * INV_SD;
  }
  if (t == 0) wts[16] = ((red[0] + red[1]) + (red[2] + red[3])) * INV_SD;
  __syncthreads();
  if (t < 64) {
    float val = (t < 17) ? wts[t] : -3.0e38f;
    float m = val;
#pragma unroll
    for (int o = 32; o; o >>= 1) m = fmaxf(m, __shfl_xor(m, o));
    float e = (t < 17) ? __expf(val - m) : 0.f;
    float ssum = e;
#pragma unroll
    for (int o = 32; o; o >>= 1) ssum += __shfl_xor(ssum, o);
    if (t < 17) wts[t] = e / ssum;
  }
  __syncthreads();
  int d = 2 * t;
  float ux = 0.f, uy = 0.f;
#pragma unroll 4
  for (int jj = 0; jj < 16; ++jj) {
    bf16x2 l2 = *(const bf16x2*)(&lnS[jj][d]);
    ux += wts[jj] * b2f(l2.x);
    uy += wts[jj] * b2f(l2.y);
  }
  bf16x2 uo, ro;
  uo.x = f2b(ux);
  uo.y = f2b(uy);
  *(bf16x2*)(u_out + (size_t)blk * 512 + d) = uo;
  float w16 = wts[16];
  ro.x = f2b(w16 * hrow[d]);
  ro.y = f2b(w16 * hrow[d + 1]);
  *(bf16x2*)(R_out + (size_t)blk * 512 + d) = ro;
}

extern "C" void kernel_launch(void* const* d_in, const int* in_sizes, int n_in,
                              void* d_out, int out_size, void* d_ws, size_t ws_size,
                              hipStream_t stream) {
  const float* att_vf = (const float*)d_in[0];
  const float* W1_h2h = (const float*)d_in[4];
  const float* W1_h2a = (const float*)d_in[5];
  const float* ln11w = (const float*)d_in[6];
  const float* ln11b = (const float*)d_in[7];
  const float* ln12w = (const float*)d_in[8];
  const float* ln12b = (const float*)d_in[9];
  const float* ln13w = (const float*)d_in[10];
  const float* ln13b = (const float*)d_in[11];
  const float* W2_a2h = (const float*)d_in[12];
  const float* W2_h2h = (const float*)d_in[13];
  const float* W2_h2a = (const float*)d_in[14];
  const float* ln21w = (const float*)d_in[15];
  const float* ln21b = (const float*)d_in[16];
  const float* ln22w = (const float*)d_in[17];
  const float* ln22b = (const float*)d_in[18];
  const float* ln23w = (const float*)d_in[19];
  const float* ln23b = (const float*)d_in[20];
  float* out = (float*)d_out;

  float* ws = (float*)d_ws;
  const size_t SM = (size_t)B_ * C_ * D_;  // 2097152 elems
  float* hl1f = ws;                                   // f32 [B*C*D]
  bf16_t* A1b = (bf16_t*)(hl1f + SM);                 // hln bf16
  bf16_t* A1t = (bf16_t*)((float*)A1b + SM / 2);      // hlnT bf16
  bf16_t* A2b = (bf16_t*)((float*)A1t + SM / 2);      // gemm out bf16
  bf16_t* hl1b = (bf16_t*)((float*)A2b + SM / 2);     // hl1 bf16
  bf16_t* u_b = (bf16_t*)((float*)hl1b + SM / 2);     // u bf16
  bf16_t* R_b = (bf16_t*)((float*)u_b + SM / 2);      // R bf16
  bf16_t* Wt0 = (bf16_t*)((float*)R_b + SM / 2);      // 6 weight slots
  const size_t WTE = (size_t)512 * 512;               // elems per slot
  bf16_t* att1b = Wt0 + 6 * WTE;                      // B*A*D bf16
  float* stats = (float*)(att1b + (size_t)B_ * A_ * D_);  // 2*B*A f32

  dim3 blk(256);
  // weight prep
  k_wt6<<<dim3(8, 8, 6), blk, 0, stream>>>(W1_h2h, W1_h2a, W2_a2h, W2_h2h, W2_h2a, Wt0);

  // ---- layer 1 ----
  k_hl0<<<B_ * C_, blk, 0, stream>>>(att_vf, ln11w, ln11b, ln12w, ln12b, A1b);  // ln12
  k_tr<<<dim3(8, B_), blk, 0, stream>>>(A1b, A1t);
  k_mfma_gemm<64, false><<<256, blk, 0, stream>>>(A1b, Wt0 + 0 * WTE, nullptr, A2b);  // hide1
  k_h2h<0><<<dim3(4, B_), blk, 0, stream>>>(A2b, A1t, ln13w, ln13b, hl1f, hl1b, A1b);  // hl1 + ln13
  k_mfma_gemm<64, false><<<256, blk, 0, stream>>>(A1b, Wt0 + 1 * WTE, nullptr, A2b);  // hW1
  k_h2a_ln<<<(B_ * A_) / 4, blk, 0, stream>>>(att_vf, A2b, att1b, stats);  // att1 + stats
  // ---- layer 2: a2h via linearity ----
  k_mfma_gemm<64, false><<<256, blk, 0, stream>>>(hl1b, Wt0 + 5 * WTE, nullptr, A2b);  // G = hl1@W^T
  k_a2h_u<<<B_ * C_, blk, 0, stream>>>(hl1f, A2b, att1b, stats, ln21w, ln21b, u_b, R_b);
  k_mfma_gemm<64, true><<<256, blk, 0, stream>>>(u_b, Wt0 + 2 * WTE, R_b, A2b);  // hl2 = u@W + R
  k_lnb_bf<<<(B_ * C_) / 4, blk, 0, stream>>>(A2b, ln22w, ln22b, A1b);  // ln22
  // h2h #2
  k_tr<<<dim3(8, B_), blk, 0, stream>>>(A1b, A1t);
  k_mfma_gemm<64, false><<<256, blk, 0, stream>>>(A1b, Wt0 + 3 * WTE, nullptr, A2b);  // hide2
  k_h2h<1><<<dim3(4, B_), blk, 0, stream>>>(A2b, A1t, ln23w, ln23b, nullptr, nullptr, A1b);  // ln23
  k_mfma_gemm<64, false><<<256, blk, 0, stream>>>(A1b, Wt0 + 4 * WTE, nullptr, A2b);  // hW2
  k_h2a_out<<<(B_ * A_) / 4, blk, 0, stream>>>(att1b, A2b, out);
}

// Round 7
// 207.594 us; speedup vs baseline: 8.1057x; 1.0046x over previous
//
#include <hip/hip_runtime.h>

#define B_ 64
#define A_ 1024
#define C_ 64
#define D_ 512
#define INV_SD 0.044194173824159216f

typedef __bf16 bf16_t;
typedef __bf16 bf16x8 __attribute__((ext_vector_type(8)));
typedef __bf16 bf16x2 __attribute__((ext_vector_type(2)));
typedef float f32x4 __attribute__((ext_vector_type(4)));

static __device__ __forceinline__ bf16_t f2b(float x) { return (bf16_t)x; }
static __device__ __forceinline__ float b2f(bf16_t x) { return (float)x; }

// async global->LDS, 16B per lane; LDS dest = wave-uniform base + lane*16 (linear)
static __device__ __forceinline__ void gl_lds16(const void* g, void* l) {
  __builtin_amdgcn_global_load_lds(
      (const __attribute__((address_space(1))) unsigned int*)g,
      (__attribute__((address_space(3))) unsigned int*)l, 16, 0, 0);
}

// ---- fused: per (b,c): stats+LN11 of 16 att rows, avg, LN12 -> hln bf16 ----
__global__ __launch_bounds__(256) void k_hl0(const float* __restrict__ att,
                                             const float* __restrict__ lw1,
                                             const float* __restrict__ lb1,
                                             const float* __restrict__ lw2,
                                             const float* __restrict__ lb2,
                                             bf16_t* __restrict__ hlnb) {
  int blk = blockIdx.x;  // B*C
  int b = blk >> 6, c = blk & 63;
  int t = threadIdx.x;
  int w = t >> 6, lane = t & 63;
  __shared__ float part[4][512];
  __shared__ float reds[8];
  float ps[8] = {0.f, 0.f, 0.f, 0.f, 0.f, 0.f, 0.f, 0.f};
#pragma unroll
  for (int i = 0; i < 4; ++i) {
    int jj = w * 4 + i;
    const float* xr = att + ((size_t)b * A_ + jj * 64 + c) * D_ + lane * 8;
    float4 v1 = *(const float4*)xr;
    float4 v2 = *(const float4*)(xr + 4);
    float v[8] = {v1.x, v1.y, v1.z, v1.w, v2.x, v2.y, v2.z, v2.w};
    float s = 0.f, q = 0.f;
#pragma unroll
    for (int u = 0; u < 8; ++u) { s += v[u]; q += v[u] * v[u]; }
#pragma unroll
    for (int o = 32; o; o >>= 1) { s += __shfl_xor(s, o); q += __shfl_xor(q, o); }
    float mu = s * (1.0f / D_);
    float rs = rsqrtf(q * (1.0f / D_) - mu * mu + 1e-5f);
#pragma unroll
    for (int u = 0; u < 8; ++u) ps[u] += (v[u] - mu) * rs;
  }
#pragma unroll
  for (int u = 0; u < 8; ++u) part[w][lane * 8 + u] = ps[u];
  __syncthreads();
  int d = 2 * t;
  float hx = ((part[0][d] + part[1][d]) + (part[2][d] + part[3][d])) * (1.f / 16.f) * lw1[d] + lb1[d];
  float hy = ((part[0][d + 1] + part[1][d + 1]) + (part[2][d + 1] + part[3][d + 1])) * (1.f / 16.f) * lw1[d + 1] + lb1[d + 1];
  float s = hx + hy, q = hx * hx + hy * hy;
#pragma unroll
  for (int o = 32; o; o >>= 1) { s += __shfl_xor(s, o); q += __shfl_xor(q, o); }
  if (lane == 0) { reds[w] = s; reds[4 + w] = q; }
  __syncthreads();
  float S = (reds[0] + reds[1]) + (reds[2] + reds[3]);
  float Q = (reds[4] + reds[5]) + (reds[6] + reds[7]);
  float mu = S * (1.0f / D_);
  float rs = rsqrtf(Q * (1.0f / D_) - mu * mu + 1e-5f);
  bf16x2 ob;
  ob.x = f2b((hx - mu) * rs * lw2[d] + lb2[d]);
  ob.y = f2b((hy - mu) * rs * lw2[d + 1] + lb2[d + 1]);
  *(bf16x2*)(hlnb + (size_t)blk * D_ + d) = ob;
}

// ---- merged: LN rows of one batch (bf16 in) -> row-major bf16 + transposed bf16 ----
__global__ __launch_bounds__(256) void k_ln_tr(const bf16_t* __restrict__ x,
                                               const float* __restrict__ lw,
                                               const float* __restrict__ lb,
                                               bf16_t* __restrict__ y,
                                               bf16_t* __restrict__ yt) {
  __shared__ bf16_t lnS[64][528];
  int b = blockIdx.x;
  int t = threadIdx.x;
  int wv = t >> 6, lane = t & 63;
  int d0 = lane * 8;
  float4 w1 = *(const float4*)(lw + d0);
  float4 w2 = *(const float4*)(lw + d0 + 4);
  float4 b1 = *(const float4*)(lb + d0);
  float4 b2 = *(const float4*)(lb + d0 + 4);
  float lwv[8] = {w1.x, w1.y, w1.z, w1.w, w2.x, w2.y, w2.z, w2.w};
  float lbv[8] = {b1.x, b1.y, b1.z, b1.w, b2.x, b2.y, b2.z, b2.w};
  const bf16_t* xb = x + (size_t)b * C_ * D_;
  bf16_t* yb = y + (size_t)b * C_ * D_;
#pragma unroll 4
  for (int i = 0; i < 16; ++i) {
    int r = wv * 16 + i;
    bf16x8 xv = *(const bf16x8*)(xb + (size_t)r * D_ + d0);
    float v[8], s = 0.f, q = 0.f;
#pragma unroll
    for (int u = 0; u < 8; ++u) { v[u] = b2f(xv[u]); s += v[u]; q += v[u] * v[u]; }
#pragma unroll
    for (int o = 32; o; o >>= 1) { s += __shfl_xor(s, o); q += __shfl_xor(q, o); }
    float mu = s * (1.0f / D_);
    float rs = rsqrtf(q * (1.0f / D_) - mu * mu + 1e-5f);
    bf16x8 ob;
#pragma unroll
    for (int u = 0; u < 8; ++u) ob[u] = f2b((v[u] - mu) * rs * lwv[u] + lbv[u]);
    *(bf16x8*)(yb + (size_t)r * D_ + d0) = ob;
    *(bf16x8*)(&lnS[r][d0]) = ob;
  }
  __syncthreads();
  bf16_t* tb = yt + (size_t)b * D_ * C_;
#pragma unroll
  for (int pass = 0; pass < 16; ++pass) {
    int d = pass * 32 + (t >> 3);
    int c0 = (t & 7) * 8;
    unsigned short tmp[8];
#pragma unroll
    for (int u = 0; u < 8; ++u) tmp[u] = *(const unsigned short*)&lnS[c0 + u][d];
    *(uint4*)(tb + (size_t)d * 64 + c0) = *(const uint4*)tmp;
  }
}

// ---------------- transpose hln bf16 [64][512] -> hlnT [512][64] per batch ----------------
__global__ __launch_bounds__(256) void k_tr(const bf16_t* __restrict__ src,
                                            bf16_t* __restrict__ dst) {
  __shared__ unsigned short sm[64][72];
  int n0 = blockIdx.x;  // 0..7
  int b = blockIdx.y;
  int t = threadIdx.x;
  const bf16_t* sb = src + (size_t)b * C_ * D_;
  bf16_t* db = dst + (size_t)b * D_ * C_;
#pragma unroll
  for (int rep = 0; rep < 2; ++rep) {
    int f = t + rep * 256;
    int r = f >> 3, c8 = f & 7;
    uint4 v = *(const uint4*)(sb + (size_t)r * D_ + n0 * 64 + c8 * 8);
    unsigned int* p = (unsigned int*)&sm[r][c8 * 8];
    p[0] = v.x; p[1] = v.y; p[2] = v.z; p[3] = v.w;
  }
  __syncthreads();
#pragma unroll
  for (int rep = 0; rep < 2; ++rep) {
    int f = t + rep * 256;
    int nr = f >> 3, c8 = f & 7;
    unsigned short tmp[8];
#pragma unroll
    for (int u = 0; u < 8; ++u) tmp[u] = sm[c8 * 8 + u][nr];
    *(uint4*)(db + (size_t)(n0 * 64 + nr) * 64 + c8 * 8) = *(const uint4*)tmp;
  }
}

// ---- weight prep: slots 0-4 transposed Wt[n][k] bf16; slot 5 = raw bf16 of W2_a2h ----
__global__ __launch_bounds__(256) void k_wt6(const float* __restrict__ W0, const float* __restrict__ W1,
                                             const float* __restrict__ W2, const float* __restrict__ W3,
                                             const float* __restrict__ W4, bf16_t* __restrict__ WtBase) {
  __shared__ float tile[64][65];
  const float* Ws[5] = {W0, W1, W2, W3, W4};
  int z = blockIdx.z;
  int k0 = blockIdx.x * 64;
  int n0 = blockIdx.y * 64;
  int t = threadIdx.x;
  int r0 = t >> 6;
  int c = t & 63;
  if (z == 5) {  // raw convert of W2_a2h
    const float* W = Ws[2];
    bf16_t* Wt = WtBase + (size_t)5 * 512 * 512;
#pragma unroll 4
    for (int i = 0; i < 16; ++i) {
      int r = r0 * 16 + i;
      Wt[(size_t)(k0 + r) * 512 + n0 + c] = f2b(W[(size_t)(k0 + r) * 512 + n0 + c]);
    }
    return;
  }
  const float* W = Ws[z];
  bf16_t* Wt = WtBase + (size_t)z * 512 * 512;
#pragma unroll 4
  for (int i = 0; i < 16; ++i) {
    int r = r0 * 16 + i;
    tile[r][c] = W[(size_t)(k0 + r) * 512 + n0 + c];
  }
  __syncthreads();
#pragma unroll 4
  for (int i = 0; i < 16; ++i) {
    int r = r0 * 16 + i;
    Wt[(size_t)(n0 + r) * 512 + k0 + c] = f2b(tile[c][r]);
  }
}

// ---- MFMA GEMM (double-buffered LDS, one barrier per K-step):
//      Cb[M,512] bf16 = Abf[M,512] bf16 @ Wt^T (+ optional bias Rb) ----
template <int BM, bool BIAS>
__global__ __launch_bounds__(256, 3) void k_mfma_gemm(const bf16_t* __restrict__ Abf,
                                                      const bf16_t* __restrict__ Wt,
                                                      const bf16_t* __restrict__ Rb,
                                                      bf16_t* __restrict__ Cmat) {
  constexpr int TR = BM / 32;
  constexpr int ABYTES = BM * 128;   // BM x 64 bf16
  constexpr int BBYTES = 128 * 128;  // 128 x 64 bf16
  constexpr int BUF = ABYTES + BBYTES;
  __shared__ char smem[2 * BUF];  // 48KB @ BM=64; epilogue Cs aliases

  int t = threadIdx.x;
  int lane = t & 63, wave = t >> 6;
  int wr = wave >> 1, wc = wave & 1;
  int lhi = lane >> 4, llo = lane & 15;

  int nwg = gridDim.x;
  int bid = blockIdx.x;
  int tile = (bid & 7) * (nwg >> 3) + (bid >> 3);
  int bm = tile >> 2, bn = tile & 3;

  const bf16_t* Ab = Abf + (size_t)bm * BM * 512;
  const bf16_t* Wb = Wt + (size_t)bn * 128 * 512;

  int l3 = lane >> 3;
  int srcOff = ((lane & 7) ^ l3) * 8;  // pre-swizzled source (rule 21)

  auto stage = [&](int k0, int bi) {
    char* As = smem + bi * BUF;
    char* Bs = As + ABYTES;
#pragma unroll
    for (int i = 0; i < BM / 32; ++i) {
      int r0 = wave * (BM / 4) + i * 8;
      gl_lds16(Ab + (size_t)(r0 + l3) * 512 + k0 + srcOff, As + r0 * 128);
    }
#pragma unroll
    for (int i = 0; i < 4; ++i) {
      int r0 = wave * 32 + i * 8;
      gl_lds16(Wb + (size_t)(r0 + l3) * 512 + k0 + srcOff, Bs + r0 * 128);
    }
  };

  f32x4 acc[TR][4] = {};
  stage(0, 0);
  __syncthreads();

  for (int it = 0; it < 8; ++it) {
    int cur = it & 1;
    if (it < 7) stage((it + 1) * 64, cur ^ 1);  // issue BEFORE compute (overlap)
    const char* As = smem + cur * BUF;
    const char* Bs = As + ABYTES;
#pragma unroll
    for (int kk = 0; kk < 2; ++kk) {
      bf16x8 af[TR], bfr[4];
      int bofs = kk * 64 + lhi * 16;
#pragma unroll
      for (int tr = 0; tr < TR; ++tr) {
        int row = wr * (BM / 2) + tr * 16 + llo;
        af[tr] = *(const bf16x8*)(As + row * 128 + (bofs ^ ((row & 7) << 4)));
      }
#pragma unroll
      for (int tc = 0; tc < 4; ++tc) {
        int col = wc * 64 + tc * 16 + llo;
        bfr[tc] = *(const bf16x8*)(Bs + col * 128 + (bofs ^ ((col & 7) << 4)));
      }
#pragma unroll
      for (int tr = 0; tr < TR; ++tr)
#pragma unroll
        for (int tc = 0; tc < 4; ++tc)
          acc[tr][tc] = __builtin_amdgcn_mfma_f32_16x16x32_bf16(af[tr], bfr[tc], acc[tr][tc], 0, 0, 0);
    }
    __syncthreads();  // drains vmcnt for next buffer + guards buffer reuse
  }

  bf16_t(*Cs)[136] = (bf16_t(*)[136])smem;
#pragma unroll
  for (int tr = 0; tr < TR; ++tr) {
    int row = wr * (BM / 2) + tr * 16 + lhi * 4;
#pragma unroll
    for (int r = 0; r < 4; ++r)
#pragma unroll
      for (int tc = 0; tc < 4; ++tc) {
        float v = acc[tr][tc][r];
        if constexpr (BIAS)
          v += b2f(Rb[(size_t)(bm * BM + row + r) * 512 + bn * 128 + wc * 64 + tc * 16 + llo]);
        Cs[row + r][wc * 64 + tc * 16 + llo] = f2b(v);
      }
  }
  __syncthreads();
#pragma unroll
  for (int i = 0; i < BM / 16; ++i) {
    int row = i * 16 + wave * 4 + lhi;
    uint4 v = *(const uint4*)(&Cs[row][llo * 8]);
    *(uint4*)(Cmat + (size_t)(bm * BM + row) * 512 + bn * 128 + llo * 8) = v;
  }
}

// ---- fused h2h: gram(MFMA) + softmax + PV(MFMA) + epilogue LN ----
// MODE 0: write hl1f (f32), hl1b (bf16), lnout=LN(hl1) bf16.  MODE 1: lnout only.
template <int MODE>
__global__ __launch_bounds__(256) void k_h2h(const bf16_t* __restrict__ hide,
                                             const bf16_t* __restrict__ hlnT,
                                             const float* __restrict__ lnw,
                                             const float* __restrict__ lnbv,
                                             float* __restrict__ hl1f,
                                             bf16_t* __restrict__ hl1b,
                                             bf16_t* __restrict__ lnout) {
  __shared__ bf16_t hS[8 * 64 * 64];  // 64KB; reused as f32 sf[16][516] in epilogue
  __shared__ float sS[16][68];
  __shared__ bf16_t wS[16 * 64];
  __shared__ float mur[16], rsr[16];

  int q = blockIdx.x;
  int b = blockIdx.y;
  int t = threadIdx.x;
  int lane = t & 63, wave = t >> 6;
  int lhi = lane >> 4, llo = lane & 15;

  const bf16_t* Hb = hide + (size_t)b * C_ * D_;
#pragma unroll
  for (int rep = 0; rep < 16; ++rep) {
    int f = t + rep * 256;
    int row = f >> 6, c16 = f & 63;
    int kc = c16 >> 3, ci = c16 & 7;
    uint4 v = *(const uint4*)(Hb + (size_t)row * 512 + c16 * 8);
    *(uint4*)((char*)hS + kc * 8192 + row * 128 + ((ci * 16) ^ ((row & 7) << 4))) = v;
  }
  __syncthreads();

  {
    f32x4 acc = {};
#pragma unroll
    for (int ks = 0; ks < 16; ++ks) {
      int kc = ks >> 1;
      int bofs = (ks & 1) * 64 + lhi * 16;
      int ra = q * 16 + llo;
      int rb = wave * 16 + llo;
      bf16x8 af = *(const bf16x8*)((const char*)hS + kc * 8192 + ra * 128 + (bofs ^ ((ra & 7) << 4)));
      bf16x8 bf = *(const bf16x8*)((const char*)hS + kc * 8192 + rb * 128 + (bofs ^ ((rb & 7) << 4)));
      acc = __builtin_amdgcn_mfma_f32_16x16x32_bf16(af, bf, acc, 0, 0, 0);
    }
#pragma unroll
    for (int r = 0; r < 4; ++r) sS[lhi * 4 + r][wave * 16 + llo] = acc[r] * INV_SD;
  }
  __syncthreads();

  if (t < 128) {
    int row = t >> 3, sg = t & 7;
    float v[8];
#pragma unroll
    for (int u = 0; u < 8; ++u) v[u] = sS[row][sg * 8 + u];
    float m = v[0];
#pragma unroll
    for (int u = 1; u < 8; ++u) m = fmaxf(m, v[u]);
#pragma unroll
    for (int o = 4; o; o >>= 1) m = fmaxf(m, __shfl_xor(m, o));
    float sum = 0.f;
#pragma unroll
    for (int u = 0; u < 8; ++u) { v[u] = __expf(v[u] - m); sum += v[u]; }
#pragma unroll
    for (int o = 4; o; o >>= 1) sum += __shfl_xor(sum, o);
    float inv = 1.f / sum;
    bf16x8 wv;
#pragma unroll
    for (int u = 0; u < 8; ++u) wv[u] = f2b(v[u] * inv);
    *(bf16x8*)((char*)wS + row * 128 + ((sg * 16) ^ ((row & 7) << 4))) = wv;
  }
  __syncthreads();

  float* sf = (float*)hS;  // [16][516]
  {
    bf16x8 af[2];
#pragma unroll
    for (int ks = 0; ks < 2; ++ks)
      af[ks] = *(const bf16x8*)((const char*)wS + llo * 128 + (((ks * 64 + lhi * 16)) ^ ((llo & 7) << 4)));
    const bf16_t* Tb = hlnT + (size_t)b * D_ * C_;
#pragma unroll
    for (int nt = 0; nt < 8; ++nt) {
      int dcol = wave * 128 + nt * 16 + llo;
      f32x4 acc = {};
#pragma unroll
      for (int ks = 0; ks < 2; ++ks) {
        bf16x8 bf = *(const bf16x8*)(Tb + (size_t)dcol * 64 + ks * 32 + lhi * 8);
        acc = __builtin_amdgcn_mfma_f32_16x16x32_bf16(af[ks], bf, acc, 0, 0, 0);
      }
#pragma unroll
      for (int r = 0; r < 4; ++r) sf[(lhi * 4 + r) * 516 + dcol] = acc[r];
    }
  }
  __syncthreads();

  {
    int lr = t >> 4, p = t & 15;
    float s = 0.f, q2 = 0.f;
#pragma unroll 8
    for (int i = 0; i < 32; ++i) {
      float v = sf[lr * 516 + p + 16 * i];
      s += v;
      q2 += v * v;
    }
#pragma unroll
    for (int o = 8; o; o >>= 1) { s += __shfl_xor(s, o); q2 += __shfl_xor(q2, o); }
    if (p == 0) {
      float mu = s * (1.0f / D_);
      mur[lr] = mu;
      rsr[lr] = rsqrtf(q2 * (1.0f / D_) - mu * mu + 1e-5f);
    }
  }
  __syncthreads();

  int d = 2 * t;
  float lwx = lnw[d], lwy = lnw[d + 1], lbx = lnbv[d], lby = lnbv[d + 1];
#pragma unroll 4
  for (int r = 0; r < 16; ++r) {
    float2 xy = *(const float2*)(&sf[r * 516 + d]);
    size_t go = ((size_t)b * C_ + q * 16 + r) * 512 + d;
    float mu = mur[r], rs = rsr[r];
    if constexpr (MODE == 0) {
      *(float2*)(hl1f + go) = xy;
      bf16x2 hb;
      hb.x = f2b(xy.x);
      hb.y = f2b(xy.y);
      *(bf16x2*)(hl1b + go) = hb;
    }
    bf16x2 lb2;
    lb2.x = f2b((xy.x - mu) * rs * lwx + lbx);
    lb2.y = f2b((xy.y - mu) * rs * lwy + lby);
    *(bf16x2*)(lnout + go) = lb2;
  }
}

// ---- h2a #1: att f32 in; out att1 bf16 + per-row LN21 stats ----
__global__ __launch_bounds__(256) void k_h2a_ln(const float* __restrict__ att,
                                                const bf16_t* __restrict__ hW,
                                                bf16_t* __restrict__ att1b,
                                                float* __restrict__ stats) {
  int t = threadIdx.x;
  int row = blockIdx.x * 4 + (t >> 6);
  int lane = t & 63;
  int b = row >> 10, a = row & 1023;
  int c = a & 63;
  int d0 = lane * 8;
  const float* ar = att + (size_t)row * D_ + d0;
  const bf16_t* wr = hW + (size_t)(b * 64 + c) * D_ + d0;
  float4 a1 = *(const float4*)ar;
  float4 a2 = *(const float4*)(ar + 4);
  bf16x8 wb = *(const bf16x8*)wr;
  float w[8], av[8] = {a1.x, a1.y, a1.z, a1.w, a2.x, a2.y, a2.z, a2.w};
#pragma unroll
  for (int u = 0; u < 8; ++u) w[u] = b2f(wb[u]);
  float d1 = 0.f, d2 = 0.f;
#pragma unroll
  for (int u = 0; u < 8; ++u) { d1 += av[u] * w[u]; d2 += av[u] * av[u]; }
#pragma unroll
  for (int o = 32; o; o >>= 1) { d1 += __shfl_xor(d1, o); d2 += __shfl_xor(d2, o); }
  float s1 = d1 * INV_SD, s2 = d2 * INV_SD;
  float m = fmaxf(s1, s2);
  float e1 = __expf(s1 - m), e2 = __expf(s2 - m);
  float inv = 1.f / (e1 + e2);
  float alpha = e1 * inv, beta = e2 * inv;
  float o8[8];
  float s = 0.f, q = 0.f;
#pragma unroll
  for (int u = 0; u < 8; ++u) {
    o8[u] = alpha * w[u] + beta * av[u];
    s += o8[u];
    q += o8[u] * o8[u];
  }
  bf16x8 ob;
#pragma unroll
  for (int u = 0; u < 8; ++u) ob[u] = f2b(o8[u]);
  *(bf16x8*)(att1b + (size_t)row * D_ + d0) = ob;
#pragma unroll
  for (int o = 32; o; o >>= 1) { s += __shfl_xor(s, o); q += __shfl_xor(q, o); }
  if (lane == 0) {
    float mu = s * (1.0f / D_);
    stats[2 * row] = mu;
    stats[2 * row + 1] = rsqrtf(q * (1.0f / D_) - mu * mu + 1e-5f);
  }
}

// ---- h2a #2 (final): att1 bf16 in, out f32 ----
__global__ __launch_bounds__(256) void k_h2a_out(const bf16_t* __restrict__ att,
                                                 const bf16_t* __restrict__ hW,
                                                 float* __restrict__ outp) {
  int t = threadIdx.x;
  int row = blockIdx.x * 4 + (t >> 6);
  int lane = t & 63;
  int b = row >> 10, a = row & 1023;
  int c = a & 63;
  int d0 = lane * 8;
  bf16x8 ab = *(const bf16x8*)(att + (size_t)row * D_ + d0);
  bf16x8 wb = *(const bf16x8*)(hW + (size_t)(b * 64 + c) * D_ + d0);
  float av[8], w[8];
#pragma unroll
  for (int u = 0; u < 8; ++u) { av[u] = b2f(ab[u]); w[u] = b2f(wb[u]); }
  float d1 = 0.f, d2 = 0.f;
#pragma unroll
  for (int u = 0; u < 8; ++u) { d1 += av[u] * w[u]; d2 += av[u] * av[u]; }
#pragma unroll
  for (int o = 32; o; o >>= 1) { d1 += __shfl_xor(d1, o); d2 += __shfl_xor(d2, o); }
  float s1 = d1 * INV_SD, s2 = d2 * INV_SD;
  float m = fmaxf(s1, s2);
  float e1 = __expf(s1 - m), e2 = __expf(s2 - m);
  float inv = 1.f / (e1 + e2);
  float alpha = e1 * inv, beta = e2 * inv;
  float4 o1, o2;
  o1.x = alpha * w[0] + beta * av[0]; o1.y = alpha * w[1] + beta * av[1];
  o1.z = alpha * w[2] + beta * av[2]; o1.w = alpha * w[3] + beta * av[3];
  o2.x = alpha * w[4] + beta * av[4]; o2.y = alpha * w[5] + beta * av[5];
  o2.z = alpha * w[6] + beta * av[6]; o2.w = alpha * w[7] + beta * av[7];
  float* orow = outp + (size_t)row * D_ + d0;
  *(float4*)orow = o1;
  *(float4*)(orow + 4) = o2;
}

// ---- layer2 a2h via linearity: per (b,c): scores attln_j·G, softmax(17),
//      u = sum_j p_j*attln_j (bf16), R = p_self*hl1 (bf16) ----
__global__ __launch_bounds__(256) void k_a2h_u(const float* __restrict__ hl1f,
                                               const bf16_t* __restrict__ G,
                                               const bf16_t* __restrict__ att1b,
                                               const float* __restrict__ stats,
                                               const float* __restrict__ lw,
                                               const float* __restrict__ lb,
                                               bf16_t* __restrict__ u_out,
                                               bf16_t* __restrict__ R_out) {
  int blk = blockIdx.x;  // B*C
  int b = blk >> 6, c = blk & 63;
  int t = threadIdx.x;
  int wave = t >> 6, lane = t & 63;
  __shared__ float hrow[512], grow[512], lwS[512], lbS[512];
  __shared__ bf16_t lnS[16][512];
  __shared__ float wts[32];
  __shared__ float red[4];
  {
    int d = 2 * t;
    float2 h2 = *(const float2*)(hl1f + (size_t)blk * 512 + d);
    hrow[d] = h2.x;
    hrow[d + 1] = h2.y;
    bf16x2 g2 = *(const bf16x2*)(G + (size_t)blk * 512 + d);
    grow[d] = b2f(g2.x);
    grow[d + 1] = b2f(g2.y);
    float2 w2 = *(const float2*)(lw + d);
    lwS[d] = w2.x;
    lwS[d + 1] = w2.y;
    float2 bb = *(const float2*)(lb + d);
    lbS[d] = bb.x;
    lbS[d + 1] = bb.y;
    float sd = h2.x * h2.x + h2.y * h2.y;
#pragma unroll
    for (int o = 32; o; o >>= 1) sd += __shfl_xor(sd, o);
    if (lane == 0) red[wave] = sd;
  }
  __syncthreads();
#pragma unroll
  for (int i = 0; i < 4; ++i) {
    int j = wave * 4 + i;
    size_t row = (size_t)b * A_ + j * 64 + c;
    float mu = stats[2 * row], rs = stats[2 * row + 1];
    bf16x8 x = *(const bf16x8*)(att1b + row * 512 + lane * 8);
    float dot = 0.f;
    bf16x8 lnv;
#pragma unroll
    for (int u = 0; u < 8; ++u) {
      int k = lane * 8 + u;
      float v = (b2f(x[u]) - mu) * rs * lwS[k] + lbS[k];
      lnv[u] = f2b(v);
      dot += v * grow[k];
    }
    *(bf16x8*)(&lnS[j][lane * 8]) = lnv;
#pragma unroll
    for (int o = 32; o; o >>= 1) dot += __shfl_xor(dot, o);
    if (lane == 0) wts[j] = dot * INV_SD;
  }
  if (t == 0) wts[16] = ((red[0] + red[1]) + (red[2] + red[3])) * INV_SD;
  __syncthreads();
  if (t < 64) {
    float val = (t < 17) ? wts[t] : -3.0e38f;
    float m = val;
#pragma unroll
    for (int o = 32; o; o >>= 1) m = fmaxf(m, __shfl_xor(m, o));
    float e = (t < 17) ? __expf(val - m) : 0.f;
    float ssum = e;
#pragma unroll
    for (int o = 32; o; o >>= 1) ssum += __shfl_xor(ssum, o);
    if (t < 17) wts[t] = e / ssum;
  }
  __syncthreads();
  int d = 2 * t;
  float ux = 0.f, uy = 0.f;
#pragma unroll 4
  for (int jj = 0; jj < 16; ++jj) {
    bf16x2 l2 = *(const bf16x2*)(&lnS[jj][d]);
    ux += wts[jj] * b2f(l2.x);
    uy += wts[jj] * b2f(l2.y);
  }
  bf16x2 uo, ro;
  uo.x = f2b(ux);
  uo.y = f2b(uy);
  *(bf16x2*)(u_out + (size_t)blk * 512 + d) = uo;
  float w16 = wts[16];
  ro.x = f2b(w16 * hrow[d]);
  ro.y = f2b(w16 * hrow[d + 1]);
  *(bf16x2*)(R_out + (size_t)blk * 512 + d) = ro;
}

extern "C" void kernel_launch(void* const* d_in, const int* in_sizes, int n_in,
                              void* d_out, int out_size, void* d_ws, size_t ws_size,
                              hipStream_t stream) {
  const float* att_vf = (const float*)d_in[0];
  const float* W1_h2h = (const float*)d_in[4];
  const float* W1_h2a = (const float*)d_in[5];
  const float* ln11w = (const float*)d_in[6];
  const float* ln11b = (const float*)d_in[7];
  const float* ln12w = (const float*)d_in[8];
  const float* ln12b = (const float*)d_in[9];
  const float* ln13w = (const float*)d_in[10];
  const float* ln13b = (const float*)d_in[11];
  const float* W2_a2h = (const float*)d_in[12];
  const float* W2_h2h = (const float*)d_in[13];
  const float* W2_h2a = (const float*)d_in[14];
  const float* ln21w = (const float*)d_in[15];
  const float* ln21b = (const float*)d_in[16];
  const float* ln22w = (const float*)d_in[17];
  const float* ln22b = (const float*)d_in[18];
  const float* ln23w = (const float*)d_in[19];
  const float* ln23b = (const float*)d_in[20];
  float* out = (float*)d_out;

  float* ws = (float*)d_ws;
  const size_t SM = (size_t)B_ * C_ * D_;  // 2097152 elems
  float* hl1f = ws;                                   // f32 [B*C*D]
  bf16_t* A1b = (bf16_t*)(hl1f + SM);                 // hln bf16
  bf16_t* A1t = (bf16_t*)((float*)A1b + SM / 2);      // hlnT bf16
  bf16_t* A2b = (bf16_t*)((float*)A1t + SM / 2);      // gemm out bf16
  bf16_t* hl1b = (bf16_t*)((float*)A2b + SM / 2);     // hl1 bf16
  bf16_t* u_b = (bf16_t*)((float*)hl1b + SM / 2);     // u bf16
  bf16_t* R_b = (bf16_t*)((float*)u_b + SM / 2);      // R bf16
  bf16_t* Wt0 = (bf16_t*)((float*)R_b + SM / 2);      // 6 weight slots
  const size_t WTE = (size_t)512 * 512;               // elems per slot
  bf16_t* att1b = Wt0 + 6 * WTE;                      // B*A*D bf16
  float* stats = (float*)(att1b + (size_t)B_ * A_ * D_);  // 2*B*A f32

  dim3 blk(256);
  // weight prep
  k_wt6<<<dim3(8, 8, 6), blk, 0, stream>>>(W1_h2h, W1_h2a, W2_a2h, W2_h2h, W2_h2a, Wt0);

  // ---- layer 1 ----
  k_hl0<<<B_ * C_, blk, 0, stream>>>(att_vf, ln11w, ln11b, ln12w, ln12b, A1b);  // ln12
  k_tr<<<dim3(8, B_), blk, 0, stream>>>(A1b, A1t);
  k_mfma_gemm<64, false><<<256, blk, 0, stream>>>(A1b, Wt0 + 0 * WTE, nullptr, A2b);  // hide1
  k_h2h<0><<<dim3(4, B_), blk, 0, stream>>>(A2b, A1t, ln13w, ln13b, hl1f, hl1b, A1b);  // hl1 + ln13
  k_mfma_gemm<64, false><<<256, blk, 0, stream>>>(A1b, Wt0 + 1 * WTE, nullptr, A2b);  // hW1
  k_h2a_ln<<<(B_ * A_) / 4, blk, 0, stream>>>(att_vf, A2b, att1b, stats);  // att1 + stats
  // ---- layer 2: a2h via linearity ----
  k_mfma_gemm<64, false><<<256, blk, 0, stream>>>(hl1b, Wt0 + 5 * WTE, nullptr, A2b);  // G = hl1@W^T
  k_a2h_u<<<B_ * C_, blk, 0, stream>>>(hl1f, A2b, att1b, stats, ln21w, ln21b, u_b, R_b);
  k_mfma_gemm<64, true><<<256, blk, 0, stream>>>(u_b, Wt0 + 2 * WTE, R_b, A2b);  // hl2 = u@W + R
  k_ln_tr<<<B_, blk, 0, stream>>>(A2b, ln22w, ln22b, A1b, A1t);  // ln22 + transpose
  // h2h #2
  k_mfma_gemm<64, false><<<256, blk, 0, stream>>>(A1b, Wt0 + 3 * WTE, nullptr, A2b);  // hide2
  k_h2h<1><<<dim3(4, B_), blk, 0, stream>>>(A2b, A1t, ln23w, ln23b, nullptr, nullptr, A1b);  // ln23
  k_mfma_gemm<64, false><<<256, blk, 0, stream>>>(A1b, Wt0 + 4 * WTE, nullptr, A2b);  // hW2
  k_h2a_out<<<(B_ * A_) / 4, blk, 0, stream>>>(att1b, A2b, out);
}

// Round 8
// 196.884 us; speedup vs baseline: 8.5466x; 1.0544x over previous
//
#include <hip/hip_runtime.h>

#define B_ 64
#define A_ 1024
#define C_ 64
#define D_ 512
#define INV_SD 0.044194173824159216f

typedef __bf16 bf16_t;
typedef __bf16 bf16x8 __attribute__((ext_vector_type(8)));
typedef __bf16 bf16x2 __attribute__((ext_vector_type(2)));
typedef float f32x4 __attribute__((ext_vector_type(4)));

static __device__ __forceinline__ bf16_t f2b(float x) { return (bf16_t)x; }
static __device__ __forceinline__ float b2f(bf16_t x) { return (float)x; }

// async global->LDS, 16B per lane; LDS dest = wave-uniform base + lane*16 (linear)
static __device__ __forceinline__ void gl_lds16(const void* g, void* l) {
  __builtin_amdgcn_global_load_lds(
      (const __attribute__((address_space(1))) unsigned int*)g,
      (__attribute__((address_space(3))) unsigned int*)l, 16, 0, 0);
}

// ---- fused: per (b,c): stats+LN11 of 16 att rows, avg, LN12 -> hln bf16 ----
__global__ __launch_bounds__(256) void k_hl0(const float* __restrict__ att,
                                             const float* __restrict__ lw1,
                                             const float* __restrict__ lb1,
                                             const float* __restrict__ lw2,
                                             const float* __restrict__ lb2,
                                             bf16_t* __restrict__ hlnb) {
  int blk = blockIdx.x;  // B*C
  int b = blk >> 6, c = blk & 63;
  int t = threadIdx.x;
  int w = t >> 6, lane = t & 63;
  __shared__ float part[4][512];
  __shared__ float reds[8];
  float ps[8] = {0.f, 0.f, 0.f, 0.f, 0.f, 0.f, 0.f, 0.f};
#pragma unroll
  for (int i = 0; i < 4; ++i) {
    int jj = w * 4 + i;
    const float* xr = att + ((size_t)b * A_ + jj * 64 + c) * D_ + lane * 8;
    float4 v1 = *(const float4*)xr;
    float4 v2 = *(const float4*)(xr + 4);
    float v[8] = {v1.x, v1.y, v1.z, v1.w, v2.x, v2.y, v2.z, v2.w};
    float s = 0.f, q = 0.f;
#pragma unroll
    for (int u = 0; u < 8; ++u) { s += v[u]; q += v[u] * v[u]; }
#pragma unroll
    for (int o = 32; o; o >>= 1) { s += __shfl_xor(s, o); q += __shfl_xor(q, o); }
    float mu = s * (1.0f / D_);
    float rs = rsqrtf(q * (1.0f / D_) - mu * mu + 1e-5f);
#pragma unroll
    for (int u = 0; u < 8; ++u) ps[u] += (v[u] - mu) * rs;
  }
#pragma unroll
  for (int u = 0; u < 8; ++u) part[w][lane * 8 + u] = ps[u];
  __syncthreads();
  int d = 2 * t;
  float hx = ((part[0][d] + part[1][d]) + (part[2][d] + part[3][d])) * (1.f / 16.f) * lw1[d] + lb1[d];
  float hy = ((part[0][d + 1] + part[1][d + 1]) + (part[2][d + 1] + part[3][d + 1])) * (1.f / 16.f) * lw1[d + 1] + lb1[d + 1];
  float s = hx + hy, q = hx * hx + hy * hy;
#pragma unroll
  for (int o = 32; o; o >>= 1) { s += __shfl_xor(s, o); q += __shfl_xor(q, o); }
  if (lane == 0) { reds[w] = s; reds[4 + w] = q; }
  __syncthreads();
  float S = (reds[0] + reds[1]) + (reds[2] + reds[3]);
  float Q = (reds[4] + reds[5]) + (reds[6] + reds[7]);
  float mu = S * (1.0f / D_);
  float rs = rsqrtf(Q * (1.0f / D_) - mu * mu + 1e-5f);
  bf16x2 ob;
  ob.x = f2b((hx - mu) * rs * lw2[d] + lb2[d]);
  ob.y = f2b((hy - mu) * rs * lw2[d + 1] + lb2[d + 1]);
  *(bf16x2*)(hlnb + (size_t)blk * D_ + d) = ob;
}

// ---- merged: LN rows of one batch (bf16 in) -> row-major bf16 + transposed bf16 ----
__global__ __launch_bounds__(256) void k_ln_tr(const bf16_t* __restrict__ x,
                                               const float* __restrict__ lw,
                                               const float* __restrict__ lb,
                                               bf16_t* __restrict__ y,
                                               bf16_t* __restrict__ yt) {
  __shared__ bf16_t lnS[64][528];
  int b = blockIdx.x;
  int t = threadIdx.x;
  int wv = t >> 6, lane = t & 63;
  int d0 = lane * 8;
  float4 w1 = *(const float4*)(lw + d0);
  float4 w2 = *(const float4*)(lw + d0 + 4);
  float4 b1 = *(const float4*)(lb + d0);
  float4 b2 = *(const float4*)(lb + d0 + 4);
  float lwv[8] = {w1.x, w1.y, w1.z, w1.w, w2.x, w2.y, w2.z, w2.w};
  float lbv[8] = {b1.x, b1.y, b1.z, b1.w, b2.x, b2.y, b2.z, b2.w};
  const bf16_t* xb = x + (size_t)b * C_ * D_;
  bf16_t* yb = y + (size_t)b * C_ * D_;
#pragma unroll 4
  for (int i = 0; i < 16; ++i) {
    int r = wv * 16 + i;
    bf16x8 xv = *(const bf16x8*)(xb + (size_t)r * D_ + d0);
    float v[8], s = 0.f, q = 0.f;
#pragma unroll
    for (int u = 0; u < 8; ++u) { v[u] = b2f(xv[u]); s += v[u]; q += v[u] * v[u]; }
#pragma unroll
    for (int o = 32; o; o >>= 1) { s += __shfl_xor(s, o); q += __shfl_xor(q, o); }
    float mu = s * (1.0f / D_);
    float rs = rsqrtf(q * (1.0f / D_) - mu * mu + 1e-5f);
    bf16x8 ob;
#pragma unroll
    for (int u = 0; u < 8; ++u) ob[u] = f2b((v[u] - mu) * rs * lwv[u] + lbv[u]);
    *(bf16x8*)(yb + (size_t)r * D_ + d0) = ob;
    *(bf16x8*)(&lnS[r][d0]) = ob;
  }
  __syncthreads();
  bf16_t* tb = yt + (size_t)b * D_ * C_;
#pragma unroll
  for (int pass = 0; pass < 16; ++pass) {
    int d = pass * 32 + (t >> 3);
    int c0 = (t & 7) * 8;
    unsigned short tmp[8];
#pragma unroll
    for (int u = 0; u < 8; ++u) tmp[u] = *(const unsigned short*)&lnS[c0 + u][d];
    *(uint4*)(tb + (size_t)d * 64 + c0) = *(const uint4*)tmp;
  }
}

// ---------------- transpose hln bf16 [64][512] -> hlnT [512][64] per batch ----------------
__global__ __launch_bounds__(256) void k_tr(const bf16_t* __restrict__ src,
                                            bf16_t* __restrict__ dst) {
  __shared__ unsigned short sm[64][72];
  int n0 = blockIdx.x;  // 0..7
  int b = blockIdx.y;
  int t = threadIdx.x;
  const bf16_t* sb = src + (size_t)b * C_ * D_;
  bf16_t* db = dst + (size_t)b * D_ * C_;
#pragma unroll
  for (int rep = 0; rep < 2; ++rep) {
    int f = t + rep * 256;
    int r = f >> 3, c8 = f & 7;
    uint4 v = *(const uint4*)(sb + (size_t)r * D_ + n0 * 64 + c8 * 8);
    unsigned int* p = (unsigned int*)&sm[r][c8 * 8];
    p[0] = v.x; p[1] = v.y; p[2] = v.z; p[3] = v.w;
  }
  __syncthreads();
#pragma unroll
  for (int rep = 0; rep < 2; ++rep) {
    int f = t + rep * 256;
    int nr = f >> 3, c8 = f & 7;
    unsigned short tmp[8];
#pragma unroll
    for (int u = 0; u < 8; ++u) tmp[u] = sm[c8 * 8 + u][nr];
    *(uint4*)(db + (size_t)(n0 * 64 + nr) * 64 + c8 * 8) = *(const uint4*)tmp;
  }
}

// ---- weight prep: slots 0-4 transposed Wt[n][k] bf16; slot 5 = raw bf16 of W2_a2h ----
__global__ __launch_bounds__(256) void k_wt6(const float* __restrict__ W0, const float* __restrict__ W1,
                                             const float* __restrict__ W2, const float* __restrict__ W3,
                                             const float* __restrict__ W4, bf16_t* __restrict__ WtBase) {
  __shared__ float tile[64][65];
  const float* Ws[5] = {W0, W1, W2, W3, W4};
  int z = blockIdx.z;
  int k0 = blockIdx.x * 64;
  int n0 = blockIdx.y * 64;
  int t = threadIdx.x;
  int r0 = t >> 6;
  int c = t & 63;
  if (z == 5) {  // raw convert of W2_a2h
    const float* W = Ws[2];
    bf16_t* Wt = WtBase + (size_t)5 * 512 * 512;
#pragma unroll 4
    for (int i = 0; i < 16; ++i) {
      int r = r0 * 16 + i;
      Wt[(size_t)(k0 + r) * 512 + n0 + c] = f2b(W[(size_t)(k0 + r) * 512 + n0 + c]);
    }
    return;
  }
  const float* W = Ws[z];
  bf16_t* Wt = WtBase + (size_t)z * 512 * 512;
#pragma unroll 4
  for (int i = 0; i < 16; ++i) {
    int r = r0 * 16 + i;
    tile[r][c] = W[(size_t)(k0 + r) * 512 + n0 + c];
  }
  __syncthreads();
#pragma unroll 4
  for (int i = 0; i < 16; ++i) {
    int r = r0 * 16 + i;
    Wt[(size_t)(n0 + r) * 512 + k0 + c] = f2b(tile[c][r]);
  }
}

// ---- MFMA GEMM, 64x64 tiles, dbuf LDS, dual-matrix merge support ----
// C[M,512] bf16 = A[M,512] bf16 @ Wt^T (+ optional bias Rb on set 0).
// Grid = tiles_per * (1 or 2); tile >= tiles_per selects set 1.
template <bool BIAS>
__global__ __launch_bounds__(256, 4) void k_gemm64(const bf16_t* __restrict__ A0,
                                                   const bf16_t* __restrict__ W0,
                                                   bf16_t* __restrict__ C0,
                                                   const bf16_t* __restrict__ A1,
                                                   const bf16_t* __restrict__ W1,
                                                   bf16_t* __restrict__ C1,
                                                   const bf16_t* __restrict__ Rb,
                                                   int tiles_per) {
  constexpr int ABYTES = 64 * 128;  // 64 rows x 64 bf16
  constexpr int BUF = 2 * ABYTES;   // A + B per buffer = 16 KB
  __shared__ char smem[2 * BUF];    // 32 KB; epilogue Cs aliases

  int t = threadIdx.x;
  int lane = t & 63, wave = t >> 6;
  int wr = wave >> 1, wc = wave & 1;
  int lhi = lane >> 4, llo = lane & 15;

  int nwg = gridDim.x;
  int bid = blockIdx.x;
  int tile = (bid & 7) * (nwg >> 3) + (bid >> 3);
  int sel = (tile >= tiles_per) ? 1 : 0;
  int tidx = tile - sel * tiles_per;
  int bm = tidx >> 3, bn = tidx & 7;

  const bf16_t* Ab = (sel ? A1 : A0) + (size_t)bm * 64 * 512;
  const bf16_t* Wb = (sel ? W1 : W0) + (size_t)bn * 64 * 512;
  bf16_t* Cmat = sel ? C1 : C0;

  int l3 = lane >> 3;
  int srcOff = ((lane & 7) ^ l3) * 8;  // pre-swizzled source (rule 21)

  auto stage = [&](int k0, int bi) {
    char* As = smem + bi * BUF;
    char* Bs = As + ABYTES;
#pragma unroll
    for (int i = 0; i < 2; ++i) {
      int r0 = wave * 16 + i * 8;
      gl_lds16(Ab + (size_t)(r0 + l3) * 512 + k0 + srcOff, As + r0 * 128);
      gl_lds16(Wb + (size_t)(r0 + l3) * 512 + k0 + srcOff, Bs + r0 * 128);
    }
  };

  f32x4 acc[2][2] = {};
  stage(0, 0);
  __syncthreads();

  for (int it = 0; it < 8; ++it) {
    int cur = it & 1;
    if (it < 7) stage((it + 1) * 64, cur ^ 1);  // issue BEFORE compute
    const char* As = smem + cur * BUF;
    const char* Bs = As + ABYTES;
#pragma unroll
    for (int kk = 0; kk < 2; ++kk) {
      bf16x8 af[2], bfr[2];
      int bofs = kk * 64 + lhi * 16;
#pragma unroll
      for (int tr = 0; tr < 2; ++tr) {
        int row = wr * 32 + tr * 16 + llo;
        af[tr] = *(const bf16x8*)(As + row * 128 + (bofs ^ ((row & 7) << 4)));
      }
#pragma unroll
      for (int tc = 0; tc < 2; ++tc) {
        int col = wc * 32 + tc * 16 + llo;
        bfr[tc] = *(const bf16x8*)(Bs + col * 128 + (bofs ^ ((col & 7) << 4)));
      }
#pragma unroll
      for (int tr = 0; tr < 2; ++tr)
#pragma unroll
        for (int tc = 0; tc < 2; ++tc)
          acc[tr][tc] = __builtin_amdgcn_mfma_f32_16x16x32_bf16(af[tr], bfr[tc], acc[tr][tc], 0, 0, 0);
    }
    __syncthreads();
  }

  bf16_t(*Cs)[80] = (bf16_t(*)[80])smem;  // 64 x 80 bf16 = 10 KB, row stride 160B (16B-mult)
#pragma unroll
  for (int tr = 0; tr < 2; ++tr) {
    int row = wr * 32 + tr * 16 + lhi * 4;
#pragma unroll
    for (int r = 0; r < 4; ++r)
#pragma unroll
      for (int tc = 0; tc < 2; ++tc) {
        float v = acc[tr][tc][r];
        if constexpr (BIAS)
          v += b2f(Rb[(size_t)(bm * 64 + row + r) * 512 + bn * 64 + wc * 32 + tc * 16 + llo]);
        Cs[row + r][wc * 32 + tc * 16 + llo] = f2b(v);
      }
  }
  __syncthreads();
#pragma unroll
  for (int it = 0; it < 2; ++it) {
    int idx = t + it * 256;
    int row = idx >> 3, c8 = idx & 7;
    uint4 v = *(const uint4*)(&Cs[row][c8 * 8]);
    *(uint4*)(Cmat + (size_t)(bm * 64 + row) * 512 + bn * 64 + c8 * 8) = v;
  }
}

// ---- fused h2h: gram(MFMA) + softmax + PV(MFMA) + epilogue LN ----
// MODE 0: write hl1f (f32), hl1b (bf16), lnout=LN(hl1) bf16.  MODE 1: lnout only.
template <int MODE>
__global__ __launch_bounds__(256) void k_h2h(const bf16_t* __restrict__ hide,
                                             const bf16_t* __restrict__ hlnT,
                                             const float* __restrict__ lnw,
                                             const float* __restrict__ lnbv,
                                             float* __restrict__ hl1f,
                                             bf16_t* __restrict__ hl1b,
                                             bf16_t* __restrict__ lnout) {
  __shared__ bf16_t hS[8 * 64 * 64];  // 64KB; reused as f32 sf[16][516] in epilogue
  __shared__ float sS[16][68];
  __shared__ bf16_t wS[16 * 64];
  __shared__ float mur[16], rsr[16];

  int q = blockIdx.x;
  int b = blockIdx.y;
  int t = threadIdx.x;
  int lane = t & 63, wave = t >> 6;
  int lhi = lane >> 4, llo = lane & 15;

  const bf16_t* Hb = hide + (size_t)b * C_ * D_;
#pragma unroll
  for (int rep = 0; rep < 16; ++rep) {
    int f = t + rep * 256;
    int row = f >> 6, c16 = f & 63;
    int kc = c16 >> 3, ci = c16 & 7;
    uint4 v = *(const uint4*)(Hb + (size_t)row * 512 + c16 * 8);
    *(uint4*)((char*)hS + kc * 8192 + row * 128 + ((ci * 16) ^ ((row & 7) << 4))) = v;
  }
  __syncthreads();

  {
    f32x4 acc = {};
#pragma unroll
    for (int ks = 0; ks < 16; ++ks) {
      int kc = ks >> 1;
      int bofs = (ks & 1) * 64 + lhi * 16;
      int ra = q * 16 + llo;
      int rb = wave * 16 + llo;
      bf16x8 af = *(const bf16x8*)((const char*)hS + kc * 8192 + ra * 128 + (bofs ^ ((ra & 7) << 4)));
      bf16x8 bf = *(const bf16x8*)((const char*)hS + kc * 8192 + rb * 128 + (bofs ^ ((rb & 7) << 4)));
      acc = __builtin_amdgcn_mfma_f32_16x16x32_bf16(af, bf, acc, 0, 0, 0);
    }
#pragma unroll
    for (int r = 0; r < 4; ++r) sS[lhi * 4 + r][wave * 16 + llo] = acc[r] * INV_SD;
  }
  __syncthreads();

  if (t < 128) {
    int row = t >> 3, sg = t & 7;
    float v[8];
#pragma unroll
    for (int u = 0; u < 8; ++u) v[u] = sS[row][sg * 8 + u];
    float m = v[0];
#pragma unroll
    for (int u = 1; u < 8; ++u) m = fmaxf(m, v[u]);
#pragma unroll
    for (int o = 4; o; o >>= 1) m = fmaxf(m, __shfl_xor(m, o));
    float sum = 0.f;
#pragma unroll
    for (int u = 0; u < 8; ++u) { v[u] = __expf(v[u] - m); sum += v[u]; }
#pragma unroll
    for (int o = 4; o; o >>= 1) sum += __shfl_xor(sum, o);
    float inv = 1.f / sum;
    bf16x8 wv;
#pragma unroll
    for (int u = 0; u < 8; ++u) wv[u] = f2b(v[u] * inv);
    *(bf16x8*)((char*)wS + row * 128 + ((sg * 16) ^ ((row & 7) << 4))) = wv;
  }
  __syncthreads();

  float* sf = (float*)hS;  // [16][516]
  {
    bf16x8 af[2];
#pragma unroll
    for (int ks = 0; ks < 2; ++ks)
      af[ks] = *(const bf16x8*)((const char*)wS + llo * 128 + (((ks * 64 + lhi * 16)) ^ ((llo & 7) << 4)));
    const bf16_t* Tb = hlnT + (size_t)b * D_ * C_;
#pragma unroll
    for (int nt = 0; nt < 8; ++nt) {
      int dcol = wave * 128 + nt * 16 + llo;
      f32x4 acc = {};
#pragma unroll
      for (int ks = 0; ks < 2; ++ks) {
        bf16x8 bf = *(const bf16x8*)(Tb + (size_t)dcol * 64 + ks * 32 + lhi * 8);
        acc = __builtin_amdgcn_mfma_f32_16x16x32_bf16(af[ks], bf, acc, 0, 0, 0);
      }
#pragma unroll
      for (int r = 0; r < 4; ++r) sf[(lhi * 4 + r) * 516 + dcol] = acc[r];
    }
  }
  __syncthreads();

  {
    int lr = t >> 4, p = t & 15;
    float s = 0.f, q2 = 0.f;
#pragma unroll 8
    for (int i = 0; i < 32; ++i) {
      float v = sf[lr * 516 + p + 16 * i];
      s += v;
      q2 += v * v;
    }
#pragma unroll
    for (int o = 8; o; o >>= 1) { s += __shfl_xor(s, o); q2 += __shfl_xor(q2, o); }
    if (p == 0) {
      float mu = s * (1.0f / D_);
      mur[lr] = mu;
      rsr[lr] = rsqrtf(q2 * (1.0f / D_) - mu * mu + 1e-5f);
    }
  }
  __syncthreads();

  int d = 2 * t;
  float lwx = lnw[d], lwy = lnw[d + 1], lbx = lnbv[d], lby = lnbv[d + 1];
#pragma unroll 4
  for (int r = 0; r < 16; ++r) {
    float2 xy = *(const float2*)(&sf[r * 516 + d]);
    size_t go = ((size_t)b * C_ + q * 16 + r) * 512 + d;
    float mu = mur[r], rs = rsr[r];
    if constexpr (MODE == 0) {
      *(float2*)(hl1f + go) = xy;
      bf16x2 hb;
      hb.x = f2b(xy.x);
      hb.y = f2b(xy.y);
      *(bf16x2*)(hl1b + go) = hb;
    }
    bf16x2 lb2;
    lb2.x = f2b((xy.x - mu) * rs * lwx + lbx);
    lb2.y = f2b((xy.y - mu) * rs * lwy + lby);
    *(bf16x2*)(lnout + go) = lb2;
  }
}

// ---- h2a #1: att f32 in; out att1 bf16 + per-row LN21 stats ----
__global__ __launch_bounds__(256) void k_h2a_ln(const float* __restrict__ att,
                                                const bf16_t* __restrict__ hW,
                                                bf16_t* __restrict__ att1b,
                                                float* __restrict__ stats) {
  int t = threadIdx.x;
  int row = blockIdx.x * 4 + (t >> 6);
  int lane = t & 63;
  int b = row >> 10, a = row & 1023;
  int c = a & 63;
  int d0 = lane * 8;
  const float* ar = att + (size_t)row * D_ + d0;
  const bf16_t* wr = hW + (size_t)(b * 64 + c) * D_ + d0;
  float4 a1 = *(const float4*)ar;
  float4 a2 = *(const float4*)(ar + 4);
  bf16x8 wb = *(const bf16x8*)wr;
  float w[8], av[8] = {a1.x, a1.y, a1.z, a1.w, a2.x, a2.y, a2.z, a2.w};
#pragma unroll
  for (int u = 0; u < 8; ++u) w[u] = b2f(wb[u]);
  float d1 = 0.f, d2 = 0.f;
#pragma unroll
  for (int u = 0; u < 8; ++u) { d1 += av[u] * w[u]; d2 += av[u] * av[u]; }
#pragma unroll
  for (int o = 32; o; o >>= 1) { d1 += __shfl_xor(d1, o); d2 += __shfl_xor(d2, o); }
  float s1 = d1 * INV_SD, s2 = d2 * INV_SD;
  float m = fmaxf(s1, s2);
  float e1 = __expf(s1 - m), e2 = __expf(s2 - m);
  float inv = 1.f / (e1 + e2);
  float alpha = e1 * inv, beta = e2 * inv;
  float o8[8];
  float s = 0.f, q = 0.f;
#pragma unroll
  for (int u = 0; u < 8; ++u) {
    o8[u] = alpha * w[u] + beta * av[u];
    s += o8[u];
    q += o8[u] * o8[u];
  }
  bf16x8 ob;
#pragma unroll
  for (int u = 0; u < 8; ++u) ob[u] = f2b(o8[u]);
  *(bf16x8*)(att1b + (size_t)row * D_ + d0) = ob;
#pragma unroll
  for (int o = 32; o; o >>= 1) { s += __shfl_xor(s, o); q += __shfl_xor(q, o); }
  if (lane == 0) {
    float mu = s * (1.0f / D_);
    stats[2 * row] = mu;
    stats[2 * row + 1] = rsqrtf(q * (1.0f / D_) - mu * mu + 1e-5f);
  }
}

// ---- h2a #2 (final): att1 bf16 in, out f32 ----
__global__ __launch_bounds__(256) void k_h2a_out(const bf16_t* __restrict__ att,
                                                 const bf16_t* __restrict__ hW,
                                                 float* __restrict__ outp) {
  int t = threadIdx.x;
  int row = blockIdx.x * 4 + (t >> 6);
  int lane = t & 63;
  int b = row >> 10, a = row & 1023;
  int c = a & 63;
  int d0 = lane * 8;
  bf16x8 ab = *(const bf16x8*)(att + (size_t)row * D_ + d0);
  bf16x8 wb = *(const bf16x8*)(hW + (size_t)(b * 64 + c) * D_ + d0);
  float av[8], w[8];
#pragma unroll
  for (int u = 0; u < 8; ++u) { av[u] = b2f(ab[u]); w[u] = b2f(wb[u]); }
  float d1 = 0.f, d2 = 0.f;
#pragma unroll
  for (int u = 0; u < 8; ++u) { d1 += av[u] * w[u]; d2 += av[u] * av[u]; }
#pragma unroll
  for (int o = 32; o; o >>= 1) { d1 += __shfl_xor(d1, o); d2 += __shfl_xor(d2, o); }
  float s1 = d1 * INV_SD, s2 = d2 * INV_SD;
  float m = fmaxf(s1, s2);
  float e1 = __expf(s1 - m), e2 = __expf(s2 - m);
  float inv = 1.f / (e1 + e2);
  float alpha = e1 * inv, beta = e2 * inv;
  float4 o1, o2;
  o1.x = alpha * w[0] + beta * av[0]; o1.y = alpha * w[1] + beta * av[1];
  o1.z = alpha * w[2] + beta * av[2]; o1.w = alpha * w[3] + beta * av[3];
  o2.x = alpha * w[4] + beta * av[4]; o2.y = alpha * w[5] + beta * av[5];
  o2.z = alpha * w[6] + beta * av[6]; o2.w = alpha * w[7] + beta * av[7];
  float* orow = outp + (size_t)row * D_ + d0;
  *(float4*)orow = o1;
  *(float4*)(orow + 4) = o2;
}

// ---- layer2 a2h via linearity: per (b,c): scores attln_j·G, softmax(17),
//      u = sum_j p_j*attln_j (bf16), R = p_self*hl1 (bf16) ----
__global__ __launch_bounds__(256) void k_a2h_u(const float* __restrict__ hl1f,
                                               const bf16_t* __restrict__ G,
                                               const bf16_t* __restrict__ att1b,
                                               const float* __restrict__ stats,
                                               const float* __restrict__ lw,
                                               const float* __restrict__ lb,
                                               bf16_t* __restrict__ u_out,
                                               bf16_t* __restrict__ R_out) {
  int blk = blockIdx.x;  // B*C
  int b = blk >> 6, c = blk & 63;
  int t = threadIdx.x;
  int wave = t >> 6, lane = t & 63;
  __shared__ float hrow[512], grow[512], lwS[512], lbS[512];
  __shared__ bf16_t lnS[16][512];
  __shared__ float wts[32];
  __shared__ float red[4];
  {
    int d = 2 * t;
    float2 h2 = *(const float2*)(hl1f + (size_t)blk * 512 + d);
    hrow[d] = h2.x;
    hrow[d + 1] = h2.y;
    bf16x2 g2 = *(const bf16x2*)(G + (size_t)blk * 512 + d);
    grow[d] = b2f(g2.x);
    grow[d + 1] = b2f(g2.y);
    float2 w2 = *(const float2*)(lw + d);
    lwS[d] = w2.x;
    lwS[d + 1] = w2.y;
    float2 bb = *(const float2*)(lb + d);
    lbS[d] = bb.x;
    lbS[d + 1] = bb.y;
    float sd = h2.x * h2.x + h2.y * h2.y;
#pragma unroll
    for (int o = 32; o; o >>= 1) sd += __shfl_xor(sd, o);
    if (lane == 0) red[wave] = sd;
  }
  __syncthreads();
#pragma unroll
  for (int i = 0; i < 4; ++i) {
    int j = wave * 4 + i;
    size_t row = (size_t)b * A_ + j * 64 + c;
    float mu = stats[2 * row], rs = stats[2 * row + 1];
    bf16x8 x = *(const bf16x8*)(att1b + row * 512 + lane * 8);
    float dot = 0.f;
    bf16x8 lnv;
#pragma unroll
    for (int u = 0; u < 8; ++u) {
      int k = lane * 8 + u;
      float v = (b2f(x[u]) - mu) * rs * lwS[k] + lbS[k];
      lnv[u] = f2b(v);
      dot += v * grow[k];
    }
    *(bf16x8*)(&lnS[j][lane * 8]) = lnv;
#pragma unroll
    for (int o = 32; o; o >>= 1) dot += __shfl_xor(dot, o);
    if (lane == 0) wts[j] = dot * INV_SD;
  }
  if (t == 0) wts[16] = ((red[0] + red[1]) + (red[2] + red[3])) * INV_SD;
  __syncthreads();
  if (t < 64) {
    float val = (t < 17) ? wts[t] : -3.0e38f;
    float m = val;
#pragma unroll
    for (int o = 32; o; o >>= 1) m = fmaxf(m, __shfl_xor(m, o));
    float e = (t < 17) ? __expf(val - m) : 0.f;
    float ssum = e;
#pragma unroll
    for (int o = 32; o; o >>= 1) ssum += __shfl_xor(ssum, o);
    if (t < 17) wts[t] = e / ssum;
  }
  __syncthreads();
  int d = 2 * t;
  float ux = 0.f, uy = 0.f;
#pragma unroll 4
  for (int jj = 0; jj < 16; ++jj) {
    bf16x2 l2 = *(const bf16x2*)(&lnS[jj][d]);
    ux += wts[jj] * b2f(l2.x);
    uy += wts[jj] * b2f(l2.y);
  }
  bf16x2 uo, ro;
  uo.x = f2b(ux);
  uo.y = f2b(uy);
  *(bf16x2*)(u_out + (size_t)blk * 512 + d) = uo;
  float w16 = wts[16];
  ro.x = f2b(w16 * hrow[d]);
  ro.y = f2b(w16 * hrow[d + 1]);
  *(bf16x2*)(R_out + (size_t)blk * 512 + d) = ro;
}

extern "C" void kernel_launch(void* const* d_in, const int* in_sizes, int n_in,
                              void* d_out, int out_size, void* d_ws, size_t ws_size,
                              hipStream_t stream) {
  const float* att_vf = (const float*)d_in[0];
  const float* W1_h2h = (const float*)d_in[4];
  const float* W1_h2a = (const float*)d_in[5];
  const float* ln11w = (const float*)d_in[6];
  const float* ln11b = (const float*)d_in[7];
  const float* ln12w = (const float*)d_in[8];
  const float* ln12b = (const float*)d_in[9];
  const float* ln13w = (const float*)d_in[10];
  const float* ln13b = (const float*)d_in[11];
  const float* W2_a2h = (const float*)d_in[12];
  const float* W2_h2h = (const float*)d_in[13];
  const float* W2_h2a = (const float*)d_in[14];
  const float* ln21w = (const float*)d_in[15];
  const float* ln21b = (const float*)d_in[16];
  const float* ln22w = (const float*)d_in[17];
  const float* ln22b = (const float*)d_in[18];
  const float* ln23w = (const float*)d_in[19];
  const float* ln23b = (const float*)d_in[20];
  float* out = (float*)d_out;

  float* ws = (float*)d_ws;
  const size_t SM = (size_t)B_ * C_ * D_;  // 2097152 elems
  float* hl1f = ws;                                   // f32 [B*C*D]
  bf16_t* A1b = (bf16_t*)(hl1f + SM);                 // hln bf16
  bf16_t* A1t = (bf16_t*)((float*)A1b + SM / 2);      // hlnT bf16
  bf16_t* A2b = (bf16_t*)((float*)A1t + SM / 2);      // gemm out bf16
  bf16_t* hl1b = (bf16_t*)((float*)A2b + SM / 2);     // hl1 bf16
  bf16_t* u_b = (bf16_t*)((float*)hl1b + SM / 2);     // u bf16
  bf16_t* R_b = (bf16_t*)((float*)u_b + SM / 2);      // R bf16
  bf16_t* Gb = (bf16_t*)((float*)R_b + SM / 2);       // G bf16
  bf16_t* Wt0 = (bf16_t*)((float*)Gb + SM / 2);       // 6 weight slots
  const size_t WTE = (size_t)512 * 512;               // elems per slot
  bf16_t* att1b = Wt0 + 6 * WTE;                      // B*A*D bf16
  float* stats = (float*)(att1b + (size_t)B_ * A_ * D_);  // 2*B*A f32

  dim3 blk(256);
  // weight prep
  k_wt6<<<dim3(8, 8, 6), blk, 0, stream>>>(W1_h2h, W1_h2a, W2_a2h, W2_h2h, W2_h2a, Wt0);

  // ---- layer 1 ----
  k_hl0<<<B_ * C_, blk, 0, stream>>>(att_vf, ln11w, ln11b, ln12w, ln12b, A1b);  // ln12
  k_tr<<<dim3(8, B_), blk, 0, stream>>>(A1b, A1t);
  k_gemm64<false><<<512, blk, 0, stream>>>(A1b, Wt0 + 0 * WTE, A2b,
                                           A1b, Wt0 + 0 * WTE, A2b, nullptr, 512);  // hide1
  k_h2h<0><<<dim3(4, B_), blk, 0, stream>>>(A2b, A1t, ln13w, ln13b, hl1f, hl1b, A1b);  // hl1 + ln13
  // merged: hW1 = ln13 @ W1_h2a^T  AND  G = hl1 @ W2_a2h^T
  k_gemm64<false><<<1024, blk, 0, stream>>>(A1b, Wt0 + 1 * WTE, A2b,
                                            hl1b, Wt0 + 5 * WTE, Gb, nullptr, 512);
  k_h2a_ln<<<(B_ * A_) / 4, blk, 0, stream>>>(att_vf, A2b, att1b, stats);  // att1 + stats
  // ---- layer 2: a2h via linearity ----
  k_a2h_u<<<B_ * C_, blk, 0, stream>>>(hl1f, Gb, att1b, stats, ln21w, ln21b, u_b, R_b);
  k_gemm64<true><<<512, blk, 0, stream>>>(u_b, Wt0 + 2 * WTE, A2b,
                                          u_b, Wt0 + 2 * WTE, A2b, R_b, 512);  // hl2 = u@W + R
  k_ln_tr<<<B_, blk, 0, stream>>>(A2b, ln22w, ln22b, A1b, A1t);  // ln22 + transpose
  // h2h #2
  k_gemm64<false><<<512, blk, 0, stream>>>(A1b, Wt0 + 3 * WTE, A2b,
                                           A1b, Wt0 + 3 * WTE, A2b, nullptr, 512);  // hide2
  k_h2h<1><<<dim3(4, B_), blk, 0, stream>>>(A2b, A1t, ln23w, ln23b, nullptr, nullptr, A1b);  // ln23
  k_gemm64<false><<<512, blk, 0, stream>>>(A1b, Wt0 + 4 * WTE, A2b,
                                           A1b, Wt0 + 4 * WTE, A2b, nullptr, 512);  // hW2
  k_h2a_out<<<(B_ * A_) / 4, blk, 0, stream>>>(att1b, A2b, out);
}

// Round 9
// 180.487 us; speedup vs baseline: 9.3230x; 1.0908x over previous
//
#include <hip/hip_runtime.h>

#define B_ 64
#define A_ 1024
#define C_ 64
#define D_ 512
#define INV_SD 0.044194173824159216f

typedef __bf16 bf16_t;
typedef __bf16 bf16x8 __attribute__((ext_vector_type(8)));
typedef __bf16 bf16x2 __attribute__((ext_vector_type(2)));
typedef float f32x4 __attribute__((ext_vector_type(4)));

static __device__ __forceinline__ bf16_t f2b(float x) { return (bf16_t)x; }
static __device__ __forceinline__ float b2f(bf16_t x) { return (float)x; }

// async global->LDS, 16B per lane; LDS dest = wave-uniform base + lane*16 (linear)
static __device__ __forceinline__ void gl_lds16(const void* g, void* l) {
  __builtin_amdgcn_global_load_lds(
      (const __attribute__((address_space(1))) unsigned int*)g,
      (__attribute__((address_space(3))) unsigned int*)l, 16, 0, 0);
}

// ---- merged prep: blocks [0, B*C) do hl0 (LN11+avg+LN12 -> hln bf16);
//      blocks [B*C, B*C+384) do weight transpose/convert (6 slots) ----
__global__ __launch_bounds__(256) void k_prep(const float* __restrict__ att,
                                              const float* __restrict__ lw1,
                                              const float* __restrict__ lb1,
                                              const float* __restrict__ lw2,
                                              const float* __restrict__ lb2,
                                              bf16_t* __restrict__ hlnb,
                                              const float* __restrict__ W0,
                                              const float* __restrict__ W1,
                                              const float* __restrict__ W2,
                                              const float* __restrict__ W3,
                                              const float* __restrict__ W4,
                                              bf16_t* __restrict__ WtBase) {
  __shared__ float shm[64 * 65];  // 16.6 KB, aliased by both paths
  __shared__ float reds[8];
  int bid = blockIdx.x;
  int t = threadIdx.x;
  if (bid < B_ * C_) {
    int b = bid >> 6, c = bid & 63;
    int w = t >> 6, lane = t & 63;
    float (*part)[512] = (float(*)[512])shm;
    float ps[8] = {0.f, 0.f, 0.f, 0.f, 0.f, 0.f, 0.f, 0.f};
#pragma unroll
    for (int i = 0; i < 4; ++i) {
      int jj = w * 4 + i;
      const float* xr = att + ((size_t)b * A_ + jj * 64 + c) * D_ + lane * 8;
      float4 v1 = *(const float4*)xr;
      float4 v2 = *(const float4*)(xr + 4);
      float v[8] = {v1.x, v1.y, v1.z, v1.w, v2.x, v2.y, v2.z, v2.w};
      float s = 0.f, q = 0.f;
#pragma unroll
      for (int u = 0; u < 8; ++u) { s += v[u]; q += v[u] * v[u]; }
#pragma unroll
      for (int o = 32; o; o >>= 1) { s += __shfl_xor(s, o); q += __shfl_xor(q, o); }
      float mu = s * (1.0f / D_);
      float rs = rsqrtf(q * (1.0f / D_) - mu * mu + 1e-5f);
#pragma unroll
      for (int u = 0; u < 8; ++u) ps[u] += (v[u] - mu) * rs;
    }
#pragma unroll
    for (int u = 0; u < 8; ++u) part[w][lane * 8 + u] = ps[u];
    __syncthreads();
    int d = 2 * t;
    float hx = ((part[0][d] + part[1][d]) + (part[2][d] + part[3][d])) * (1.f / 16.f) * lw1[d] + lb1[d];
    float hy = ((part[0][d + 1] + part[1][d + 1]) + (part[2][d + 1] + part[3][d + 1])) * (1.f / 16.f) * lw1[d + 1] + lb1[d + 1];
    float s = hx + hy, q = hx * hx + hy * hy;
#pragma unroll
    for (int o = 32; o; o >>= 1) { s += __shfl_xor(s, o); q += __shfl_xor(q, o); }
    if (lane == 0) { reds[w] = s; reds[4 + w] = q; }
    __syncthreads();
    float S = (reds[0] + reds[1]) + (reds[2] + reds[3]);
    float Q = (reds[4] + reds[5]) + (reds[6] + reds[7]);
    float mu = S * (1.0f / D_);
    float rs = rsqrtf(Q * (1.0f / D_) - mu * mu + 1e-5f);
    bf16x2 ob;
    ob.x = f2b((hx - mu) * rs * lw2[d] + lb2[d]);
    ob.y = f2b((hy - mu) * rs * lw2[d + 1] + lb2[d + 1]);
    *(bf16x2*)(hlnb + (size_t)bid * D_ + d) = ob;
  } else {
    int idx = bid - B_ * C_;
    int z = idx >> 6;  // 0..5
    int rem = idx & 63;
    int k0 = (rem & 7) * 64, n0 = (rem >> 3) * 64;
    const float* Ws[5] = {W0, W1, W2, W3, W4};
    int r0 = t >> 6;
    int c = t & 63;
    if (z == 5) {  // raw bf16 convert of W2_a2h
      const float* W = Ws[2];
      bf16_t* Wt = WtBase + (size_t)5 * 512 * 512;
#pragma unroll 4
      for (int i = 0; i < 16; ++i) {
        int r = r0 * 16 + i;
        Wt[(size_t)(k0 + r) * 512 + n0 + c] = f2b(W[(size_t)(k0 + r) * 512 + n0 + c]);
      }
      return;
    }
    const float* W = Ws[z];
    bf16_t* Wt = WtBase + (size_t)z * 512 * 512;
    float (*tile)[65] = (float(*)[65])shm;
#pragma unroll 4
    for (int i = 0; i < 16; ++i) {
      int r = r0 * 16 + i;
      tile[r][c] = W[(size_t)(k0 + r) * 512 + n0 + c];
    }
    __syncthreads();
#pragma unroll 4
    for (int i = 0; i < 16; ++i) {
      int r = r0 * 16 + i;
      Wt[(size_t)(n0 + r) * 512 + k0 + c] = f2b(tile[c][r]);
    }
  }
}

// ---- merged: LN rows of one batch (bf16 in) -> row-major bf16 + transposed bf16 ----
__global__ __launch_bounds__(256) void k_ln_tr(const bf16_t* __restrict__ x,
                                               const float* __restrict__ lw,
                                               const float* __restrict__ lb,
                                               bf16_t* __restrict__ y,
                                               bf16_t* __restrict__ yt) {
  __shared__ bf16_t lnS[64][528];
  int b = blockIdx.x;
  int t = threadIdx.x;
  int wv = t >> 6, lane = t & 63;
  int d0 = lane * 8;
  float4 w1 = *(const float4*)(lw + d0);
  float4 w2 = *(const float4*)(lw + d0 + 4);
  float4 b1 = *(const float4*)(lb + d0);
  float4 b2 = *(const float4*)(lb + d0 + 4);
  float lwv[8] = {w1.x, w1.y, w1.z, w1.w, w2.x, w2.y, w2.z, w2.w};
  float lbv[8] = {b1.x, b1.y, b1.z, b1.w, b2.x, b2.y, b2.z, b2.w};
  const bf16_t* xb = x + (size_t)b * C_ * D_;
  bf16_t* yb = y + (size_t)b * C_ * D_;
#pragma unroll 4
  for (int i = 0; i < 16; ++i) {
    int r = wv * 16 + i;
    bf16x8 xv = *(const bf16x8*)(xb + (size_t)r * D_ + d0);
    float v[8], s = 0.f, q = 0.f;
#pragma unroll
    for (int u = 0; u < 8; ++u) { v[u] = b2f(xv[u]); s += v[u]; q += v[u] * v[u]; }
#pragma unroll
    for (int o = 32; o; o >>= 1) { s += __shfl_xor(s, o); q += __shfl_xor(q, o); }
    float mu = s * (1.0f / D_);
    float rs = rsqrtf(q * (1.0f / D_) - mu * mu + 1e-5f);
    bf16x8 ob;
#pragma unroll
    for (int u = 0; u < 8; ++u) ob[u] = f2b((v[u] - mu) * rs * lwv[u] + lbv[u]);
    *(bf16x8*)(yb + (size_t)r * D_ + d0) = ob;
    *(bf16x8*)(&lnS[r][d0]) = ob;
  }
  __syncthreads();
  bf16_t* tb = yt + (size_t)b * D_ * C_;
#pragma unroll
  for (int pass = 0; pass < 16; ++pass) {
    int d = pass * 32 + (t >> 3);
    int c0 = (t & 7) * 8;
    unsigned short tmp[8];
#pragma unroll
    for (int u = 0; u < 8; ++u) tmp[u] = *(const unsigned short*)&lnS[c0 + u][d];
    *(uint4*)(tb + (size_t)d * 64 + c0) = *(const uint4*)tmp;
  }
}

// ---- MFMA GEMM, 64x64 tiles, dbuf LDS, dual-matrix merge + optional appended
//      transpose blocks (blocks >= ntiles do hln [64][512] -> [512][64] per batch) ----
template <bool BIAS>
__global__ __launch_bounds__(256, 4) void k_gemm64(const bf16_t* __restrict__ A0,
                                                   const bf16_t* __restrict__ W0,
                                                   bf16_t* __restrict__ C0,
                                                   const bf16_t* __restrict__ A1,
                                                   const bf16_t* __restrict__ W1,
                                                   bf16_t* __restrict__ C1,
                                                   const bf16_t* __restrict__ Rb,
                                                   int tiles_per, int ntiles,
                                                   const bf16_t* __restrict__ trS,
                                                   bf16_t* __restrict__ trD) {
  constexpr int ABYTES = 64 * 128;  // 64 rows x 64 bf16
  constexpr int BUF = 2 * ABYTES;   // A + B per buffer = 16 KB
  __shared__ char smem[2 * BUF];    // 32 KB; epilogue Cs + tr path alias

  int t = threadIdx.x;
  int bid = blockIdx.x;

  if (bid >= ntiles) {  // appended transpose block
    int idx = bid - ntiles;
    int n0 = idx & 7, b = idx >> 3;
    unsigned short(*sm)[72] = (unsigned short(*)[72])smem;
    const bf16_t* sb = trS + (size_t)b * C_ * D_;
    bf16_t* db = trD + (size_t)b * D_ * C_;
#pragma unroll
    for (int rep = 0; rep < 2; ++rep) {
      int f = t + rep * 256;
      int r = f >> 3, c8 = f & 7;
      uint4 v = *(const uint4*)(sb + (size_t)r * D_ + n0 * 64 + c8 * 8);
      unsigned int* p = (unsigned int*)&sm[r][c8 * 8];
      p[0] = v.x; p[1] = v.y; p[2] = v.z; p[3] = v.w;
    }
    __syncthreads();
#pragma unroll
    for (int rep = 0; rep < 2; ++rep) {
      int f = t + rep * 256;
      int nr = f >> 3, c8 = f & 7;
      unsigned short tmp[8];
#pragma unroll
      for (int u = 0; u < 8; ++u) tmp[u] = sm[c8 * 8 + u][nr];
      *(uint4*)(db + (size_t)(n0 * 64 + nr) * 64 + c8 * 8) = *(const uint4*)tmp;
    }
    return;
  }

  int lane = t & 63, wave = t >> 6;
  int wr = wave >> 1, wc = wave & 1;
  int lhi = lane >> 4, llo = lane & 15;

  int tile = (bid & 7) * (ntiles >> 3) + (bid >> 3);
  int sel = (tile >= tiles_per) ? 1 : 0;
  int tidx = tile - sel * tiles_per;
  int bm = tidx >> 3, bn = tidx & 7;

  const bf16_t* Ab = (sel ? A1 : A0) + (size_t)bm * 64 * 512;
  const bf16_t* Wb = (sel ? W1 : W0) + (size_t)bn * 64 * 512;
  bf16_t* Cmat = sel ? C1 : C0;

  int l3 = lane >> 3;
  int srcOff = ((lane & 7) ^ l3) * 8;  // pre-swizzled source (rule 21)

  auto stage = [&](int k0, int bi) {
    char* As = smem + bi * BUF;
    char* Bs = As + ABYTES;
#pragma unroll
    for (int i = 0; i < 2; ++i) {
      int r0 = wave * 16 + i * 8;
      gl_lds16(Ab + (size_t)(r0 + l3) * 512 + k0 + srcOff, As + r0 * 128);
      gl_lds16(Wb + (size_t)(r0 + l3) * 512 + k0 + srcOff, Bs + r0 * 128);
    }
  };

  f32x4 acc[2][2] = {};
  stage(0, 0);
  __syncthreads();

  for (int it = 0; it < 8; ++it) {
    int cur = it & 1;
    if (it < 7) stage((it + 1) * 64, cur ^ 1);  // issue BEFORE compute
    const char* As = smem + cur * BUF;
    const char* Bs = As + ABYTES;
#pragma unroll
    for (int kk = 0; kk < 2; ++kk) {
      bf16x8 af[2], bfr[2];
      int bofs = kk * 64 + lhi * 16;
#pragma unroll
      for (int tr = 0; tr < 2; ++tr) {
        int row = wr * 32 + tr * 16 + llo;
        af[tr] = *(const bf16x8*)(As + row * 128 + (bofs ^ ((row & 7) << 4)));
      }
#pragma unroll
      for (int tc = 0; tc < 2; ++tc) {
        int col = wc * 32 + tc * 16 + llo;
        bfr[tc] = *(const bf16x8*)(Bs + col * 128 + (bofs ^ ((col & 7) << 4)));
      }
#pragma unroll
      for (int tr = 0; tr < 2; ++tr)
#pragma unroll
        for (int tc = 0; tc < 2; ++tc)
          acc[tr][tc] = __builtin_amdgcn_mfma_f32_16x16x32_bf16(af[tr], bfr[tc], acc[tr][tc], 0, 0, 0);
    }
    __syncthreads();
  }

  bf16_t(*Cs)[80] = (bf16_t(*)[80])smem;  // 64 x 80 bf16, row stride 160B
#pragma unroll
  for (int tr = 0; tr < 2; ++tr) {
    int row = wr * 32 + tr * 16 + lhi * 4;
#pragma unroll
    for (int r = 0; r < 4; ++r)
#pragma unroll
      for (int tc = 0; tc < 2; ++tc) {
        float v = acc[tr][tc][r];
        if constexpr (BIAS)
          v += b2f(Rb[(size_t)(bm * 64 + row + r) * 512 + bn * 64 + wc * 32 + tc * 16 + llo]);
        Cs[row + r][wc * 32 + tc * 16 + llo] = f2b(v);
      }
  }
  __syncthreads();
#pragma unroll
  for (int it = 0; it < 2; ++it) {
    int idx = t + it * 256;
    int row = idx >> 3, c8 = idx & 7;
    uint4 v = *(const uint4*)(&Cs[row][c8 * 8]);
    *(uint4*)(Cmat + (size_t)(bm * 64 + row) * 512 + bn * 64 + c8 * 8) = v;
  }
}

// ---- fused h2h: gram(MFMA) + softmax + PV(MFMA) + epilogue LN ----
// MODE 0: write hl1f (f32), hl1b (bf16), lnout=LN(hl1) bf16.  MODE 1: lnout only.
template <int MODE>
__global__ __launch_bounds__(256) void k_h2h(const bf16_t* __restrict__ hide,
                                             const bf16_t* __restrict__ hlnT,
                                             const float* __restrict__ lnw,
                                             const float* __restrict__ lnbv,
                                             float* __restrict__ hl1f,
                                             bf16_t* __restrict__ hl1b,
                                             bf16_t* __restrict__ lnout) {
  __shared__ bf16_t hS[8 * 64 * 64];  // 64KB; reused as f32 sf[16][516] in epilogue
  __shared__ float sS[16][68];
  __shared__ bf16_t wS[16 * 64];
  __shared__ float mur[16], rsr[16];

  int q = blockIdx.x;
  int b = blockIdx.y;
  int t = threadIdx.x;
  int lane = t & 63, wave = t >> 6;
  int lhi = lane >> 4, llo = lane & 15;

  const bf16_t* Hb = hide + (size_t)b * C_ * D_;
#pragma unroll
  for (int rep = 0; rep < 16; ++rep) {
    int f = t + rep * 256;
    int row = f >> 6, c16 = f & 63;
    int kc = c16 >> 3, ci = c16 & 7;
    uint4 v = *(const uint4*)(Hb + (size_t)row * 512 + c16 * 8);
    *(uint4*)((char*)hS + kc * 8192 + row * 128 + ((ci * 16) ^ ((row & 7) << 4))) = v;
  }
  __syncthreads();

  {
    f32x4 acc = {};
#pragma unroll
    for (int ks = 0; ks < 16; ++ks) {
      int kc = ks >> 1;
      int bofs = (ks & 1) * 64 + lhi * 16;
      int ra = q * 16 + llo;
      int rb = wave * 16 + llo;
      bf16x8 af = *(const bf16x8*)((const char*)hS + kc * 8192 + ra * 128 + (bofs ^ ((ra & 7) << 4)));
      bf16x8 bf = *(const bf16x8*)((const char*)hS + kc * 8192 + rb * 128 + (bofs ^ ((rb & 7) << 4)));
      acc = __builtin_amdgcn_mfma_f32_16x16x32_bf16(af, bf, acc, 0, 0, 0);
    }
#pragma unroll
    for (int r = 0; r < 4; ++r) sS[lhi * 4 + r][wave * 16 + llo] = acc[r] * INV_SD;
  }
  __syncthreads();

  if (t < 128) {
    int row = t >> 3, sg = t & 7;
    float v[8];
#pragma unroll
    for (int u = 0; u < 8; ++u) v[u] = sS[row][sg * 8 + u];
    float m = v[0];
#pragma unroll
    for (int u = 1; u < 8; ++u) m = fmaxf(m, v[u]);
#pragma unroll
    for (int o = 4; o; o >>= 1) m = fmaxf(m, __shfl_xor(m, o));
    float sum = 0.f;
#pragma unroll
    for (int u = 0; u < 8; ++u) { v[u] = __expf(v[u] - m); sum += v[u]; }
#pragma unroll
    for (int o = 4; o; o >>= 1) sum += __shfl_xor(sum, o);
    float inv = 1.f / sum;
    bf16x8 wv;
#pragma unroll
    for (int u = 0; u < 8; ++u) wv[u] = f2b(v[u] * inv);
    *(bf16x8*)((char*)wS + row * 128 + ((sg * 16) ^ ((row & 7) << 4))) = wv;
  }
  __syncthreads();

  float* sf = (float*)hS;  // [16][516]
  {
    bf16x8 af[2];
#pragma unroll
    for (int ks = 0; ks < 2; ++ks)
      af[ks] = *(const bf16x8*)((const char*)wS + llo * 128 + (((ks * 64 + lhi * 16)) ^ ((llo & 7) << 4)));
    const bf16_t* Tb = hlnT + (size_t)b * D_ * C_;
#pragma unroll
    for (int nt = 0; nt < 8; ++nt) {
      int dcol = wave * 128 + nt * 16 + llo;
      f32x4 acc = {};
#pragma unroll
      for (int ks = 0; ks < 2; ++ks) {
        bf16x8 bf = *(const bf16x8*)(Tb + (size_t)dcol * 64 + ks * 32 + lhi * 8);
        acc = __builtin_amdgcn_mfma_f32_16x16x32_bf16(af[ks], bf, acc, 0, 0, 0);
      }
#pragma unroll
      for (int r = 0; r < 4; ++r) sf[(lhi * 4 + r) * 516 + dcol] = acc[r];
    }
  }
  __syncthreads();

  {
    int lr = t >> 4, p = t & 15;
    float s = 0.f, q2 = 0.f;
#pragma unroll 8
    for (int i = 0; i < 32; ++i) {
      float v = sf[lr * 516 + p + 16 * i];
      s += v;
      q2 += v * v;
    }
#pragma unroll
    for (int o = 8; o; o >>= 1) { s += __shfl_xor(s, o); q2 += __shfl_xor(q2, o); }
    if (p == 0) {
      float mu = s * (1.0f / D_);
      mur[lr] = mu;
      rsr[lr] = rsqrtf(q2 * (1.0f / D_) - mu * mu + 1e-5f);
    }
  }
  __syncthreads();

  int d = 2 * t;
  float lwx = lnw[d], lwy = lnw[d + 1], lbx = lnbv[d], lby = lnbv[d + 1];
#pragma unroll 4
  for (int r = 0; r < 16; ++r) {
    float2 xy = *(const float2*)(&sf[r * 516 + d]);
    size_t go = ((size_t)b * C_ + q * 16 + r) * 512 + d;
    float mu = mur[r], rs = rsr[r];
    if constexpr (MODE == 0) {
      *(float2*)(hl1f + go) = xy;
      bf16x2 hb;
      hb.x = f2b(xy.x);
      hb.y = f2b(xy.y);
      *(bf16x2*)(hl1b + go) = hb;
    }
    bf16x2 lb2;
    lb2.x = f2b((xy.x - mu) * rs * lwx + lbx);
    lb2.y = f2b((xy.y - mu) * rs * lwy + lby);
    *(bf16x2*)(lnout + go) = lb2;
  }
}

// ---- fused layer2 head: per (b,c): h2a#1 for the 16 rows {j*64+c} (att1 bf16 out),
//      LN21 in-register, dot with G, 17-way softmax, u = sum p_j*attln_j, R = p_self*hl1 ----
__global__ __launch_bounds__(256) void k_l2head(const float* __restrict__ att,
                                                const bf16_t* __restrict__ hW,
                                                const float* __restrict__ hl1f,
                                                const bf16_t* __restrict__ G,
                                                const float* __restrict__ lw,
                                                const float* __restrict__ lb,
                                                bf16_t* __restrict__ att1b,
                                                bf16_t* __restrict__ u_out,
                                                bf16_t* __restrict__ R_out) {
  int blk = blockIdx.x;  // b*64 + c
  int b = blk >> 6, c = blk & 63;
  int t = threadIdx.x;
  int w = t >> 6, lane = t & 63;
  int d0 = lane * 8;
  __shared__ bf16_t lnS[16][512];
  __shared__ float hrow[512];
  __shared__ float wts[32];
  __shared__ float red[4];

  {  // stage hl1 row + self-dot
    int d = 2 * t;
    float2 h2 = *(const float2*)(hl1f + (size_t)blk * 512 + d);
    hrow[d] = h2.x;
    hrow[d + 1] = h2.y;
    float sd = h2.x * h2.x + h2.y * h2.y;
#pragma unroll
    for (int o = 32; o; o >>= 1) sd += __shfl_xor(sd, o);
    if (lane == 0) red[w] = sd;
  }
  // wave-private constants (same d0 for all of this wave's rows)
  bf16x8 wb = *(const bf16x8*)(hW + (size_t)blk * 512 + d0);
  bf16x8 gb = *(const bf16x8*)(G + (size_t)blk * 512 + d0);
  float wv[8], gv[8];
#pragma unroll
  for (int u = 0; u < 8; ++u) { wv[u] = b2f(wb[u]); gv[u] = b2f(gb[u]); }
  float4 w1 = *(const float4*)(lw + d0);
  float4 w2 = *(const float4*)(lw + d0 + 4);
  float4 b1 = *(const float4*)(lb + d0);
  float4 b2 = *(const float4*)(lb + d0 + 4);
  float lwv[8] = {w1.x, w1.y, w1.z, w1.w, w2.x, w2.y, w2.z, w2.w};
  float lbv[8] = {b1.x, b1.y, b1.z, b1.w, b2.x, b2.y, b2.z, b2.w};

#pragma unroll
  for (int i = 0; i < 4; ++i) {
    int j = w * 4 + i;
    size_t row = (size_t)b * A_ + j * 64 + c;
    const float* ar = att + row * 512 + d0;
    float4 a1 = *(const float4*)ar;
    float4 a2 = *(const float4*)(ar + 4);
    float av[8] = {a1.x, a1.y, a1.z, a1.w, a2.x, a2.y, a2.z, a2.w};
    float d1 = 0.f, d2 = 0.f;
#pragma unroll
    for (int u = 0; u < 8; ++u) { d1 += av[u] * wv[u]; d2 += av[u] * av[u]; }
#pragma unroll
    for (int o = 32; o; o >>= 1) { d1 += __shfl_xor(d1, o); d2 += __shfl_xor(d2, o); }
    float s1 = d1 * INV_SD, s2 = d2 * INV_SD;
    float m = fmaxf(s1, s2);
    float e1 = __expf(s1 - m), e2 = __expf(s2 - m);
    float inv = 1.f / (e1 + e2);
    float alpha = e1 * inv, beta = e2 * inv;
    float o8[8], s = 0.f, q = 0.f;
    bf16x8 ob;
#pragma unroll
    for (int u = 0; u < 8; ++u) {
      o8[u] = alpha * wv[u] + beta * av[u];
      s += o8[u];
      q += o8[u] * o8[u];
      ob[u] = f2b(o8[u]);
    }
    *(bf16x8*)(att1b + row * 512 + d0) = ob;
#pragma unroll
    for (int o = 32; o; o >>= 1) { s += __shfl_xor(s, o); q += __shfl_xor(q, o); }
    float mu = s * (1.0f / D_);
    float rs = rsqrtf(q * (1.0f / D_) - mu * mu + 1e-5f);
    float dot = 0.f;
    bf16x8 lnv;
#pragma unroll
    for (int u = 0; u < 8; ++u) {
      float v = (o8[u] - mu) * rs * lwv[u] + lbv[u];
      lnv[u] = f2b(v);
      dot += v * gv[u];
    }
    *(bf16x8*)(&lnS[j][d0]) = lnv;
#pragma unroll
    for (int o = 32; o; o >>= 1) dot += __shfl_xor(dot, o);
    if (lane == 0) wts[j] = dot * INV_SD;
  }
  __syncthreads();  // red ready (from pre-loop barrier-free stage) + wts[0..15] + lnS
  if (t == 0) wts[16] = ((red[0] + red[1]) + (red[2] + red[3])) * INV_SD;
  __syncthreads();
  if (t < 64) {
    float val = (t < 17) ? wts[t] : -3.0e38f;
    float m = val;
#pragma unroll
    for (int o = 32; o; o >>= 1) m = fmaxf(m, __shfl_xor(m, o));
    float e = (t < 17) ? __expf(val - m) : 0.f;
    float ssum = e;
#pragma unroll
    for (int o = 32; o; o >>= 1) ssum += __shfl_xor(ssum, o);
    if (t < 17) wts[t] = e / ssum;
  }
  __syncthreads();
  int d = 2 * t;
  float ux = 0.f, uy = 0.f;
#pragma unroll 4
  for (int jj = 0; jj < 16; ++jj) {
    bf16x2 l2 = *(const bf16x2*)(&lnS[jj][d]);
    ux += wts[jj] * b2f(l2.x);
    uy += wts[jj] * b2f(l2.y);
  }
  bf16x2 uo, ro;
  uo.x = f2b(ux);
  uo.y = f2b(uy);
  *(bf16x2*)(u_out + (size_t)blk * 512 + d) = uo;
  float w16 = wts[16];
  ro.x = f2b(w16 * hrow[d]);
  ro.y = f2b(w16 * hrow[d + 1]);
  *(bf16x2*)(R_out + (size_t)blk * 512 + d) = ro;
}

// ---- h2a #2 (final): att1 bf16 in, out f32 ----
__global__ __launch_bounds__(256) void k_h2a_out(const bf16_t* __restrict__ att,
                                                 const bf16_t* __restrict__ hW,
                                                 float* __restrict__ outp) {
  int t = threadIdx.x;
  int row = blockIdx.x * 4 + (t >> 6);
  int lane = t & 63;
  int b = row >> 10, a = row & 1023;
  int c = a & 63;
  int d0 = lane * 8;
  bf16x8 ab = *(const bf16x8*)(att + (size_t)row * D_ + d0);
  bf16x8 wb = *(const bf16x8*)(hW + (size_t)(b * 64 + c) * D_ + d0);
  float av[8], w[8];
#pragma unroll
  for (int u = 0; u < 8; ++u) { av[u] = b2f(ab[u]); w[u] = b2f(wb[u]); }
  float d1 = 0.f, d2 = 0.f;
#pragma unroll
  for (int u = 0; u < 8; ++u) { d1 += av[u] * w[u]; d2 += av[u] * av[u]; }
#pragma unroll
  for (int o = 32; o; o >>= 1) { d1 += __shfl_xor(d1, o); d2 += __shfl_xor(d2, o); }
  float s1 = d1 * INV_SD, s2 = d2 * INV_SD;
  float m = fmaxf(s1, s2);
  float e1 = __expf(s1 - m), e2 = __expf(s2 - m);
  float inv = 1.f / (e1 + e2);
  float alpha = e1 * inv, beta = e2 * inv;
  float4 o1, o2;
  o1.x = alpha * w[0] + beta * av[0]; o1.y = alpha * w[1] + beta * av[1];
  o1.z = alpha * w[2] + beta * av[2]; o1.w = alpha * w[3] + beta * av[3];
  o2.x = alpha * w[4] + beta * av[4]; o2.y = alpha * w[5] + beta * av[5];
  o2.z = alpha * w[6] + beta * av[6]; o2.w = alpha * w[7] + beta * av[7];
  float* orow = outp + (size_t)row * D_ + d0;
  *(float4*)orow = o1;
  *(float4*)(orow + 4) = o2;
}

extern "C" void kernel_launch(void* const* d_in, const int* in_sizes, int n_in,
                              void* d_out, int out_size, void* d_ws, size_t ws_size,
                              hipStream_t stream) {
  const float* att_vf = (const float*)d_in[0];
  const float* W1_h2h = (const float*)d_in[4];
  const float* W1_h2a = (const float*)d_in[5];
  const float* ln11w = (const float*)d_in[6];
  const float* ln11b = (const float*)d_in[7];
  const float* ln12w = (const float*)d_in[8];
  const float* ln12b = (const float*)d_in[9];
  const float* ln13w = (const float*)d_in[10];
  const float* ln13b = (const float*)d_in[11];
  const float* W2_a2h = (const float*)d_in[12];
  const float* W2_h2h = (const float*)d_in[13];
  const float* W2_h2a = (const float*)d_in[14];
  const float* ln21w = (const float*)d_in[15];
  const float* ln21b = (const float*)d_in[16];
  const float* ln22w = (const float*)d_in[17];
  const float* ln22b = (const float*)d_in[18];
  const float* ln23w = (const float*)d_in[19];
  const float* ln23b = (const float*)d_in[20];
  float* out = (float*)d_out;

  float* ws = (float*)d_ws;
  const size_t SM = (size_t)B_ * C_ * D_;  // 2097152 elems
  float* hl1f = ws;                                   // f32 [B*C*D]
  bf16_t* A1b = (bf16_t*)(hl1f + SM);                 // hln bf16
  bf16_t* A1t = (bf16_t*)((float*)A1b + SM / 2);      // hlnT bf16
  bf16_t* A2b = (bf16_t*)((float*)A1t + SM / 2);      // gemm out bf16
  bf16_t* hl1b = (bf16_t*)((float*)A2b + SM / 2);     // hl1 bf16
  bf16_t* u_b = (bf16_t*)((float*)hl1b + SM / 2);     // u bf16
  bf16_t* R_b = (bf16_t*)((float*)u_b + SM / 2);      // R bf16
  bf16_t* Gb = (bf16_t*)((float*)R_b + SM / 2);       // G bf16
  bf16_t* Wt0 = (bf16_t*)((float*)Gb + SM / 2);       // 6 weight slots
  const size_t WTE = (size_t)512 * 512;               // elems per slot
  bf16_t* att1b = Wt0 + 6 * WTE;                      // B*A*D bf16

  dim3 blk(256);
  // prep: hl0 (4096 blocks) + weight transpose/convert (384 blocks)
  k_prep<<<B_ * C_ + 384, blk, 0, stream>>>(att_vf, ln11w, ln11b, ln12w, ln12b, A1b,
                                            W1_h2h, W1_h2a, W2_a2h, W2_h2h, W2_h2a, Wt0);
  // hide1 GEMM (512 tiles) + appended hln transpose blocks (512)
  k_gemm64<false><<<1024, blk, 0, stream>>>(A1b, Wt0 + 0 * WTE, A2b,
                                            A1b, Wt0 + 0 * WTE, A2b, nullptr, 512, 512,
                                            A1b, A1t);
  k_h2h<0><<<dim3(4, B_), blk, 0, stream>>>(A2b, A1t, ln13w, ln13b, hl1f, hl1b, A1b);  // hl1 + ln13
  // merged: hW1 = ln13 @ W1_h2a^T  AND  G = hl1 @ W2_a2h^T
  k_gemm64<false><<<1024, blk, 0, stream>>>(A1b, Wt0 + 1 * WTE, A2b,
                                            hl1b, Wt0 + 5 * WTE, Gb, nullptr, 512, 1024,
                                            nullptr, nullptr);
  // fused layer2 head: att1 + LN21 + scores + softmax17 + u/R
  k_l2head<<<B_ * C_, blk, 0, stream>>>(att_vf, A2b, hl1f, Gb, ln21w, ln21b, att1b, u_b, R_b);
  k_gemm64<true><<<512, blk, 0, stream>>>(u_b, Wt0 + 2 * WTE, A2b,
                                          u_b, Wt0 + 2 * WTE, A2b, R_b, 512, 512,
                                          nullptr, nullptr);  // hl2 = u@W + R
  k_ln_tr<<<B_, blk, 0, stream>>>(A2b, ln22w, ln22b, A1b, A1t);  // ln22 + transpose
  // h2h #2
  k_gemm64<false><<<512, blk, 0, stream>>>(A1b, Wt0 + 3 * WTE, A2b,
                                           A1b, Wt0 + 3 * WTE, A2b, nullptr, 512, 512,
                                           nullptr, nullptr);  // hide2
  k_h2h<1><<<dim3(4, B_), blk, 0, stream>>>(A2b, A1t, ln23w, ln23b, nullptr, nullptr, A1b);  // ln23
  k_gemm64<false><<<512, blk, 0, stream>>>(A1b, Wt0 + 4 * WTE, A2b,
                                           A1b, Wt0 + 4 * WTE, A2b, nullptr, 512, 512,
                                           nullptr, nullptr);  // hW2
  k_h2a_out<<<(B_ * A_) / 4, blk, 0, stream>>>(att1b, A2b, out);
}